// Round 1
// baseline (9791.051 us; speedup 1.0000x reference)
//
#include <hip/hip_runtime.h>
#include <math.h>

#define ED 2700     // basis_dim
#define NC 1024     // num_codes
#define DM 256      // d_model
#define BKROWS 32768

#define IDX_OFF 88473600
#define VQ_OFF  88506368
#define ENT_OFF 88506369

// ---------------- K0: bsq[c] = sum_j basis[c][j]^2 (f64 accumulate) ----------------
__global__ void k_bsq(const float* __restrict__ basis, float* __restrict__ bsq) {
    int c = blockIdx.x;
    const float* row = basis + (size_t)c * ED;
    double s = 0.0;
    for (int j = threadIdx.x; j < ED; j += 256) { float v = row[j]; s += (double)v * (double)v; }
    __shared__ double sd[256];
    sd[threadIdx.x] = s;
    __syncthreads();
    for (int off = 128; off > 0; off >>= 1) {
        if (threadIdx.x < off) sd[threadIdx.x] += sd[threadIdx.x + off];
        __syncthreads();
    }
    if (threadIdx.x == 0) bsq[c] = (float)sd[0];
}

// ---------------- K1: Z = S @ W^T + b  (f32, 64x64 tile, 4x4/thread) ----------------
// Also accumulates zsq[row] = sum_e Z[row][e]^2 via atomics.
__global__ __launch_bounds__(256, 4)
void k_gemm1(const float* __restrict__ S, const float* __restrict__ W,
             const float* __restrict__ bproj, float* __restrict__ Z,
             float* __restrict__ zsq) {
    const int e0 = blockIdx.x * 64;   // 43 tiles over 2700
    const int m0 = blockIdx.y * 64;   // 512 tiles over 32768
    const int t  = threadIdx.x;
    const int tx = t & 15, ty = t >> 4;

    __shared__ float alds[32 * 68];   // [k][row], pad 68 keeps 16B align + spreads banks
    __shared__ float blds[32 * 68];   // [k][e]

    float acc[4][4] = {};

    for (int k0 = 0; k0 < DM; k0 += 32) {
        #pragma unroll
        for (int rep = 0; rep < 2; ++rep) {
            const int id  = t + rep * 256;
            const int row = id >> 3, kq = id & 7;
            const float4 va = *(const float4*)(S + (size_t)(m0 + row) * DM + k0 + 4 * kq);
            alds[(4*kq+0)*68 + row] = va.x;
            alds[(4*kq+1)*68 + row] = va.y;
            alds[(4*kq+2)*68 + row] = va.z;
            alds[(4*kq+3)*68 + row] = va.w;
            float4 vb = make_float4(0.f, 0.f, 0.f, 0.f);
            if (e0 + row < ED)
                vb = *(const float4*)(W + (size_t)(e0 + row) * DM + k0 + 4 * kq);
            blds[(4*kq+0)*68 + row] = vb.x;
            blds[(4*kq+1)*68 + row] = vb.y;
            blds[(4*kq+2)*68 + row] = vb.z;
            blds[(4*kq+3)*68 + row] = vb.w;
        }
        __syncthreads();
        #pragma unroll 8
        for (int k = 0; k < 32; ++k) {
            const float4 a = *(const float4*)&alds[k*68 + 4*ty];
            const float4 b = *(const float4*)&blds[k*68 + 4*tx];
            const float av[4] = {a.x, a.y, a.z, a.w};
            const float bv[4] = {b.x, b.y, b.z, b.w};
            #pragma unroll
            for (int i = 0; i < 4; ++i)
                #pragma unroll
                for (int j = 0; j < 4; ++j)
                    acc[i][j] = fmaf(av[i], bv[j], acc[i][j]);
        }
        __syncthreads();
    }

    const bool valid = (e0 + 4*tx + 4) <= ED;   // ED%4==0 -> all-or-nothing per float4
    float4 bias = make_float4(0.f, 0.f, 0.f, 0.f);
    if (valid) bias = *(const float4*)(bproj + e0 + 4*tx);
    float psum[4] = {0.f, 0.f, 0.f, 0.f};
    #pragma unroll
    for (int i = 0; i < 4; ++i) {
        if (valid) {
            float4 o;
            o.x = acc[i][0] + bias.x;
            o.y = acc[i][1] + bias.y;
            o.z = acc[i][2] + bias.z;
            o.w = acc[i][3] + bias.w;
            *(float4*)(Z + (size_t)(m0 + 4*ty + i) * ED + e0 + 4*tx) = o;
            psum[i] = o.x*o.x + o.y*o.y + o.z*o.z + o.w*o.w;
        }
    }
    float* red = alds;  // reuse (safe: loop ended with __syncthreads)
    #pragma unroll
    for (int i = 0; i < 4; ++i) red[(4*ty + i) * 16 + tx] = psum[i];
    __syncthreads();
    if (t < 64) {
        float s = 0.f;
        #pragma unroll
        for (int x = 0; x < 16; ++x) s += red[t * 16 + x];
        atomicAdd(&zsq[m0 + t], s);
    }
}

// ---------------- K2: fused dist GEMM + argmin + softmax + avg_prob partials ----------------
// One workgroup owns 32 rows x ALL 1024 codes (acc fully register-resident).
__global__ __launch_bounds__(512, 4)
void k_dist(const float* __restrict__ Z, const float* __restrict__ basis,
            const float* __restrict__ bsq, const float* __restrict__ zsq,
            float* __restrict__ A, float* __restrict__ wgpart,
            int* __restrict__ idxws, float* __restrict__ out) {
    const int bid = blockIdx.x;
    const int wr0 = bid * 32;
    const int t   = threadIdx.x;
    const int cg  = t & 127;
    const int rq  = t >> 7;
    const int r0  = rq * 8;
    const int c0  = cg * 4;
    const int c1  = 512 + cg * 4;

    __shared__ float blds[16 * 1024];  // [k][code] (transposed stage)
    __shared__ float zlds[16 * 36];    // [k][row], stride 36 keeps 16B align

    float acc[8][8];
    #pragma unroll
    for (int i = 0; i < 8; ++i)
        #pragma unroll
        for (int j = 0; j < 8; ++j) acc[i][j] = 0.f;

    for (int k0 = 0; k0 < ED; k0 += 16) {
        const bool full = (k0 + 16) <= ED;
        // stage basis chunk, transposed: blds[kk][c] = basis[c][k0+kk]
        #pragma unroll
        for (int rep = 0; rep < 2; ++rep) {
            const int c = t + rep * 512;
            const float* bp = basis + (size_t)c * ED + k0;
            if (full) {
                const float4 v0 = *(const float4*)(bp + 0);
                const float4 v1 = *(const float4*)(bp + 4);
                const float4 v2 = *(const float4*)(bp + 8);
                const float4 v3 = *(const float4*)(bp + 12);
                blds[ 0*1024+c]=v0.x; blds[ 1*1024+c]=v0.y; blds[ 2*1024+c]=v0.z; blds[ 3*1024+c]=v0.w;
                blds[ 4*1024+c]=v1.x; blds[ 5*1024+c]=v1.y; blds[ 6*1024+c]=v1.z; blds[ 7*1024+c]=v1.w;
                blds[ 8*1024+c]=v2.x; blds[ 9*1024+c]=v2.y; blds[10*1024+c]=v2.z; blds[11*1024+c]=v2.w;
                blds[12*1024+c]=v3.x; blds[13*1024+c]=v3.y; blds[14*1024+c]=v3.z; blds[15*1024+c]=v3.w;
            } else {
                for (int kk = 0; kk < 16; ++kk)
                    blds[kk*1024 + c] = (k0 + kk < ED) ? bp[kk] : 0.f;
            }
        }
        // stage z chunk, transposed: zlds[kk][row] = Z[wr0+row][k0+kk]
        if (t < 128) {
            const int row = t >> 2, kq = t & 3;
            const float* zp = Z + (size_t)(wr0 + row) * ED + k0 + 4 * kq;
            if (full) {
                const float4 v = *(const float4*)zp;
                zlds[(4*kq+0)*36 + row] = v.x;
                zlds[(4*kq+1)*36 + row] = v.y;
                zlds[(4*kq+2)*36 + row] = v.z;
                zlds[(4*kq+3)*36 + row] = v.w;
            } else {
                for (int j = 0; j < 4; ++j) {
                    const int k = k0 + 4*kq + j;
                    zlds[(4*kq+j)*36 + row] = (k < ED) ? zp[j] : 0.f;
                }
            }
        }
        __syncthreads();
        #pragma unroll
        for (int k = 0; k < 16; ++k) {
            const float4 z0 = *(const float4*)&zlds[k*36 + r0];
            const float4 z1 = *(const float4*)&zlds[k*36 + r0 + 4];
            const float4 b0 = *(const float4*)&blds[k*1024 + c0];
            const float4 b1 = *(const float4*)&blds[k*1024 + c1];
            const float zz[8] = {z0.x, z0.y, z0.z, z0.w, z1.x, z1.y, z1.z, z1.w};
            const float bb[8] = {b0.x, b0.y, b0.z, b0.w, b1.x, b1.y, b1.z, b1.w};
            #pragma unroll
            for (int i = 0; i < 8; ++i)
                #pragma unroll
                for (int j = 0; j < 8; ++j)
                    acc[i][j] = fmaf(zz[i], bb[j], acc[i][j]);
        }
        __syncthreads();
    }

    // ---------------- epilogue (LDS reused) ----------------
    float* red_v    = blds;               // [32][128]
    int*   red_i    = (int*)(blds + 4096);// [32][128]
    float* row_dmin = blds + 8192;        // [32]
    float* row_s    = blds + 8224;        // [32]
    float* pc       = blds + 8256;        // [1024]

    float bsqv[8], zsqv[8];
    #pragma unroll
    for (int j = 0; j < 4; ++j) { bsqv[j] = bsq[c0 + j]; bsqv[4 + j] = bsq[c1 + j]; }
    #pragma unroll
    for (int i = 0; i < 8; ++i) zsqv[i] = zsq[wr0 + r0 + i];

    // d = (zsq - 2*zb) + bsq  (mimics numpy association); overwrite acc with d
    #pragma unroll
    for (int i = 0; i < 8; ++i)
        #pragma unroll
        for (int j = 0; j < 8; ++j) {
            const float tv = zsqv[i] - 2.f * acc[i][j];
            acc[i][j] = tv + bsqv[j];
        }

    // thread-local argmin per row (codes ascending within thread)
    #pragma unroll
    for (int i = 0; i < 8; ++i) {
        float bv = acc[i][0]; int bi = c0;
        #pragma unroll
        for (int j = 1; j < 8; ++j) {
            const int c = (j < 4) ? (c0 + j) : (c1 + (j - 4));
            if (acc[i][j] < bv || (acc[i][j] == bv && c < bi)) { bv = acc[i][j]; bi = c; }
        }
        red_v[(r0 + i) * 128 + cg] = bv;
        red_i[(r0 + i) * 128 + cg] = bi;
    }
    __syncthreads();
    if (t < 32) {   // row owners: global argmin with first-index tiebreak
        float bv = red_v[t * 128]; int bi = red_i[t * 128];
        for (int x = 1; x < 128; ++x) {
            const float v = red_v[t * 128 + x];
            const int  iv = red_i[t * 128 + x];
            if (v < bv || (v == bv && iv < bi)) { bv = v; bi = iv; }
        }
        row_dmin[t] = bv;
        idxws[wr0 + t] = bi;
        out[IDX_OFF + wr0 + t] = (float)bi;
    }
    __syncthreads();

    // u = exp(dmin - d); row sums
    float su[8];
    #pragma unroll
    for (int i = 0; i < 8; ++i) {
        const float dm = row_dmin[r0 + i];
        float s = 0.f;
        #pragma unroll
        for (int j = 0; j < 8; ++j) {
            const float u = expf(dm - acc[i][j]);
            acc[i][j] = u;
            s += u;
        }
        su[i] = s;
    }
    #pragma unroll
    for (int i = 0; i < 8; ++i) red_v[(r0 + i) * 128 + cg] = su[i];
    __syncthreads();
    if (t < 32) {
        float s = 0.f;
        for (int x = 0; x < 128; ++x) s += red_v[t * 128 + x];
        row_s[t] = s;
    }
    __syncthreads();

    float rcp[8];
    #pragma unroll
    for (int i = 0; i < 8; ++i) rcp[i] = 1.f / row_s[r0 + i];

    pc[t] = 0.f; pc[t + 512] = 0.f;
    __syncthreads();
    #pragma unroll
    for (int j = 0; j < 8; ++j) {
        const int c = (j < 4) ? (c0 + j) : (c1 + (j - 4));
        float s = 0.f;
        #pragma unroll
        for (int i = 0; i < 8; ++i) s += acc[i][j] * rcp[i];
        atomicAdd(&pc[c], s);
    }
    __syncthreads();
    atomicAdd(&A[t],       pc[t]);
    atomicAdd(&A[t + 512], pc[t + 512]);

    if (t == 0) {
        float s = 0.f;
        for (int r = 0; r < 32; ++r) s += row_dmin[r];   // sum of dist_min = sum ||z-e||^2
        wgpart[bid] = s;
    }
}

// ---------------- K3: finalize scalars ----------------
__global__ void k_final(const float* __restrict__ wgpart, const float* __restrict__ A,
                        float* __restrict__ out) {
    __shared__ double sd[1024];
    const int t = threadIdx.x;
    sd[t] = (double)wgpart[t];
    __syncthreads();
    for (int off = 512; off > 0; off >>= 1) {
        if (t < off) sd[t] += sd[t + off];
        __syncthreads();
    }
    if (t == 0) out[VQ_OFF] = (float)(0.25 * sd[0] / 88473600.0);
    __syncthreads();
    const double p = (double)A[t] * (1.0 / 32768.0);
    sd[t] = -p * log(p + 1e-8);
    __syncthreads();
    for (int off = 512; off > 0; off >>= 1) {
        if (t < off) sd[t] += sd[t + off];
        __syncthreads();
    }
    if (t == 0) out[ENT_OFF] = (float)sd[0];
}

// ---------------- K4: q_st = basis[indices] (overwrites Z scratch region) ----------------
__global__ void k_gather(const float* __restrict__ basis, const int* __restrict__ idxws,
                         float* __restrict__ out) {
    const int r = blockIdx.x;
    const int idx = idxws[r];
    const float4* src = (const float4*)(basis + (size_t)idx * ED);
    float4* dst = (float4*)(out + (size_t)r * ED);
    for (int j = threadIdx.x; j < ED / 4; j += 256) dst[j] = src[j];
}

extern "C" void kernel_launch(void* const* d_in, const int* in_sizes, int n_in,
                              void* d_out, int out_size, void* d_ws, size_t ws_size,
                              hipStream_t stream) {
    const float* S     = (const float*)d_in[0];  // [32768, 256]
    const float* W     = (const float*)d_in[1];  // [2700, 256]
    const float* bproj = (const float*)d_in[2];  // [2700]
    const float* basis = (const float*)d_in[3];  // [1024, 2700]
    float* out = (float*)d_out;
    float* ws  = (float*)d_ws;

    float* zsq    = ws;            // 32768
    float* A      = ws + 32768;    // 1024
    float* bsq    = ws + 33792;    // 1024
    float* wgpart = ws + 34816;    // 1024
    int*   idxws  = (int*)(ws + 35840); // 32768
    float* Z      = out;           // q_st region doubles as Z scratch

    // zero the accumulated regions (ws poisoned 0xAA once; not re-poisoned between replays)
    hipMemsetAsync(ws, 0, (size_t)35840 * sizeof(float), stream);

    k_bsq   <<<NC, 256, 0, stream>>>(basis, bsq);
    k_gemm1 <<<dim3(43, 512), 256, 0, stream>>>(S, W, bproj, Z, zsq);
    k_dist  <<<BKROWS / 32, 512, 0, stream>>>(Z, basis, bsq, zsq, A, wgpart, idxws, out);
    k_final <<<1, 1024, 0, stream>>>(wgpart, A, out);
    k_gather<<<BKROWS, 256, 0, stream>>>(basis, idxws, out);
}

// Round 2
// 4175.098 us; speedup vs baseline: 2.3451x; 2.3451x over previous
//
#include <hip/hip_runtime.h>
#include <math.h>

#define ED 2700     // basis_dim
#define NC 1024     // num_codes
#define DM 256      // d_model
#define BKROWS 32768

#define IDX_OFF 88473600
#define VQ_OFF  88506368
#define ENT_OFF 88506369

// ---------------- K0: bsq[c] = sum_j basis[c][j]^2 (f64 accumulate) ----------------
__global__ void k_bsq(const float* __restrict__ basis, float* __restrict__ bsq) {
    int c = blockIdx.x;
    const float* row = basis + (size_t)c * ED;
    double s = 0.0;
    for (int j = threadIdx.x; j < ED; j += 256) { float v = row[j]; s += (double)v * (double)v; }
    __shared__ double sd[256];
    sd[threadIdx.x] = s;
    __syncthreads();
    for (int off = 128; off > 0; off >>= 1) {
        if (threadIdx.x < off) sd[threadIdx.x] += sd[threadIdx.x + off];
        __syncthreads();
    }
    if (threadIdx.x == 0) bsq[c] = (float)sd[0];
}

// ---------------- K1: Z = S @ W^T + b  (f32, 64x64 tile, 4x4/thread) ----------------
__global__ __launch_bounds__(256, 4)
void k_gemm1(const float* __restrict__ S, const float* __restrict__ W,
             const float* __restrict__ bproj, float* __restrict__ Z) {
    const int e0 = blockIdx.x * 64;   // 43 tiles over 2700
    const int m0 = blockIdx.y * 64;   // 512 tiles over 32768
    const int t  = threadIdx.x;
    const int tx = t & 15, ty = t >> 4;

    __shared__ float alds[32 * 68];   // [k][row]
    __shared__ float blds[32 * 68];   // [k][e]

    float acc[4][4] = {};

    for (int k0 = 0; k0 < DM; k0 += 32) {
        #pragma unroll
        for (int rep = 0; rep < 2; ++rep) {
            const int id  = t + rep * 256;
            const int row = id >> 3, kq = id & 7;
            const float4 va = *(const float4*)(S + (size_t)(m0 + row) * DM + k0 + 4 * kq);
            alds[(4*kq+0)*68 + row] = va.x;
            alds[(4*kq+1)*68 + row] = va.y;
            alds[(4*kq+2)*68 + row] = va.z;
            alds[(4*kq+3)*68 + row] = va.w;
            float4 vb = make_float4(0.f, 0.f, 0.f, 0.f);
            if (e0 + row < ED)
                vb = *(const float4*)(W + (size_t)(e0 + row) * DM + k0 + 4 * kq);
            blds[(4*kq+0)*68 + row] = vb.x;
            blds[(4*kq+1)*68 + row] = vb.y;
            blds[(4*kq+2)*68 + row] = vb.z;
            blds[(4*kq+3)*68 + row] = vb.w;
        }
        __syncthreads();
        #pragma unroll 8
        for (int k = 0; k < 32; ++k) {
            const float4 a = *(const float4*)&alds[k*68 + 4*ty];
            const float4 b = *(const float4*)&blds[k*68 + 4*tx];
            const float av[4] = {a.x, a.y, a.z, a.w};
            const float bv[4] = {b.x, b.y, b.z, b.w};
            #pragma unroll
            for (int i = 0; i < 4; ++i)
                #pragma unroll
                for (int j = 0; j < 4; ++j)
                    acc[i][j] = fmaf(av[i], bv[j], acc[i][j]);
        }
        __syncthreads();
    }

    const bool valid = (e0 + 4*tx + 4) <= ED;
    float4 bias = make_float4(0.f, 0.f, 0.f, 0.f);
    if (valid) bias = *(const float4*)(bproj + e0 + 4*tx);
    #pragma unroll
    for (int i = 0; i < 4; ++i) {
        if (valid) {
            float4 o;
            o.x = acc[i][0] + bias.x;
            o.y = acc[i][1] + bias.y;
            o.z = acc[i][2] + bias.z;
            o.w = acc[i][3] + bias.w;
            *(float4*)(Z + (size_t)(m0 + 4*ty + i) * ED + e0 + 4*tx) = o;
        }
    }
}

// ---------------- K1b: zsq[r] = sum_e Z[r][e]^2 (deterministic, f64 accumulate) ----------------
__global__ __launch_bounds__(64)
void k_zsq(const float* __restrict__ Z, float* __restrict__ zsq) {
    const int r = blockIdx.x;
    const float4* row4 = (const float4*)(Z + (size_t)r * ED);
    double s = 0.0;
    for (int q = threadIdx.x; q < ED / 4; q += 64) {   // ED%4 == 0
        const float4 v = row4[q];
        s += (double)v.x * v.x + (double)v.y * v.y + (double)v.z * v.z + (double)v.w * v.w;
    }
    #pragma unroll
    for (int off = 32; off > 0; off >>= 1) s += __shfl_down(s, off);
    if (threadIdx.x == 0) zsq[r] = (float)s;
}

// ---------------- K2: fused dist GEMM + argmin + softmax + avg_prob partials ----------------
__global__ __launch_bounds__(512, 2)
void k_dist(const float* __restrict__ Z, const float* __restrict__ basis,
            const float* __restrict__ bsq, const float* __restrict__ zsq,
            float* __restrict__ A, float* __restrict__ wgpart,
            int* __restrict__ idxws, float* __restrict__ out) {
    const int bid = blockIdx.x;
    const int wr0 = bid * 32;
    const int t   = threadIdx.x;
    const int cg  = t & 127;
    const int rq  = t >> 7;
    const int r0  = rq * 8;
    const int c0  = cg * 4;
    const int c1  = 512 + cg * 4;

    __shared__ float blds[16 * 1024];  // [k][code] (transposed stage)
    __shared__ float zlds[16 * 36];    // [k][row]

    float acc[8][8];
    #pragma unroll
    for (int i = 0; i < 8; ++i)
        #pragma unroll
        for (int j = 0; j < 8; ++j) acc[i][j] = 0.f;

    for (int k0 = 0; k0 < ED; k0 += 16) {
        const bool full = (k0 + 16) <= ED;
        #pragma unroll
        for (int rep = 0; rep < 2; ++rep) {
            const int c = t + rep * 512;
            const float* bp = basis + (size_t)c * ED + k0;
            if (full) {
                const float4 v0 = *(const float4*)(bp + 0);
                const float4 v1 = *(const float4*)(bp + 4);
                const float4 v2 = *(const float4*)(bp + 8);
                const float4 v3 = *(const float4*)(bp + 12);
                blds[ 0*1024+c]=v0.x; blds[ 1*1024+c]=v0.y; blds[ 2*1024+c]=v0.z; blds[ 3*1024+c]=v0.w;
                blds[ 4*1024+c]=v1.x; blds[ 5*1024+c]=v1.y; blds[ 6*1024+c]=v1.z; blds[ 7*1024+c]=v1.w;
                blds[ 8*1024+c]=v2.x; blds[ 9*1024+c]=v2.y; blds[10*1024+c]=v2.z; blds[11*1024+c]=v2.w;
                blds[12*1024+c]=v3.x; blds[13*1024+c]=v3.y; blds[14*1024+c]=v3.z; blds[15*1024+c]=v3.w;
            } else {
                for (int kk = 0; kk < 16; ++kk)
                    blds[kk*1024 + c] = (k0 + kk < ED) ? bp[kk] : 0.f;
            }
        }
        if (t < 128) {
            const int row = t >> 2, kq = t & 3;
            const float* zp = Z + (size_t)(wr0 + row) * ED + k0 + 4 * kq;
            if (full) {
                const float4 v = *(const float4*)zp;
                zlds[(4*kq+0)*36 + row] = v.x;
                zlds[(4*kq+1)*36 + row] = v.y;
                zlds[(4*kq+2)*36 + row] = v.z;
                zlds[(4*kq+3)*36 + row] = v.w;
            } else {
                for (int j = 0; j < 4; ++j) {
                    const int k = k0 + 4*kq + j;
                    zlds[(4*kq+j)*36 + row] = (k < ED) ? zp[j] : 0.f;
                }
            }
        }
        __syncthreads();
        #pragma unroll
        for (int k = 0; k < 16; ++k) {
            const float4 z0 = *(const float4*)&zlds[k*36 + r0];
            const float4 z1 = *(const float4*)&zlds[k*36 + r0 + 4];
            const float4 b0 = *(const float4*)&blds[k*1024 + c0];
            const float4 b1 = *(const float4*)&blds[k*1024 + c1];
            const float zz[8] = {z0.x, z0.y, z0.z, z0.w, z1.x, z1.y, z1.z, z1.w};
            const float bb[8] = {b0.x, b0.y, b0.z, b0.w, b1.x, b1.y, b1.z, b1.w};
            #pragma unroll
            for (int i = 0; i < 8; ++i)
                #pragma unroll
                for (int j = 0; j < 8; ++j)
                    acc[i][j] = fmaf(zz[i], bb[j], acc[i][j]);
        }
        __syncthreads();
    }

    // ---------------- epilogue (LDS reused) ----------------
    float* red_v    = blds;               // [32][128]
    int*   red_i    = (int*)(blds + 4096);// [32][128]
    float* row_dmin = blds + 8192;        // [32]
    float* row_s    = blds + 8224;        // [32]
    float* pc       = blds + 8256;        // [1024]

    float bsqv[8], zsqv[8];
    #pragma unroll
    for (int j = 0; j < 4; ++j) { bsqv[j] = bsq[c0 + j]; bsqv[4 + j] = bsq[c1 + j]; }
    #pragma unroll
    for (int i = 0; i < 8; ++i) zsqv[i] = zsq[wr0 + r0 + i];

    #pragma unroll
    for (int i = 0; i < 8; ++i)
        #pragma unroll
        for (int j = 0; j < 8; ++j) {
            const float tv = zsqv[i] - 2.f * acc[i][j];
            acc[i][j] = tv + bsqv[j];
        }

    #pragma unroll
    for (int i = 0; i < 8; ++i) {
        float bv = acc[i][0]; int bi = c0;
        #pragma unroll
        for (int j = 1; j < 8; ++j) {
            const int c = (j < 4) ? (c0 + j) : (c1 + (j - 4));
            if (acc[i][j] < bv || (acc[i][j] == bv && c < bi)) { bv = acc[i][j]; bi = c; }
        }
        red_v[(r0 + i) * 128 + cg] = bv;
        red_i[(r0 + i) * 128 + cg] = bi;
    }
    __syncthreads();
    if (t < 32) {
        float bv = red_v[t * 128]; int bi = red_i[t * 128];
        for (int x = 1; x < 128; ++x) {
            const float v = red_v[t * 128 + x];
            const int  iv = red_i[t * 128 + x];
            if (v < bv || (v == bv && iv < bi)) { bv = v; bi = iv; }
        }
        row_dmin[t] = bv;
        idxws[wr0 + t] = bi;
        out[IDX_OFF + wr0 + t] = (float)bi;
    }
    __syncthreads();

    float su[8];
    #pragma unroll
    for (int i = 0; i < 8; ++i) {
        const float dm = row_dmin[r0 + i];
        float s = 0.f;
        #pragma unroll
        for (int j = 0; j < 8; ++j) {
            const float u = expf(dm - acc[i][j]);
            acc[i][j] = u;
            s += u;
        }
        su[i] = s;
    }
    #pragma unroll
    for (int i = 0; i < 8; ++i) red_v[(r0 + i) * 128 + cg] = su[i];
    __syncthreads();
    if (t < 32) {
        float s = 0.f;
        for (int x = 0; x < 128; ++x) s += red_v[t * 128 + x];
        row_s[t] = s;
    }
    __syncthreads();

    float rcp[8];
    #pragma unroll
    for (int i = 0; i < 8; ++i) rcp[i] = 1.f / row_s[r0 + i];

    pc[t] = 0.f; pc[t + 512] = 0.f;
    __syncthreads();
    #pragma unroll
    for (int j = 0; j < 8; ++j) {
        const int c = (j < 4) ? (c0 + j) : (c1 + (j - 4));
        float s = 0.f;
        #pragma unroll
        for (int i = 0; i < 8; ++i) s += acc[i][j] * rcp[i];
        atomicAdd(&pc[c], s);
    }
    __syncthreads();
    atomicAdd(&A[t],       pc[t]);
    atomicAdd(&A[t + 512], pc[t + 512]);

    if (t == 0) {
        float s = 0.f;
        for (int r = 0; r < 32; ++r) s += row_dmin[r];
        wgpart[bid] = s;
    }
}

// ---------------- K3: finalize scalars ----------------
__global__ void k_final(const float* __restrict__ wgpart, const float* __restrict__ A,
                        float* __restrict__ out) {
    __shared__ double sd[1024];
    const int t = threadIdx.x;
    sd[t] = (double)wgpart[t];
    __syncthreads();
    for (int off = 512; off > 0; off >>= 1) {
        if (t < off) sd[t] += sd[t + off];
        __syncthreads();
    }
    if (t == 0) out[VQ_OFF] = (float)(0.25 * sd[0] / 88473600.0);
    __syncthreads();
    const double p = (double)A[t] * (1.0 / 32768.0);
    sd[t] = -p * log(p + 1e-8);
    __syncthreads();
    for (int off = 512; off > 0; off >>= 1) {
        if (t < off) sd[t] += sd[t + off];
        __syncthreads();
    }
    if (t == 0) out[ENT_OFF] = (float)sd[0];
}

// ---------------- K4: q_st = basis[indices] ----------------
__global__ void k_gather(const float* __restrict__ basis, const int* __restrict__ idxws,
                         float* __restrict__ out) {
    const int r = blockIdx.x;
    const int idx = idxws[r];
    const float4* src = (const float4*)(basis + (size_t)idx * ED);
    float4* dst = (float4*)(out + (size_t)r * ED);
    for (int j = threadIdx.x; j < ED / 4; j += 256) dst[j] = src[j];
}

extern "C" void kernel_launch(void* const* d_in, const int* in_sizes, int n_in,
                              void* d_out, int out_size, void* d_ws, size_t ws_size,
                              hipStream_t stream) {
    const float* S     = (const float*)d_in[0];  // [32768, 256]
    const float* W     = (const float*)d_in[1];  // [2700, 256]
    const float* bproj = (const float*)d_in[2];  // [2700]
    const float* basis = (const float*)d_in[3];  // [1024, 2700]
    float* out = (float*)d_out;
    float* ws  = (float*)d_ws;

    float* zsq    = ws;            // 32768
    float* A      = ws + 32768;    // 1024
    float* bsq    = ws + 33792;    // 1024
    float* wgpart = ws + 34816;    // 1024
    int*   idxws  = (int*)(ws + 35840); // 32768
    float* Z      = out;           // q_st region doubles as Z scratch

    // A is accumulated via atomics each call -> zero it every launch
    hipMemsetAsync(A, 0, (size_t)NC * sizeof(float), stream);

    k_bsq   <<<NC, 256, 0, stream>>>(basis, bsq);
    k_gemm1 <<<dim3(43, 512), 256, 0, stream>>>(S, W, bproj, Z);
    k_zsq   <<<BKROWS, 64, 0, stream>>>(Z, zsq);
    k_dist  <<<BKROWS / 32, 512, 0, stream>>>(Z, basis, bsq, zsq, A, wgpart, idxws, out);
    k_final <<<1, 1024, 0, stream>>>(wgpart, A, out);
    k_gather<<<BKROWS, 256, 0, stream>>>(basis, idxws, out);
}

// Round 3
// 1494.145 us; speedup vs baseline: 6.5529x; 2.7943x over previous
//
#include <hip/hip_runtime.h>
#include <math.h>

#define ED 2700     // basis_dim
#define NC 1024     // num_codes
#define DM 256      // d_model
#define BKROWS 32768

#define IDX_OFF 88473600
#define VQ_OFF  88506368
#define ENT_OFF 88506369

#define BSTRIDE 2720        // padded k-stride for basis planes (zero tail)
#define NCHUNK 85           // ceil(2700/32)

typedef float  f32x4  __attribute__((ext_vector_type(4)));
typedef short  bf16x8 __attribute__((ext_vector_type(8)));

__device__ inline unsigned short f2bf(float x) {
    unsigned int u = __float_as_uint(x);
    unsigned int r = (u + 0x7FFFu + ((u >> 16) & 1u)) >> 16;
    return (unsigned short)r;
}
__device__ inline float bf2f(unsigned short h) {
    return __uint_as_float(((unsigned int)h) << 16);
}

// =====================================================================
// ============================ NEW MFMA PATH ==========================
// =====================================================================

// ---- K-packB: basis -> Bh/Bm bf16 planes (stride 2720, zero pad) + bsq (f64) ----
__global__ void k_packB(const float* __restrict__ basis, unsigned short* __restrict__ Bh,
                        unsigned short* __restrict__ Bm, float* __restrict__ bsq) {
    const int c = blockIdx.x;
    const int t = threadIdx.x;
    const float* row = basis + (size_t)c * ED;
    double s = 0.0;
    for (int j = t; j < ED; j += 256) {
        const float x = row[j];
        s += (double)x * (double)x;
        const unsigned short h = f2bf(x);
        Bh[(size_t)c * BSTRIDE + j] = h;
        Bm[(size_t)c * BSTRIDE + j] = f2bf(x - bf2f(h));
    }
    if (t < BSTRIDE - ED) {
        Bh[(size_t)c * BSTRIDE + ED + t] = 0;
        Bm[(size_t)c * BSTRIDE + ED + t] = 0;
    }
    __shared__ double sd[256];
    sd[t] = s;
    __syncthreads();
    for (int off = 128; off > 0; off >>= 1) {
        if (t < off) sd[t] += sd[t + off];
        __syncthreads();
    }
    if (t == 0) bsq[c] = (float)sd[0];
}

// ---- K1p: Z = S@W^T + b, emitted as bf16 hi/lo planes + zsq partials ----
__global__ __launch_bounds__(256, 4)
void k_gemm1p(const float* __restrict__ S, const float* __restrict__ W,
              const float* __restrict__ bproj, unsigned short* __restrict__ Zh,
              unsigned short* __restrict__ Zm, float* __restrict__ zsqpart) {
    const int e0 = blockIdx.x * 64;   // 43 tiles over 2700
    const int m0 = blockIdx.y * 64;   // 512 tiles over 32768
    const int t  = threadIdx.x;
    const int tx = t & 15, ty = t >> 4;

    __shared__ float alds[32 * 68];
    __shared__ float blds[32 * 68];

    float acc[4][4] = {};

    for (int k0 = 0; k0 < DM; k0 += 32) {
        #pragma unroll
        for (int rep = 0; rep < 2; ++rep) {
            const int id  = t + rep * 256;
            const int row = id >> 3, kq = id & 7;
            const float4 va = *(const float4*)(S + (size_t)(m0 + row) * DM + k0 + 4 * kq);
            alds[(4*kq+0)*68 + row] = va.x;
            alds[(4*kq+1)*68 + row] = va.y;
            alds[(4*kq+2)*68 + row] = va.z;
            alds[(4*kq+3)*68 + row] = va.w;
            float4 vb = make_float4(0.f, 0.f, 0.f, 0.f);
            if (e0 + row < ED)
                vb = *(const float4*)(W + (size_t)(e0 + row) * DM + k0 + 4 * kq);
            blds[(4*kq+0)*68 + row] = vb.x;
            blds[(4*kq+1)*68 + row] = vb.y;
            blds[(4*kq+2)*68 + row] = vb.z;
            blds[(4*kq+3)*68 + row] = vb.w;
        }
        __syncthreads();
        #pragma unroll 8
        for (int k = 0; k < 32; ++k) {
            const float4 a = *(const float4*)&alds[k*68 + 4*ty];
            const float4 b = *(const float4*)&blds[k*68 + 4*tx];
            const float av[4] = {a.x, a.y, a.z, a.w};
            const float bv[4] = {b.x, b.y, b.z, b.w};
            #pragma unroll
            for (int i = 0; i < 4; ++i)
                #pragma unroll
                for (int j = 0; j < 4; ++j)
                    acc[i][j] = fmaf(av[i], bv[j], acc[i][j]);
        }
        __syncthreads();
    }

    const bool valid = (e0 + 4*tx + 4) <= ED;
    float4 bias = make_float4(0.f, 0.f, 0.f, 0.f);
    if (valid) bias = *(const float4*)(bproj + e0 + 4*tx);
    float psum[4] = {0.f, 0.f, 0.f, 0.f};
    #pragma unroll
    for (int i = 0; i < 4; ++i) {
        if (valid) {
            float z[4];
            z[0] = acc[i][0] + bias.x;
            z[1] = acc[i][1] + bias.y;
            z[2] = acc[i][2] + bias.z;
            z[3] = acc[i][3] + bias.w;
            ushort4 hv, mv;
            unsigned short* hp = (unsigned short*)&hv;
            unsigned short* mp = (unsigned short*)&mv;
            #pragma unroll
            for (int j = 0; j < 4; ++j) {
                const unsigned short h = f2bf(z[j]);
                hp[j] = h;
                mp[j] = f2bf(z[j] - bf2f(h));
                psum[i] += z[j] * z[j];
            }
            const size_t off = (size_t)(m0 + 4*ty + i) * ED + e0 + 4*tx;
            *(ushort4*)(Zh + off) = hv;
            *(ushort4*)(Zm + off) = mv;
        }
    }
    float* red = alds;
    #pragma unroll
    for (int i = 0; i < 4; ++i) red[(4*ty + i) * 16 + tx] = psum[i];
    __syncthreads();
    if (t < 64) {
        float s = 0.f;
        #pragma unroll
        for (int x = 0; x < 16; ++x) s += red[t * 16 + x];
        zsqpart[(size_t)blockIdx.x * BKROWS + m0 + t] = s;  // [43][32768] coalesced
    }
}

// ---- zsq[r] = sum over 43 partials (f64, deterministic) ----
__global__ void k_zsqred(const float* __restrict__ part, float* __restrict__ zsq) {
    const int r = blockIdx.x * 256 + threadIdx.x;
    double s = 0.0;
    #pragma unroll
    for (int b = 0; b < 43; ++b) s += (double)part[(size_t)b * BKROWS + r];
    zsq[r] = (float)s;
}

// ---- K2m: G = Z.B^T via 3-product split-bf16 MFMA, 128x128 tile ----
__global__ __launch_bounds__(256, 2)
void k_gemm2(const unsigned short* __restrict__ Zh, const unsigned short* __restrict__ Zm,
             const unsigned short* __restrict__ Bh, const unsigned short* __restrict__ Bm,
             float* __restrict__ G) {
    // tile rows: 64 ushorts = 128B = 8 x 16B units; units 0-3 = h plane (k 0..31),
    // units 4-7 = m plane. Swizzle: physical_unit = logical_unit ^ (row & 7).
    __shared__ unsigned short lds[2 * 16384];   // 2 buffers x (A tile 8192 + B tile 8192)

    const int bid  = blockIdx.x;
    const int xcd  = bid & 7, local = bid >> 3;
    const int mt   = xcd * 32 + (local >> 3);
    const int nt   = local & 7;
    const int m0   = mt * 128, n0 = nt * 128;
    const int tid  = threadIdx.x;
    const int w    = tid >> 6, l = tid & 63;
    const int wr   = (w >> 1) * 64;   // wave tile origin (rows)
    const int wc   = (w & 1) * 64;    // wave tile origin (cols)

    // per-thread staging sources (8 instrs: 4 A-tile, 4 B-tile)
    const unsigned short* gsrc[8];
    int ldsoff[8];
    #pragma unroll
    for (int i = 0; i < 8; ++i) {
        const int q    = i & 3;
        const int row  = q * 32 + w * 8 + (l >> 3);
        const int sg   = (l & 7) ^ (row & 7);          // logical unit fetched
        const int pl   = sg >> 2;                       // 0=h, 1=m
        const int koff = (sg & 3) * 8;                  // bf16 elems within plane chunk
        if (i < 4)
            gsrc[i] = (pl ? Zm : Zh) + (size_t)(m0 + row) * ED + koff;
        else
            gsrc[i] = (pl ? Bm : Bh) + (size_t)(n0 + row) * BSTRIDE + koff;
        ldsoff[i] = (i >= 4 ? 8192 : 0) + q * 2048 + w * 512 + l * 8;
    }

    f32x4 acc[4][4];
    #pragma unroll
    for (int i = 0; i < 4; ++i)
        #pragma unroll
        for (int j = 0; j < 4; ++j) acc[i][j] = (f32x4){0.f, 0.f, 0.f, 0.f};

    #define STAGE(buf, t) { \
        const int bb = (buf) * 16384; \
        const int kk = (t) * 32;      \
        _Pragma("unroll") \
        for (int i = 0; i < 8; ++i) \
            __builtin_amdgcn_global_load_lds( \
                (const __attribute__((address_space(1))) unsigned int*)(const void*)(gsrc[i] + kk), \
                (__attribute__((address_space(3))) unsigned int*)(void*)&lds[bb + ldsoff[i]], \
                16, 0, 0); \
    }

    STAGE(0, 0);
    __syncthreads();

    const int lrow = l & 15;   // row/col within fragment
    const int lu   = l >> 4;   // 16B unit index (0..3) within plane

    for (int t = 0; t < NCHUNK; ++t) {
        if (t + 1 < NCHUNK) STAGE((t + 1) & 1, t + 1);

        const unsigned short* At = &lds[(t & 1) * 16384];
        const unsigned short* Bt = At + 8192;

        bf16x8 ah[4], am[4], bh[4], bm[4];
        #pragma unroll
        for (int f = 0; f < 4; ++f) {
            const int row = wr + f * 16 + lrow;
            const int uh  = (0 + lu) ^ (row & 7);
            const int um  = (4 + lu) ^ (row & 7);
            ah[f] = *(const bf16x8*)(At + row * 64 + uh * 8);
            am[f] = *(const bf16x8*)(At + row * 64 + um * 8);
        }
        #pragma unroll
        for (int f = 0; f < 4; ++f) {
            const int col = wc + f * 16 + lrow;
            const int uh  = (0 + lu) ^ (col & 7);
            const int um  = (4 + lu) ^ (col & 7);
            bh[f] = *(const bf16x8*)(Bt + col * 64 + uh * 8);
            bm[f] = *(const bf16x8*)(Bt + col * 64 + um * 8);
        }
        #pragma unroll
        for (int fm = 0; fm < 4; ++fm)
            #pragma unroll
            for (int fn = 0; fn < 4; ++fn) {
                acc[fm][fn] = __builtin_amdgcn_mfma_f32_16x16x32_bf16(ah[fm], bh[fn], acc[fm][fn], 0, 0, 0);
                acc[fm][fn] = __builtin_amdgcn_mfma_f32_16x16x32_bf16(ah[fm], bm[fn], acc[fm][fn], 0, 0, 0);
                acc[fm][fn] = __builtin_amdgcn_mfma_f32_16x16x32_bf16(am[fm], bh[fn], acc[fm][fn], 0, 0, 0);
            }
        __syncthreads();
    }
    #undef STAGE

    // C layout: col = lane&15, row = (lane>>4)*4 + reg
    #pragma unroll
    for (int fm = 0; fm < 4; ++fm)
        #pragma unroll
        for (int fn = 0; fn < 4; ++fn) {
            const int col = n0 + wc + fn * 16 + lrow;
            #pragma unroll
            for (int r = 0; r < 4; ++r) {
                const int row = m0 + wr + fm * 16 + lu * 4 + r;
                G[(size_t)row * NC + col] = acc[fm][fn][r];
            }
        }
}

// ---- K-post: dist assembly + argmin + softmax + avg_prob partials (reads G) ----
__global__ __launch_bounds__(512)
void k_post(const float* __restrict__ G, const float* __restrict__ bsq,
            const float* __restrict__ zsq, float* __restrict__ A,
            float* __restrict__ wgpart, int* __restrict__ idxws,
            float* __restrict__ out) {
    const int bid = blockIdx.x;
    const int wr0 = bid * 32;
    const int t   = threadIdx.x;
    const int cg  = t & 127;
    const int rq  = t >> 7;
    const int r0  = rq * 8;
    const int c0  = cg * 4;
    const int c1  = 512 + cg * 4;

    __shared__ float sm[9280];
    float* red_v    = sm;                 // [32][128]
    int*   red_i    = (int*)(sm + 4096);  // [32][128]
    float* row_dmin = sm + 8192;          // [32]
    float* row_s    = sm + 8224;          // [32]
    float* pc       = sm + 8256;          // [1024]

    float acc[8][8];
    #pragma unroll
    for (int i = 0; i < 8; ++i) {
        const float4 g0 = *(const float4*)&G[(size_t)(wr0 + r0 + i) * NC + c0];
        const float4 g1 = *(const float4*)&G[(size_t)(wr0 + r0 + i) * NC + c1];
        acc[i][0] = g0.x; acc[i][1] = g0.y; acc[i][2] = g0.z; acc[i][3] = g0.w;
        acc[i][4] = g1.x; acc[i][5] = g1.y; acc[i][6] = g1.z; acc[i][7] = g1.w;
    }

    float bsqv[8], zsqv[8];
    #pragma unroll
    for (int j = 0; j < 4; ++j) { bsqv[j] = bsq[c0 + j]; bsqv[4 + j] = bsq[c1 + j]; }
    #pragma unroll
    for (int i = 0; i < 8; ++i) zsqv[i] = zsq[wr0 + r0 + i];

    #pragma unroll
    for (int i = 0; i < 8; ++i)
        #pragma unroll
        for (int j = 0; j < 8; ++j) {
            const float tv = zsqv[i] - 2.f * acc[i][j];
            acc[i][j] = tv + bsqv[j];
        }

    #pragma unroll
    for (int i = 0; i < 8; ++i) {
        float bv = acc[i][0]; int bi = c0;
        #pragma unroll
        for (int j = 1; j < 8; ++j) {
            const int c = (j < 4) ? (c0 + j) : (c1 + (j - 4));
            if (acc[i][j] < bv || (acc[i][j] == bv && c < bi)) { bv = acc[i][j]; bi = c; }
        }
        red_v[(r0 + i) * 128 + cg] = bv;
        red_i[(r0 + i) * 128 + cg] = bi;
    }
    __syncthreads();
    if (t < 32) {
        float bv = red_v[t * 128]; int bi = red_i[t * 128];
        for (int x = 1; x < 128; ++x) {
            const float v = red_v[t * 128 + x];
            const int  iv = red_i[t * 128 + x];
            if (v < bv || (v == bv && iv < bi)) { bv = v; bi = iv; }
        }
        row_dmin[t] = bv;
        idxws[wr0 + t] = bi;
        out[IDX_OFF + wr0 + t] = (float)bi;
    }
    __syncthreads();

    float su[8];
    #pragma unroll
    for (int i = 0; i < 8; ++i) {
        const float dm = row_dmin[r0 + i];
        float s = 0.f;
        #pragma unroll
        for (int j = 0; j < 8; ++j) {
            const float u = expf(dm - acc[i][j]);
            acc[i][j] = u;
            s += u;
        }
        su[i] = s;
    }
    #pragma unroll
    for (int i = 0; i < 8; ++i) red_v[(r0 + i) * 128 + cg] = su[i];
    __syncthreads();
    if (t < 32) {
        float s = 0.f;
        for (int x = 0; x < 128; ++x) s += red_v[t * 128 + x];
        row_s[t] = s;
    }
    __syncthreads();

    float rcp[8];
    #pragma unroll
    for (int i = 0; i < 8; ++i) rcp[i] = 1.f / row_s[r0 + i];

    pc[t] = 0.f; pc[t + 512] = 0.f;
    __syncthreads();
    #pragma unroll
    for (int j = 0; j < 8; ++j) {
        const int c = (j < 4) ? (c0 + j) : (c1 + (j - 4));
        float s = 0.f;
        #pragma unroll
        for (int i = 0; i < 8; ++i) s += acc[i][j] * rcp[i];
        atomicAdd(&pc[c], s);
    }
    __syncthreads();
    atomicAdd(&A[t],       pc[t]);
    atomicAdd(&A[t + 512], pc[t + 512]);

    if (t == 0) {
        float s = 0.f;
        for (int r = 0; r < 32; ++r) s += row_dmin[r];
        wgpart[bid] = s;
    }
}

// ---- finalize scalars ----
__global__ void k_final(const float* __restrict__ wgpart, const float* __restrict__ A,
                        float* __restrict__ out) {
    __shared__ double sd[1024];
    const int t = threadIdx.x;
    sd[t] = (double)wgpart[t];
    __syncthreads();
    for (int off = 512; off > 0; off >>= 1) {
        if (t < off) sd[t] += sd[t + off];
        __syncthreads();
    }
    if (t == 0) out[VQ_OFF] = (float)(0.25 * sd[0] / 88473600.0);
    __syncthreads();
    const double p = (double)A[t] * (1.0 / 32768.0);
    sd[t] = -p * log(p + 1e-8);
    __syncthreads();
    for (int off = 512; off > 0; off >>= 1) {
        if (t < off) sd[t] += sd[t + off];
        __syncthreads();
    }
    if (t == 0) out[ENT_OFF] = (float)sd[0];
}

// ---- q_st = basis[indices] ----
__global__ void k_gather(const float* __restrict__ basis, const int* __restrict__ idxws,
                         float* __restrict__ out) {
    const int r = blockIdx.x;
    const int idx = idxws[r];
    const float4* src = (const float4*)(basis + (size_t)idx * ED);
    float4* dst = (float4*)(out + (size_t)r * ED);
    for (int j = threadIdx.x; j < ED / 4; j += 256) dst[j] = src[j];
}

// =====================================================================
// ===================== FALLBACK (round-2, f32 VALU) ==================
// =====================================================================

__global__ void k_bsq(const float* __restrict__ basis, float* __restrict__ bsq) {
    int c = blockIdx.x;
    const float* row = basis + (size_t)c * ED;
    double s = 0.0;
    for (int j = threadIdx.x; j < ED; j += 256) { float v = row[j]; s += (double)v * (double)v; }
    __shared__ double sd[256];
    sd[threadIdx.x] = s;
    __syncthreads();
    for (int off = 128; off > 0; off >>= 1) {
        if (threadIdx.x < off) sd[threadIdx.x] += sd[threadIdx.x + off];
        __syncthreads();
    }
    if (threadIdx.x == 0) bsq[c] = (float)sd[0];
}

__global__ __launch_bounds__(256, 4)
void k_gemm1(const float* __restrict__ S, const float* __restrict__ W,
             const float* __restrict__ bproj, float* __restrict__ Z) {
    const int e0 = blockIdx.x * 64;
    const int m0 = blockIdx.y * 64;
    const int t  = threadIdx.x;
    const int tx = t & 15, ty = t >> 4;
    __shared__ float alds[32 * 68];
    __shared__ float blds[32 * 68];
    float acc[4][4] = {};
    for (int k0 = 0; k0 < DM; k0 += 32) {
        #pragma unroll
        for (int rep = 0; rep < 2; ++rep) {
            const int id  = t + rep * 256;
            const int row = id >> 3, kq = id & 7;
            const float4 va = *(const float4*)(S + (size_t)(m0 + row) * DM + k0 + 4 * kq);
            alds[(4*kq+0)*68 + row] = va.x;
            alds[(4*kq+1)*68 + row] = va.y;
            alds[(4*kq+2)*68 + row] = va.z;
            alds[(4*kq+3)*68 + row] = va.w;
            float4 vb = make_float4(0.f, 0.f, 0.f, 0.f);
            if (e0 + row < ED)
                vb = *(const float4*)(W + (size_t)(e0 + row) * DM + k0 + 4 * kq);
            blds[(4*kq+0)*68 + row] = vb.x;
            blds[(4*kq+1)*68 + row] = vb.y;
            blds[(4*kq+2)*68 + row] = vb.z;
            blds[(4*kq+3)*68 + row] = vb.w;
        }
        __syncthreads();
        #pragma unroll 8
        for (int k = 0; k < 32; ++k) {
            const float4 a = *(const float4*)&alds[k*68 + 4*ty];
            const float4 b = *(const float4*)&blds[k*68 + 4*tx];
            const float av[4] = {a.x, a.y, a.z, a.w};
            const float bv[4] = {b.x, b.y, b.z, b.w};
            #pragma unroll
            for (int i = 0; i < 4; ++i)
                #pragma unroll
                for (int j = 0; j < 4; ++j)
                    acc[i][j] = fmaf(av[i], bv[j], acc[i][j]);
        }
        __syncthreads();
    }
    const bool valid = (e0 + 4*tx + 4) <= ED;
    float4 bias = make_float4(0.f, 0.f, 0.f, 0.f);
    if (valid) bias = *(const float4*)(bproj + e0 + 4*tx);
    #pragma unroll
    for (int i = 0; i < 4; ++i) {
        if (valid) {
            float4 o;
            o.x = acc[i][0] + bias.x;
            o.y = acc[i][1] + bias.y;
            o.z = acc[i][2] + bias.z;
            o.w = acc[i][3] + bias.w;
            *(float4*)(Z + (size_t)(m0 + 4*ty + i) * ED + e0 + 4*tx) = o;
        }
    }
}

__global__ __launch_bounds__(64)
void k_zsq(const float* __restrict__ Z, float* __restrict__ zsq) {
    const int r = blockIdx.x;
    const float4* row4 = (const float4*)(Z + (size_t)r * ED);
    double s = 0.0;
    for (int q = threadIdx.x; q < ED / 4; q += 64) {
        const float4 v = row4[q];
        s += (double)v.x * v.x + (double)v.y * v.y + (double)v.z * v.z + (double)v.w * v.w;
    }
    #pragma unroll
    for (int off = 32; off > 0; off >>= 1) s += __shfl_down(s, off);
    if (threadIdx.x == 0) zsq[r] = (float)s;
}

__global__ __launch_bounds__(512, 2)
void k_dist(const float* __restrict__ Z, const float* __restrict__ basis,
            const float* __restrict__ bsq, const float* __restrict__ zsq,
            float* __restrict__ A, float* __restrict__ wgpart,
            int* __restrict__ idxws, float* __restrict__ out) {
    const int bid = blockIdx.x;
    const int wr0 = bid * 32;
    const int t   = threadIdx.x;
    const int cg  = t & 127;
    const int rq  = t >> 7;
    const int r0  = rq * 8;
    const int c0  = cg * 4;
    const int c1  = 512 + cg * 4;
    __shared__ float blds[16 * 1024];
    __shared__ float zlds[16 * 36];
    float acc[8][8];
    #pragma unroll
    for (int i = 0; i < 8; ++i)
        #pragma unroll
        for (int j = 0; j < 8; ++j) acc[i][j] = 0.f;
    for (int k0 = 0; k0 < ED; k0 += 16) {
        const bool full = (k0 + 16) <= ED;
        #pragma unroll
        for (int rep = 0; rep < 2; ++rep) {
            const int c = t + rep * 512;
            const float* bp = basis + (size_t)c * ED + k0;
            if (full) {
                const float4 v0 = *(const float4*)(bp + 0);
                const float4 v1 = *(const float4*)(bp + 4);
                const float4 v2 = *(const float4*)(bp + 8);
                const float4 v3 = *(const float4*)(bp + 12);
                blds[ 0*1024+c]=v0.x; blds[ 1*1024+c]=v0.y; blds[ 2*1024+c]=v0.z; blds[ 3*1024+c]=v0.w;
                blds[ 4*1024+c]=v1.x; blds[ 5*1024+c]=v1.y; blds[ 6*1024+c]=v1.z; blds[ 7*1024+c]=v1.w;
                blds[ 8*1024+c]=v2.x; blds[ 9*1024+c]=v2.y; blds[10*1024+c]=v2.z; blds[11*1024+c]=v2.w;
                blds[12*1024+c]=v3.x; blds[13*1024+c]=v3.y; blds[14*1024+c]=v3.z; blds[15*1024+c]=v3.w;
            } else {
                for (int kk = 0; kk < 16; ++kk)
                    blds[kk*1024 + c] = (k0 + kk < ED) ? bp[kk] : 0.f;
            }
        }
        if (t < 128) {
            const int row = t >> 2, kq = t & 3;
            const float* zp = Z + (size_t)(wr0 + row) * ED + k0 + 4 * kq;
            if (full) {
                const float4 v = *(const float4*)zp;
                zlds[(4*kq+0)*36 + row] = v.x;
                zlds[(4*kq+1)*36 + row] = v.y;
                zlds[(4*kq+2)*36 + row] = v.z;
                zlds[(4*kq+3)*36 + row] = v.w;
            } else {
                for (int j = 0; j < 4; ++j) {
                    const int k = k0 + 4*kq + j;
                    zlds[(4*kq+j)*36 + row] = (k < ED) ? zp[j] : 0.f;
                }
            }
        }
        __syncthreads();
        #pragma unroll
        for (int k = 0; k < 16; ++k) {
            const float4 z0 = *(const float4*)&zlds[k*36 + r0];
            const float4 z1 = *(const float4*)&zlds[k*36 + r0 + 4];
            const float4 b0 = *(const float4*)&blds[k*1024 + c0];
            const float4 b1 = *(const float4*)&blds[k*1024 + c1];
            const float zz[8] = {z0.x, z0.y, z0.z, z0.w, z1.x, z1.y, z1.z, z1.w};
            const float bb[8] = {b0.x, b0.y, b0.z, b0.w, b1.x, b1.y, b1.z, b1.w};
            #pragma unroll
            for (int i = 0; i < 8; ++i)
                #pragma unroll
                for (int j = 0; j < 8; ++j)
                    acc[i][j] = fmaf(zz[i], bb[j], acc[i][j]);
        }
        __syncthreads();
    }
    float* red_v    = blds;
    int*   red_i    = (int*)(blds + 4096);
    float* row_dmin = blds + 8192;
    float* row_s    = blds + 8224;
    float* pc       = blds + 8256;
    float bsqv[8], zsqv[8];
    #pragma unroll
    for (int j = 0; j < 4; ++j) { bsqv[j] = bsq[c0 + j]; bsqv[4 + j] = bsq[c1 + j]; }
    #pragma unroll
    for (int i = 0; i < 8; ++i) zsqv[i] = zsq[wr0 + r0 + i];
    #pragma unroll
    for (int i = 0; i < 8; ++i)
        #pragma unroll
        for (int j = 0; j < 8; ++j) {
            const float tv = zsqv[i] - 2.f * acc[i][j];
            acc[i][j] = tv + bsqv[j];
        }
    #pragma unroll
    for (int i = 0; i < 8; ++i) {
        float bv = acc[i][0]; int bi = c0;
        #pragma unroll
        for (int j = 1; j < 8; ++j) {
            const int c = (j < 4) ? (c0 + j) : (c1 + (j - 4));
            if (acc[i][j] < bv || (acc[i][j] == bv && c < bi)) { bv = acc[i][j]; bi = c; }
        }
        red_v[(r0 + i) * 128 + cg] = bv;
        red_i[(r0 + i) * 128 + cg] = bi;
    }
    __syncthreads();
    if (t < 32) {
        float bv = red_v[t * 128]; int bi = red_i[t * 128];
        for (int x = 1; x < 128; ++x) {
            const float v = red_v[t * 128 + x];
            const int  iv = red_i[t * 128 + x];
            if (v < bv || (v == bv && iv < bi)) { bv = v; bi = iv; }
        }
        row_dmin[t] = bv;
        idxws[wr0 + t] = bi;
        out[IDX_OFF + wr0 + t] = (float)bi;
    }
    __syncthreads();
    float su[8];
    #pragma unroll
    for (int i = 0; i < 8; ++i) {
        const float dm = row_dmin[r0 + i];
        float s = 0.f;
        #pragma unroll
        for (int j = 0; j < 8; ++j) {
            const float u = expf(dm - acc[i][j]);
            acc[i][j] = u;
            s += u;
        }
        su[i] = s;
    }
    #pragma unroll
    for (int i = 0; i < 8; ++i) red_v[(r0 + i) * 128 + cg] = su[i];
    __syncthreads();
    if (t < 32) {
        float s = 0.f;
        for (int x = 0; x < 128; ++x) s += red_v[t * 128 + x];
        row_s[t] = s;
    }
    __syncthreads();
    float rcp[8];
    #pragma unroll
    for (int i = 0; i < 8; ++i) rcp[i] = 1.f / row_s[r0 + i];
    pc[t] = 0.f; pc[t + 512] = 0.f;
    __syncthreads();
    #pragma unroll
    for (int j = 0; j < 8; ++j) {
        const int c = (j < 4) ? (c0 + j) : (c1 + (j - 4));
        float s = 0.f;
        #pragma unroll
        for (int i = 0; i < 8; ++i) s += acc[i][j] * rcp[i];
        atomicAdd(&pc[c], s);
    }
    __syncthreads();
    atomicAdd(&A[t],       pc[t]);
    atomicAdd(&A[t + 512], pc[t + 512]);
    if (t == 0) {
        float s = 0.f;
        for (int r = 0; r < 32; ++r) s += row_dmin[r];
        wgpart[bid] = s;
    }
}

// =====================================================================

extern "C" void kernel_launch(void* const* d_in, const int* in_sizes, int n_in,
                              void* d_out, int out_size, void* d_ws, size_t ws_size,
                              hipStream_t stream) {
    const float* S     = (const float*)d_in[0];  // [32768, 256]
    const float* W     = (const float*)d_in[1];  // [2700, 256]
    const float* bproj = (const float*)d_in[2];  // [2700]
    const float* basis = (const float*)d_in[3];  // [1024, 2700]
    float* out = (float*)d_out;
    float* ws  = (float*)d_ws;

    // common small regions
    float* zsq    = ws;                  // 32768
    float* A      = ws + 32768;          // 1024
    float* bsq    = ws + 33792;          // 1024
    float* wgpart = ws + 34816;          // 1024
    int*   idxws  = (int*)(ws + 35840);  // 32768

    const size_t NEED = (size_t)37817344 * sizeof(float);   // ~151 MB
    if (ws_size >= NEED) {
        // -------- MFMA path --------
        float*          zsqpart = ws + 68608;                       // 43*32768
        unsigned short* Bh      = (unsigned short*)(ws + 1477632);  // 1024*2720 ush
        unsigned short* Bm      = (unsigned short*)(ws + 2870272);
        float*          G       = ws + 4262912;                     // 32768*1024
        unsigned short* Zh      = (unsigned short*)out;             // planes live in q_st region
        unsigned short* Zm      = Zh + (size_t)BKROWS * ED;

        hipMemsetAsync(A, 0, (size_t)NC * sizeof(float), stream);
        k_packB <<<NC, 256, 0, stream>>>(basis, Bh, Bm, bsq);
        k_gemm1p<<<dim3(43, 512), 256, 0, stream>>>(S, W, bproj, Zh, Zm, zsqpart);
        k_zsqred<<<BKROWS / 256, 256, 0, stream>>>(zsqpart, zsq);
        k_gemm2 <<<2048, 256, 0, stream>>>(Zh, Zm, Bh, Bm, G);
        k_post  <<<BKROWS / 32, 512, 0, stream>>>(G, bsq, zsq, A, wgpart, idxws, out);
        k_final <<<1, 1024, 0, stream>>>(wgpart, A, out);
        k_gather<<<BKROWS, 256, 0, stream>>>(basis, idxws, out);
    } else {
        // -------- fallback: round-2 f32 path --------
        float* Z = out;
        hipMemsetAsync(A, 0, (size_t)NC * sizeof(float), stream);
        k_bsq   <<<NC, 256, 0, stream>>>(basis, bsq);
        k_gemm1 <<<dim3(43, 512), 256, 0, stream>>>(S, W, bproj, Z);
        k_zsq   <<<BKROWS, 64, 0, stream>>>(Z, zsq);
        k_dist  <<<BKROWS / 32, 512, 0, stream>>>(Z, basis, bsq, zsq, A, wgpart, idxws, out);
        k_final <<<1, 1024, 0, stream>>>(wgpart, A, out);
        k_gather<<<BKROWS, 256, 0, stream>>>(basis, idxws, out);
    }
}

// Round 4
// 1158.737 us; speedup vs baseline: 8.4498x; 1.2895x over previous
//
#include <hip/hip_runtime.h>
#include <math.h>

#define ED 2700     // basis_dim
#define NC 1024     // num_codes
#define DM 256      // d_model
#define BKROWS 32768

#define IDX_OFF 88473600
#define VQ_OFF  88506368
#define ENT_OFF 88506369

#define BSTRIDE 2720        // padded k-stride for basis planes (zero tail)
#define NCHUNK 85           // ceil(2700/32)
#define WPAD 2816           // padded e-rows for W planes (22 tiles of 128)
#define NT1 22              // N-tiles in gemm1

typedef float  f32x4  __attribute__((ext_vector_type(4)));
typedef short  bf16x8 __attribute__((ext_vector_type(8)));

__device__ inline unsigned short f2bf(float x) {
    unsigned int u = __float_as_uint(x);
    unsigned int r = (u + 0x7FFFu + ((u >> 16) & 1u)) >> 16;
    return (unsigned short)r;
}
__device__ inline float bf2f(unsigned short h) {
    return __uint_as_float(((unsigned int)h) << 16);
}

// =====================================================================
// ============================ MFMA PATH ==============================
// =====================================================================

// ---- packs S -> Sh/Sm planes ----
__global__ __launch_bounds__(256)
void k_packS(const float* __restrict__ S, unsigned short* __restrict__ Sh,
             unsigned short* __restrict__ Sm) {
    const size_t i4 = (size_t)blockIdx.x * 256 + threadIdx.x;   // float4 index
    const float4 v = *(const float4*)(S + i4 * 4);
    ushort4 hv, mv;
    unsigned short* hp = (unsigned short*)&hv;
    unsigned short* mp = (unsigned short*)&mv;
    const float xs[4] = {v.x, v.y, v.z, v.w};
    #pragma unroll
    for (int j = 0; j < 4; ++j) {
        const unsigned short h = f2bf(xs[j]);
        hp[j] = h;
        mp[j] = f2bf(xs[j] - bf2f(h));
    }
    *(ushort4*)(Sh + i4 * 4) = hv;
    *(ushort4*)(Sm + i4 * 4) = mv;
}

// ---- packs W -> Wh/Wm planes, padded to WPAD rows (zeros) ----
__global__ __launch_bounds__(256)
void k_packW(const float* __restrict__ W, unsigned short* __restrict__ Wh,
             unsigned short* __restrict__ Wm) {
    const size_t i4 = (size_t)blockIdx.x * 256 + threadIdx.x;   // float4 index
    const size_t row = (i4 * 4) / DM;
    float4 v = make_float4(0.f, 0.f, 0.f, 0.f);
    if (row < ED) v = *(const float4*)(W + i4 * 4);
    ushort4 hv, mv;
    unsigned short* hp = (unsigned short*)&hv;
    unsigned short* mp = (unsigned short*)&mv;
    const float xs[4] = {v.x, v.y, v.z, v.w};
    #pragma unroll
    for (int j = 0; j < 4; ++j) {
        const unsigned short h = f2bf(xs[j]);
        hp[j] = h;
        mp[j] = f2bf(xs[j] - bf2f(h));
    }
    *(ushort4*)(Wh + i4 * 4) = hv;
    *(ushort4*)(Wm + i4 * 4) = mv;
}

// ---- basis -> Bh/Bm bf16 planes (stride 2720, zero pad) + bsq (f64) ----
__global__ void k_packB(const float* __restrict__ basis, unsigned short* __restrict__ Bh,
                        unsigned short* __restrict__ Bm, float* __restrict__ bsq) {
    const int c = blockIdx.x;
    const int t = threadIdx.x;
    const float* row = basis + (size_t)c * ED;
    double s = 0.0;
    for (int j = t; j < ED; j += 256) {
        const float x = row[j];
        s += (double)x * (double)x;
        const unsigned short h = f2bf(x);
        Bh[(size_t)c * BSTRIDE + j] = h;
        Bm[(size_t)c * BSTRIDE + j] = f2bf(x - bf2f(h));
    }
    if (t < BSTRIDE - ED) {
        Bh[(size_t)c * BSTRIDE + ED + t] = 0;
        Bm[(size_t)c * BSTRIDE + ED + t] = 0;
    }
    __shared__ double sd[256];
    sd[t] = s;
    __syncthreads();
    for (int off = 128; off > 0; off >>= 1) {
        if (t < off) sd[t] += sd[t + off];
        __syncthreads();
    }
    if (t == 0) bsq[c] = (float)sd[0];
}

// ---- K1m: Z = S@W^T + b via split-bf16 MFMA; emits Zh/Zm planes + zsq partials ----
__global__ __launch_bounds__(256, 2)
void k_gemm1m(const unsigned short* __restrict__ Sh, const unsigned short* __restrict__ Sm,
              const unsigned short* __restrict__ Wh, const unsigned short* __restrict__ Wm,
              const float* __restrict__ bproj, unsigned short* __restrict__ Zh,
              unsigned short* __restrict__ Zm, float* __restrict__ zsqpart) {
    __shared__ unsigned short lds[2 * 16384];

    const int bid  = blockIdx.x;
    const int mt   = bid / NT1;
    const int nt   = bid % NT1;
    const int m0   = mt * 128, n0 = nt * 128;
    const int tid  = threadIdx.x;
    const int w    = tid >> 6, l = tid & 63;
    const int wr   = (w >> 1) * 64;
    const int wc   = (w & 1) * 64;

    const unsigned short* gsrc[8];
    int ldsoff[8];
    #pragma unroll
    for (int i = 0; i < 8; ++i) {
        const int q    = i & 3;
        const int row  = q * 32 + w * 8 + (l >> 3);
        const int sg   = (l & 7) ^ (row & 7);
        const int pl   = sg >> 2;
        const int koff = (sg & 3) * 8;
        if (i < 4)
            gsrc[i] = (pl ? Sm : Sh) + (size_t)(m0 + row) * DM + koff;
        else
            gsrc[i] = (pl ? Wm : Wh) + (size_t)(n0 + row) * DM + koff;
        ldsoff[i] = (i >= 4 ? 8192 : 0) + q * 2048 + w * 512 + l * 8;
    }

    f32x4 acc[4][4];
    #pragma unroll
    for (int i = 0; i < 4; ++i)
        #pragma unroll
        for (int j = 0; j < 4; ++j) acc[i][j] = (f32x4){0.f, 0.f, 0.f, 0.f};

    #define STAGE1(buf, t) { \
        const int bb = (buf) * 16384; \
        const int kk = (t) * 32;      \
        _Pragma("unroll") \
        for (int i = 0; i < 8; ++i) \
            __builtin_amdgcn_global_load_lds( \
                (const __attribute__((address_space(1))) unsigned int*)(const void*)(gsrc[i] + kk), \
                (__attribute__((address_space(3))) unsigned int*)(void*)&lds[bb + ldsoff[i]], \
                16, 0, 0); \
    }

    STAGE1(0, 0);
    __syncthreads();

    const int lrow = l & 15;
    const int lu   = l >> 4;

    for (int t = 0; t < 8; ++t) {
        if (t + 1 < 8) STAGE1((t + 1) & 1, t + 1);

        const unsigned short* At = &lds[(t & 1) * 16384];
        const unsigned short* Bt = At + 8192;

        bf16x8 ah[4], am[4], bh[4], bm[4];
        #pragma unroll
        for (int f = 0; f < 4; ++f) {
            const int row = wr + f * 16 + lrow;
            const int uh  = (0 + lu) ^ (row & 7);
            const int um  = (4 + lu) ^ (row & 7);
            ah[f] = *(const bf16x8*)(At + row * 64 + uh * 8);
            am[f] = *(const bf16x8*)(At + row * 64 + um * 8);
        }
        #pragma unroll
        for (int f = 0; f < 4; ++f) {
            const int col = wc + f * 16 + lrow;
            const int uh  = (0 + lu) ^ (col & 7);
            const int um  = (4 + lu) ^ (col & 7);
            bh[f] = *(const bf16x8*)(Bt + col * 64 + uh * 8);
            bm[f] = *(const bf16x8*)(Bt + col * 64 + um * 8);
        }
        #pragma unroll
        for (int fm = 0; fm < 4; ++fm)
            #pragma unroll
            for (int fn = 0; fn < 4; ++fn) {
                acc[fm][fn] = __builtin_amdgcn_mfma_f32_16x16x32_bf16(ah[fm], bh[fn], acc[fm][fn], 0, 0, 0);
                acc[fm][fn] = __builtin_amdgcn_mfma_f32_16x16x32_bf16(ah[fm], bm[fn], acc[fm][fn], 0, 0, 0);
                acc[fm][fn] = __builtin_amdgcn_mfma_f32_16x16x32_bf16(am[fm], bh[fn], acc[fm][fn], 0, 0, 0);
            }
        __syncthreads();
    }
    #undef STAGE1

    // ---- epilogue: bias, split to planes, deterministic zsq partials ----
    float* rowsum = (float*)lds;   // [2][128], safe after final barrier
    if (tid < 256) rowsum[tid] = 0.f;
    __syncthreads();

    float bias_v[4]; int colv[4]; bool cok[4];
    #pragma unroll
    for (int fn = 0; fn < 4; ++fn) {
        const int col = n0 + wc + fn * 16 + lrow;
        colv[fn] = col;
        cok[fn]  = (col < ED);
        bias_v[fn] = cok[fn] ? bproj[col] : 0.f;
    }
    #pragma unroll
    for (int fm = 0; fm < 4; ++fm) {
        #pragma unroll
        for (int r = 0; r < 4; ++r) {
            const int lrowid = wr + fm * 16 + lu * 4 + r;   // row within tile
            const int grow   = m0 + lrowid;                  // global row
            float z2 = 0.f;
            #pragma unroll
            for (int fn = 0; fn < 4; ++fn) {
                if (cok[fn]) {
                    const float zv = acc[fm][fn][r] + bias_v[fn];
                    const unsigned short h  = f2bf(zv);
                    const unsigned short ml = f2bf(zv - bf2f(h));
                    Zh[(size_t)grow * ED + colv[fn]] = h;
                    Zm[(size_t)grow * ED + colv[fn]] = ml;
                    z2 += zv * zv;
                }
            }
            #pragma unroll
            for (int off = 8; off > 0; off >>= 1) z2 += __shfl_xor(z2, off, 16);
            if ((l & 15) == 0) rowsum[(w & 1) * 128 + lrowid] = z2;
        }
    }
    __syncthreads();
    if (tid < 128)
        zsqpart[(size_t)nt * BKROWS + m0 + tid] = rowsum[tid] + rowsum[128 + tid];
}

// ---- zsq[r] = sum over NT1 partials (f64, deterministic) ----
__global__ void k_zsqred(const float* __restrict__ part, float* __restrict__ zsq) {
    const int r = blockIdx.x * 256 + threadIdx.x;
    double s = 0.0;
    #pragma unroll
    for (int b = 0; b < NT1; ++b) s += (double)part[(size_t)b * BKROWS + r];
    zsq[r] = (float)s;
}

// ---- K2m: G = Z.B^T via 3-product split-bf16 MFMA, 128x128 tile ----
__global__ __launch_bounds__(256, 2)
void k_gemm2(const unsigned short* __restrict__ Zh, const unsigned short* __restrict__ Zm,
             const unsigned short* __restrict__ Bh, const unsigned short* __restrict__ Bm,
             float* __restrict__ G) {
    __shared__ unsigned short lds[2 * 16384];

    const int bid  = blockIdx.x;
    const int xcd  = bid & 7, local = bid >> 3;
    const int mt   = xcd * 32 + (local >> 3);
    const int nt   = local & 7;
    const int m0   = mt * 128, n0 = nt * 128;
    const int tid  = threadIdx.x;
    const int w    = tid >> 6, l = tid & 63;
    const int wr   = (w >> 1) * 64;
    const int wc   = (w & 1) * 64;

    const unsigned short* gsrc[8];
    int ldsoff[8];
    #pragma unroll
    for (int i = 0; i < 8; ++i) {
        const int q    = i & 3;
        const int row  = q * 32 + w * 8 + (l >> 3);
        const int sg   = (l & 7) ^ (row & 7);
        const int pl   = sg >> 2;
        const int koff = (sg & 3) * 8;
        if (i < 4)
            gsrc[i] = (pl ? Zm : Zh) + (size_t)(m0 + row) * ED + koff;
        else
            gsrc[i] = (pl ? Bm : Bh) + (size_t)(n0 + row) * BSTRIDE + koff;
        ldsoff[i] = (i >= 4 ? 8192 : 0) + q * 2048 + w * 512 + l * 8;
    }

    f32x4 acc[4][4];
    #pragma unroll
    for (int i = 0; i < 4; ++i)
        #pragma unroll
        for (int j = 0; j < 4; ++j) acc[i][j] = (f32x4){0.f, 0.f, 0.f, 0.f};

    #define STAGE(buf, t) { \
        const int bb = (buf) * 16384; \
        const int kk = (t) * 32;      \
        _Pragma("unroll") \
        for (int i = 0; i < 8; ++i) \
            __builtin_amdgcn_global_load_lds( \
                (const __attribute__((address_space(1))) unsigned int*)(const void*)(gsrc[i] + kk), \
                (__attribute__((address_space(3))) unsigned int*)(void*)&lds[bb + ldsoff[i]], \
                16, 0, 0); \
    }

    STAGE(0, 0);
    __syncthreads();

    const int lrow = l & 15;
    const int lu   = l >> 4;

    for (int t = 0; t < NCHUNK; ++t) {
        if (t + 1 < NCHUNK) STAGE((t + 1) & 1, t + 1);

        const unsigned short* At = &lds[(t & 1) * 16384];
        const unsigned short* Bt = At + 8192;

        bf16x8 ah[4], am[4], bh[4], bm[4];
        #pragma unroll
        for (int f = 0; f < 4; ++f) {
            const int row = wr + f * 16 + lrow;
            const int uh  = (0 + lu) ^ (row & 7);
            const int um  = (4 + lu) ^ (row & 7);
            ah[f] = *(const bf16x8*)(At + row * 64 + uh * 8);
            am[f] = *(const bf16x8*)(At + row * 64 + um * 8);
        }
        #pragma unroll
        for (int f = 0; f < 4; ++f) {
            const int col = wc + f * 16 + lrow;
            const int uh  = (0 + lu) ^ (col & 7);
            const int um  = (4 + lu) ^ (col & 7);
            bh[f] = *(const bf16x8*)(Bt + col * 64 + uh * 8);
            bm[f] = *(const bf16x8*)(Bt + col * 64 + um * 8);
        }
        #pragma unroll
        for (int fm = 0; fm < 4; ++fm)
            #pragma unroll
            for (int fn = 0; fn < 4; ++fn) {
                acc[fm][fn] = __builtin_amdgcn_mfma_f32_16x16x32_bf16(ah[fm], bh[fn], acc[fm][fn], 0, 0, 0);
                acc[fm][fn] = __builtin_amdgcn_mfma_f32_16x16x32_bf16(ah[fm], bm[fn], acc[fm][fn], 0, 0, 0);
                acc[fm][fn] = __builtin_amdgcn_mfma_f32_16x16x32_bf16(am[fm], bh[fn], acc[fm][fn], 0, 0, 0);
            }
        __syncthreads();
    }
    #undef STAGE

    #pragma unroll
    for (int fm = 0; fm < 4; ++fm)
        #pragma unroll
        for (int fn = 0; fn < 4; ++fn) {
            const int col = n0 + wc + fn * 16 + lrow;
            #pragma unroll
            for (int r = 0; r < 4; ++r) {
                const int row = m0 + wr + fm * 16 + lu * 4 + r;
                G[(size_t)row * NC + col] = acc[fm][fn][r];
            }
        }
}

// ---- K-post: dist assembly + argmin + softmax + avg_prob partials ----
__global__ __launch_bounds__(512)
void k_post(const float* __restrict__ G, const float* __restrict__ bsq,
            const float* __restrict__ zsq, float* __restrict__ A,
            float* __restrict__ wgpart, int* __restrict__ idxws,
            float* __restrict__ out) {
    const int bid = blockIdx.x;
    const int wr0 = bid * 32;
    const int t   = threadIdx.x;
    const int cg  = t & 127;
    const int rq  = t >> 7;
    const int r0  = rq * 8;
    const int c0  = cg * 4;
    const int c1  = 512 + cg * 4;

    __shared__ float sm[9280];
    float* red_v    = sm;
    int*   red_i    = (int*)(sm + 4096);
    float* row_dmin = sm + 8192;
    float* row_s    = sm + 8224;
    float* pc       = sm + 8256;

    float acc[8][8];
    #pragma unroll
    for (int i = 0; i < 8; ++i) {
        const float4 g0 = *(const float4*)&G[(size_t)(wr0 + r0 + i) * NC + c0];
        const float4 g1 = *(const float4*)&G[(size_t)(wr0 + r0 + i) * NC + c1];
        acc[i][0] = g0.x; acc[i][1] = g0.y; acc[i][2] = g0.z; acc[i][3] = g0.w;
        acc[i][4] = g1.x; acc[i][5] = g1.y; acc[i][6] = g1.z; acc[i][7] = g1.w;
    }

    float bsqv[8], zsqv[8];
    #pragma unroll
    for (int j = 0; j < 4; ++j) { bsqv[j] = bsq[c0 + j]; bsqv[4 + j] = bsq[c1 + j]; }
    #pragma unroll
    for (int i = 0; i < 8; ++i) zsqv[i] = zsq[wr0 + r0 + i];

    #pragma unroll
    for (int i = 0; i < 8; ++i)
        #pragma unroll
        for (int j = 0; j < 8; ++j) {
            const float tv = zsqv[i] - 2.f * acc[i][j];
            acc[i][j] = tv + bsqv[j];
        }

    #pragma unroll
    for (int i = 0; i < 8; ++i) {
        float bv = acc[i][0]; int bi = c0;
        #pragma unroll
        for (int j = 1; j < 8; ++j) {
            const int c = (j < 4) ? (c0 + j) : (c1 + (j - 4));
            if (acc[i][j] < bv || (acc[i][j] == bv && c < bi)) { bv = acc[i][j]; bi = c; }
        }
        red_v[(r0 + i) * 128 + cg] = bv;
        red_i[(r0 + i) * 128 + cg] = bi;
    }
    __syncthreads();
    if (t < 32) {
        float bv = red_v[t * 128]; int bi = red_i[t * 128];
        for (int x = 1; x < 128; ++x) {
            const float v = red_v[t * 128 + x];
            const int  iv = red_i[t * 128 + x];
            if (v < bv || (v == bv && iv < bi)) { bv = v; bi = iv; }
        }
        row_dmin[t] = bv;
        idxws[wr0 + t] = bi;
        out[IDX_OFF + wr0 + t] = (float)bi;
    }
    __syncthreads();

    float su[8];
    #pragma unroll
    for (int i = 0; i < 8; ++i) {
        const float dm = row_dmin[r0 + i];
        float s = 0.f;
        #pragma unroll
        for (int j = 0; j < 8; ++j) {
            const float u = expf(dm - acc[i][j]);
            acc[i][j] = u;
            s += u;
        }
        su[i] = s;
    }
    #pragma unroll
    for (int i = 0; i < 8; ++i) red_v[(r0 + i) * 128 + cg] = su[i];
    __syncthreads();
    if (t < 32) {
        float s = 0.f;
        for (int x = 0; x < 128; ++x) s += red_v[t * 128 + x];
        row_s[t] = s;
    }
    __syncthreads();

    float rcp[8];
    #pragma unroll
    for (int i = 0; i < 8; ++i) rcp[i] = 1.f / row_s[r0 + i];

    pc[t] = 0.f; pc[t + 512] = 0.f;
    __syncthreads();
    #pragma unroll
    for (int j = 0; j < 8; ++j) {
        const int c = (j < 4) ? (c0 + j) : (c1 + (j - 4));
        float s = 0.f;
        #pragma unroll
        for (int i = 0; i < 8; ++i) s += acc[i][j] * rcp[i];
        atomicAdd(&pc[c], s);
    }
    __syncthreads();
    atomicAdd(&A[t],       pc[t]);
    atomicAdd(&A[t + 512], pc[t + 512]);

    if (t == 0) {
        float s = 0.f;
        for (int r = 0; r < 32; ++r) s += row_dmin[r];
        wgpart[bid] = s;
    }
}

// ---- finalize scalars ----
__global__ void k_final(const float* __restrict__ wgpart, const float* __restrict__ A,
                        float* __restrict__ out) {
    __shared__ double sd[1024];
    const int t = threadIdx.x;
    sd[t] = (double)wgpart[t];
    __syncthreads();
    for (int off = 512; off > 0; off >>= 1) {
        if (t < off) sd[t] += sd[t + off];
        __syncthreads();
    }
    if (t == 0) out[VQ_OFF] = (float)(0.25 * sd[0] / 88473600.0);
    __syncthreads();
    const double p = (double)A[t] * (1.0 / 32768.0);
    sd[t] = -p * log(p + 1e-8);
    __syncthreads();
    for (int off = 512; off > 0; off >>= 1) {
        if (t < off) sd[t] += sd[t + off];
        __syncthreads();
    }
    if (t == 0) out[ENT_OFF] = (float)sd[0];
}

// ---- q_st = basis[indices] ----
__global__ void k_gather(const float* __restrict__ basis, const int* __restrict__ idxws,
                         float* __restrict__ out) {
    const int r = blockIdx.x;
    const int idx = idxws[r];
    const float4* src = (const float4*)(basis + (size_t)idx * ED);
    float4* dst = (float4*)(out + (size_t)r * ED);
    for (int j = threadIdx.x; j < ED / 4; j += 256) dst[j] = src[j];
}

// =====================================================================
// ===================== FALLBACK (round-2, f32 VALU) ==================
// =====================================================================

__global__ void k_bsq(const float* __restrict__ basis, float* __restrict__ bsq) {
    int c = blockIdx.x;
    const float* row = basis + (size_t)c * ED;
    double s = 0.0;
    for (int j = threadIdx.x; j < ED; j += 256) { float v = row[j]; s += (double)v * (double)v; }
    __shared__ double sd[256];
    sd[threadIdx.x] = s;
    __syncthreads();
    for (int off = 128; off > 0; off >>= 1) {
        if (threadIdx.x < off) sd[threadIdx.x] += sd[threadIdx.x + off];
        __syncthreads();
    }
    if (threadIdx.x == 0) bsq[c] = (float)sd[0];
}

__global__ __launch_bounds__(256, 4)
void k_gemm1(const float* __restrict__ S, const float* __restrict__ W,
             const float* __restrict__ bproj, float* __restrict__ Z) {
    const int e0 = blockIdx.x * 64;
    const int m0 = blockIdx.y * 64;
    const int t  = threadIdx.x;
    const int tx = t & 15, ty = t >> 4;
    __shared__ float alds[32 * 68];
    __shared__ float blds[32 * 68];
    float acc[4][4] = {};
    for (int k0 = 0; k0 < DM; k0 += 32) {
        #pragma unroll
        for (int rep = 0; rep < 2; ++rep) {
            const int id  = t + rep * 256;
            const int row = id >> 3, kq = id & 7;
            const float4 va = *(const float4*)(S + (size_t)(m0 + row) * DM + k0 + 4 * kq);
            alds[(4*kq+0)*68 + row] = va.x;
            alds[(4*kq+1)*68 + row] = va.y;
            alds[(4*kq+2)*68 + row] = va.z;
            alds[(4*kq+3)*68 + row] = va.w;
            float4 vb = make_float4(0.f, 0.f, 0.f, 0.f);
            if (e0 + row < ED)
                vb = *(const float4*)(W + (size_t)(e0 + row) * DM + k0 + 4 * kq);
            blds[(4*kq+0)*68 + row] = vb.x;
            blds[(4*kq+1)*68 + row] = vb.y;
            blds[(4*kq+2)*68 + row] = vb.z;
            blds[(4*kq+3)*68 + row] = vb.w;
        }
        __syncthreads();
        #pragma unroll 8
        for (int k = 0; k < 32; ++k) {
            const float4 a = *(const float4*)&alds[k*68 + 4*ty];
            const float4 b = *(const float4*)&blds[k*68 + 4*tx];
            const float av[4] = {a.x, a.y, a.z, a.w};
            const float bv[4] = {b.x, b.y, b.z, b.w};
            #pragma unroll
            for (int i = 0; i < 4; ++i)
                #pragma unroll
                for (int j = 0; j < 4; ++j)
                    acc[i][j] = fmaf(av[i], bv[j], acc[i][j]);
        }
        __syncthreads();
    }
    const bool valid = (e0 + 4*tx + 4) <= ED;
    float4 bias = make_float4(0.f, 0.f, 0.f, 0.f);
    if (valid) bias = *(const float4*)(bproj + e0 + 4*tx);
    #pragma unroll
    for (int i = 0; i < 4; ++i) {
        if (valid) {
            float4 o;
            o.x = acc[i][0] + bias.x;
            o.y = acc[i][1] + bias.y;
            o.z = acc[i][2] + bias.z;
            o.w = acc[i][3] + bias.w;
            *(float4*)(Z + (size_t)(m0 + 4*ty + i) * ED + e0 + 4*tx) = o;
        }
    }
}

__global__ __launch_bounds__(64)
void k_zsq(const float* __restrict__ Z, float* __restrict__ zsq) {
    const int r = blockIdx.x;
    const float4* row4 = (const float4*)(Z + (size_t)r * ED);
    double s = 0.0;
    for (int q = threadIdx.x; q < ED / 4; q += 64) {
        const float4 v = row4[q];
        s += (double)v.x * v.x + (double)v.y * v.y + (double)v.z * v.z + (double)v.w * v.w;
    }
    #pragma unroll
    for (int off = 32; off > 0; off >>= 1) s += __shfl_down(s, off);
    if (threadIdx.x == 0) zsq[r] = (float)s;
}

__global__ __launch_bounds__(512, 2)
void k_dist(const float* __restrict__ Z, const float* __restrict__ basis,
            const float* __restrict__ bsq, const float* __restrict__ zsq,
            float* __restrict__ A, float* __restrict__ wgpart,
            int* __restrict__ idxws, float* __restrict__ out) {
    const int bid = blockIdx.x;
    const int wr0 = bid * 32;
    const int t   = threadIdx.x;
    const int cg  = t & 127;
    const int rq  = t >> 7;
    const int r0  = rq * 8;
    const int c0  = cg * 4;
    const int c1  = 512 + cg * 4;
    __shared__ float blds[16 * 1024];
    __shared__ float zlds[16 * 36];
    float acc[8][8];
    #pragma unroll
    for (int i = 0; i < 8; ++i)
        #pragma unroll
        for (int j = 0; j < 8; ++j) acc[i][j] = 0.f;
    for (int k0 = 0; k0 < ED; k0 += 16) {
        const bool full = (k0 + 16) <= ED;
        #pragma unroll
        for (int rep = 0; rep < 2; ++rep) {
            const int c = t + rep * 512;
            const float* bp = basis + (size_t)c * ED + k0;
            if (full) {
                const float4 v0 = *(const float4*)(bp + 0);
                const float4 v1 = *(const float4*)(bp + 4);
                const float4 v2 = *(const float4*)(bp + 8);
                const float4 v3 = *(const float4*)(bp + 12);
                blds[ 0*1024+c]=v0.x; blds[ 1*1024+c]=v0.y; blds[ 2*1024+c]=v0.z; blds[ 3*1024+c]=v0.w;
                blds[ 4*1024+c]=v1.x; blds[ 5*1024+c]=v1.y; blds[ 6*1024+c]=v1.z; blds[ 7*1024+c]=v1.w;
                blds[ 8*1024+c]=v2.x; blds[ 9*1024+c]=v2.y; blds[10*1024+c]=v2.z; blds[11*1024+c]=v2.w;
                blds[12*1024+c]=v3.x; blds[13*1024+c]=v3.y; blds[14*1024+c]=v3.z; blds[15*1024+c]=v3.w;
            } else {
                for (int kk = 0; kk < 16; ++kk)
                    blds[kk*1024 + c] = (k0 + kk < ED) ? bp[kk] : 0.f;
            }
        }
        if (t < 128) {
            const int row = t >> 2, kq = t & 3;
            const float* zp = Z + (size_t)(wr0 + row) * ED + k0 + 4 * kq;
            if (full) {
                const float4 v = *(const float4*)zp;
                zlds[(4*kq+0)*36 + row] = v.x;
                zlds[(4*kq+1)*36 + row] = v.y;
                zlds[(4*kq+2)*36 + row] = v.z;
                zlds[(4*kq+3)*36 + row] = v.w;
            } else {
                for (int j = 0; j < 4; ++j) {
                    const int k = k0 + 4*kq + j;
                    zlds[(4*kq+j)*36 + row] = (k < ED) ? zp[j] : 0.f;
                }
            }
        }
        __syncthreads();
        #pragma unroll
        for (int k = 0; k < 16; ++k) {
            const float4 z0 = *(const float4*)&zlds[k*36 + r0];
            const float4 z1 = *(const float4*)&zlds[k*36 + r0 + 4];
            const float4 b0 = *(const float4*)&blds[k*1024 + c0];
            const float4 b1 = *(const float4*)&blds[k*1024 + c1];
            const float zz[8] = {z0.x, z0.y, z0.z, z0.w, z1.x, z1.y, z1.z, z1.w};
            const float bb[8] = {b0.x, b0.y, b0.z, b0.w, b1.x, b1.y, b1.z, b1.w};
            #pragma unroll
            for (int i = 0; i < 8; ++i)
                #pragma unroll
                for (int j = 0; j < 8; ++j)
                    acc[i][j] = fmaf(zz[i], bb[j], acc[i][j]);
        }
        __syncthreads();
    }
    float* red_v    = blds;
    int*   red_i    = (int*)(blds + 4096);
    float* row_dmin = blds + 8192;
    float* row_s    = blds + 8224;
    float* pc       = blds + 8256;
    float bsqv[8], zsqv[8];
    #pragma unroll
    for (int j = 0; j < 4; ++j) { bsqv[j] = bsq[c0 + j]; bsqv[4 + j] = bsq[c1 + j]; }
    #pragma unroll
    for (int i = 0; i < 8; ++i) zsqv[i] = zsq[wr0 + r0 + i];
    #pragma unroll
    for (int i = 0; i < 8; ++i)
        #pragma unroll
        for (int j = 0; j < 8; ++j) {
            const float tv = zsqv[i] - 2.f * acc[i][j];
            acc[i][j] = tv + bsqv[j];
        }
    #pragma unroll
    for (int i = 0; i < 8; ++i) {
        float bv = acc[i][0]; int bi = c0;
        #pragma unroll
        for (int j = 1; j < 8; ++j) {
            const int c = (j < 4) ? (c0 + j) : (c1 + (j - 4));
            if (acc[i][j] < bv || (acc[i][j] == bv && c < bi)) { bv = acc[i][j]; bi = c; }
        }
        red_v[(r0 + i) * 128 + cg] = bv;
        red_i[(r0 + i) * 128 + cg] = bi;
    }
    __syncthreads();
    if (t < 32) {
        float bv = red_v[t * 128]; int bi = red_i[t * 128];
        for (int x = 1; x < 128; ++x) {
            const float v = red_v[t * 128 + x];
            const int  iv = red_i[t * 128 + x];
            if (v < bv || (v == bv && iv < bi)) { bv = v; bi = iv; }
        }
        row_dmin[t] = bv;
        idxws[wr0 + t] = bi;
        out[IDX_OFF + wr0 + t] = (float)bi;
    }
    __syncthreads();
    float su[8];
    #pragma unroll
    for (int i = 0; i < 8; ++i) {
        const float dm = row_dmin[r0 + i];
        float s = 0.f;
        #pragma unroll
        for (int j = 0; j < 8; ++j) {
            const float u = expf(dm - acc[i][j]);
            acc[i][j] = u;
            s += u;
        }
        su[i] = s;
    }
    #pragma unroll
    for (int i = 0; i < 8; ++i) red_v[(r0 + i) * 128 + cg] = su[i];
    __syncthreads();
    if (t < 32) {
        float s = 0.f;
        for (int x = 0; x < 128; ++x) s += red_v[t * 128 + x];
        row_s[t] = s;
    }
    __syncthreads();
    float rcp[8];
    #pragma unroll
    for (int i = 0; i < 8; ++i) rcp[i] = 1.f / row_s[r0 + i];
    pc[t] = 0.f; pc[t + 512] = 0.f;
    __syncthreads();
    #pragma unroll
    for (int j = 0; j < 8; ++j) {
        const int c = (j < 4) ? (c0 + j) : (c1 + (j - 4));
        float s = 0.f;
        #pragma unroll
        for (int i = 0; i < 8; ++i) s += acc[i][j] * rcp[i];
        atomicAdd(&pc[c], s);
    }
    __syncthreads();
    atomicAdd(&A[t],       pc[t]);
    atomicAdd(&A[t + 512], pc[t + 512]);
    if (t == 0) {
        float s = 0.f;
        for (int r = 0; r < 32; ++r) s += row_dmin[r];
        wgpart[bid] = s;
    }
}

// =====================================================================

extern "C" void kernel_launch(void* const* d_in, const int* in_sizes, int n_in,
                              void* d_out, int out_size, void* d_ws, size_t ws_size,
                              hipStream_t stream) {
    const float* S     = (const float*)d_in[0];  // [32768, 256]
    const float* W     = (const float*)d_in[1];  // [2700, 256]
    const float* bproj = (const float*)d_in[2];  // [2700]
    const float* basis = (const float*)d_in[3];  // [1024, 2700]
    float* out = (float*)d_out;
    float* ws  = (float*)d_ws;

    // common small regions
    float* zsq    = ws;                  // 32768
    float* A      = ws + 32768;          // 1024
    float* bsq    = ws + 33792;          // 1024
    float* wgpart = ws + 34816;          // 1024
    int*   idxws  = (int*)(ws + 35840);  // 32768

    // ws need (floats): 68608 small + Bh/Bm 2*1392640 + Wh/Wm 2*360448 + G 33554432
    const size_t NEED = (size_t)37129216 * sizeof(float);   // ~148.5 MB
    if (ws_size >= NEED) {
        // -------- MFMA path --------
        unsigned short* Bh = (unsigned short*)(ws + 68608);            // 1024*2720
        unsigned short* Bm = (unsigned short*)(ws + 68608 + 1392640);
        unsigned short* Wh = (unsigned short*)(ws + 68608 + 2785280);  // 2816*256
        unsigned short* Wm = (unsigned short*)(ws + 68608 + 3145728);
        float*          G  = ws + 3574784;                             // 32768*1024
        // transient allocations inside the G region (dead before k_gemm2 writes G)
        unsigned short* Sh = (unsigned short*)G;                       // 32768*256
        unsigned short* Sm = (unsigned short*)(G + 4194304);
        float*     zsqpart = G + 8388608;                              // 22*32768
        // Z planes live in the q_st output region (overwritten by k_gather at the end)
        unsigned short* Zh = (unsigned short*)out;
        unsigned short* Zm = Zh + (size_t)BKROWS * ED;

        hipMemsetAsync(A, 0, (size_t)NC * sizeof(float), stream);
        k_packS <<<BKROWS * DM / 1024, 256, 0, stream>>>(S, Sh, Sm);
        k_packW <<<WPAD * DM / 1024, 256, 0, stream>>>(W, Wh, Wm);
        k_packB <<<NC, 256, 0, stream>>>(basis, Bh, Bm, bsq);
        k_gemm1m<<<(BKROWS / 128) * NT1, 256, 0, stream>>>(Sh, Sm, Wh, Wm, bproj, Zh, Zm, zsqpart);
        k_zsqred<<<BKROWS / 256, 256, 0, stream>>>(zsqpart, zsq);
        k_gemm2 <<<2048, 256, 0, stream>>>(Zh, Zm, Bh, Bm, G);
        k_post  <<<BKROWS / 32, 512, 0, stream>>>(G, bsq, zsq, A, wgpart, idxws, out);
        k_final <<<1, 1024, 0, stream>>>(wgpart, A, out);
        k_gather<<<BKROWS, 256, 0, stream>>>(basis, idxws, out);
    } else {
        // -------- fallback: round-2 f32 path --------
        float* Z = out;
        hipMemsetAsync(A, 0, (size_t)NC * sizeof(float), stream);
        k_bsq   <<<NC, 256, 0, stream>>>(basis, bsq);
        k_gemm1 <<<dim3(43, 512), 256, 0, stream>>>(S, W, bproj, Z);
        k_zsq   <<<BKROWS, 64, 0, stream>>>(Z, zsq);
        k_dist  <<<BKROWS / 32, 512, 0, stream>>>(Z, basis, bsq, zsq, A, wgpart, idxws, out);
        k_final <<<1, 1024, 0, stream>>>(wgpart, A, out);
        k_gather<<<BKROWS, 256, 0, stream>>>(basis, idxws, out);
    }
}

// Round 5
// 939.586 us; speedup vs baseline: 10.4206x; 1.2332x over previous
//
#include <hip/hip_runtime.h>
#include <math.h>

#define ED 2700     // basis_dim
#define NC 1024     // num_codes
#define DM 256      // d_model
#define BKROWS 32768

#define IDX_OFF 88473600
#define VQ_OFF  88506368
#define ENT_OFF 88506369

#define BSTRIDE 2720        // padded k-stride for basis planes (zero tail)
#define NCHUNK 85           // ceil(2700/32)
#define WPAD 2816           // padded e-rows for W planes
#define NT1 22              // N-tiles in gemm1

typedef float  f32x4  __attribute__((ext_vector_type(4)));
typedef short  bf16x8 __attribute__((ext_vector_type(8)));

__device__ inline unsigned short f2bf(float x) {
    unsigned int u = __float_as_uint(x);
    unsigned int r = (u + 0x7FFFu + ((u >> 16) & 1u)) >> 16;
    return (unsigned short)r;
}
__device__ inline float bf2f(unsigned short h) {
    return __uint_as_float(((unsigned int)h) << 16);
}

// =====================================================================
// ============================ MFMA PATH ==============================
// =====================================================================

// ---- packs S -> Sh/Sm planes ----
__global__ __launch_bounds__(256)
void k_packS(const float* __restrict__ S, unsigned short* __restrict__ Sh,
             unsigned short* __restrict__ Sm) {
    const size_t i4 = (size_t)blockIdx.x * 256 + threadIdx.x;
    const float4 v = *(const float4*)(S + i4 * 4);
    ushort4 hv, mv;
    unsigned short* hp = (unsigned short*)&hv;
    unsigned short* mp = (unsigned short*)&mv;
    const float xs[4] = {v.x, v.y, v.z, v.w};
    #pragma unroll
    for (int j = 0; j < 4; ++j) {
        const unsigned short h = f2bf(xs[j]);
        hp[j] = h;
        mp[j] = f2bf(xs[j] - bf2f(h));
    }
    *(ushort4*)(Sh + i4 * 4) = hv;
    *(ushort4*)(Sm + i4 * 4) = mv;
}

// ---- packs W -> Wh/Wm planes, padded to WPAD rows (zeros) ----
__global__ __launch_bounds__(256)
void k_packW(const float* __restrict__ W, unsigned short* __restrict__ Wh,
             unsigned short* __restrict__ Wm) {
    const size_t i4 = (size_t)blockIdx.x * 256 + threadIdx.x;
    const size_t row = (i4 * 4) / DM;
    float4 v = make_float4(0.f, 0.f, 0.f, 0.f);
    if (row < ED) v = *(const float4*)(W + i4 * 4);
    ushort4 hv, mv;
    unsigned short* hp = (unsigned short*)&hv;
    unsigned short* mp = (unsigned short*)&mv;
    const float xs[4] = {v.x, v.y, v.z, v.w};
    #pragma unroll
    for (int j = 0; j < 4; ++j) {
        const unsigned short h = f2bf(xs[j]);
        hp[j] = h;
        mp[j] = f2bf(xs[j] - bf2f(h));
    }
    *(ushort4*)(Wh + i4 * 4) = hv;
    *(ushort4*)(Wm + i4 * 4) = mv;
}

// ---- basis -> Bh/Bm bf16 planes (stride 2720, zero pad) + bsq (f64) ----
__global__ void k_packB(const float* __restrict__ basis, unsigned short* __restrict__ Bh,
                        unsigned short* __restrict__ Bm, float* __restrict__ bsq) {
    const int c = blockIdx.x;
    const int t = threadIdx.x;
    const float* row = basis + (size_t)c * ED;
    double s = 0.0;
    for (int j = t; j < ED; j += 256) {
        const float x = row[j];
        s += (double)x * (double)x;
        const unsigned short h = f2bf(x);
        Bh[(size_t)c * BSTRIDE + j] = h;
        Bm[(size_t)c * BSTRIDE + j] = f2bf(x - bf2f(h));
    }
    if (t < BSTRIDE - ED) {
        Bh[(size_t)c * BSTRIDE + ED + t] = 0;
        Bm[(size_t)c * BSTRIDE + ED + t] = 0;
    }
    __shared__ double sd[256];
    sd[t] = s;
    __syncthreads();
    for (int off = 128; off > 0; off >>= 1) {
        if (t < off) sd[t] += sd[t + off];
        __syncthreads();
    }
    if (t == 0) bsq[c] = (float)sd[0];
}

// ---- K1m: Z = S@W^T + b via split-bf16 MFMA; emits Zh/Zm planes + zsq partials ----
__global__ __launch_bounds__(256, 2)
void k_gemm1m(const unsigned short* __restrict__ Sh, const unsigned short* __restrict__ Sm,
              const unsigned short* __restrict__ Wh, const unsigned short* __restrict__ Wm,
              const float* __restrict__ bproj, unsigned short* __restrict__ Zh,
              unsigned short* __restrict__ Zm, float* __restrict__ zsqpart) {
    __shared__ unsigned short lds[2 * 16384];

    const int bid  = blockIdx.x;
    const int mt   = bid / NT1;
    const int nt   = bid % NT1;
    const int m0   = mt * 128, n0 = nt * 128;
    const int tid  = threadIdx.x;
    const int w    = tid >> 6, l = tid & 63;
    const int wr   = (w >> 1) * 64;
    const int wc   = (w & 1) * 64;

    const unsigned short* gsrc[8];
    int ldsoff[8];
    #pragma unroll
    for (int i = 0; i < 8; ++i) {
        const int q    = i & 3;
        const int row  = q * 32 + w * 8 + (l >> 3);
        const int sg   = (l & 7) ^ (row & 7);
        const int pl   = sg >> 2;
        const int koff = (sg & 3) * 8;
        if (i < 4)
            gsrc[i] = (pl ? Sm : Sh) + (size_t)(m0 + row) * DM + koff;
        else
            gsrc[i] = (pl ? Wm : Wh) + (size_t)(n0 + row) * DM + koff;
        ldsoff[i] = (i >= 4 ? 8192 : 0) + q * 2048 + w * 512 + l * 8;
    }

    f32x4 acc[4][4];
    #pragma unroll
    for (int i = 0; i < 4; ++i)
        #pragma unroll
        for (int j = 0; j < 4; ++j) acc[i][j] = (f32x4){0.f, 0.f, 0.f, 0.f};

    #define STAGE1(buf, t) { \
        const int bb = (buf) * 16384; \
        const int kk = (t) * 32;      \
        _Pragma("unroll") \
        for (int i = 0; i < 8; ++i) \
            __builtin_amdgcn_global_load_lds( \
                (const __attribute__((address_space(1))) unsigned int*)(const void*)(gsrc[i] + kk), \
                (__attribute__((address_space(3))) unsigned int*)(void*)&lds[bb + ldsoff[i]], \
                16, 0, 0); \
    }

    STAGE1(0, 0);
    __syncthreads();

    const int lrow = l & 15;
    const int lu   = l >> 4;

    for (int t = 0; t < 8; ++t) {
        if (t + 1 < 8) STAGE1((t + 1) & 1, t + 1);

        const unsigned short* At = &lds[(t & 1) * 16384];
        const unsigned short* Bt = At + 8192;

        bf16x8 ah[4], am[4], bh[4], bm[4];
        #pragma unroll
        for (int f = 0; f < 4; ++f) {
            const int row = wr + f * 16 + lrow;
            const int uh  = (0 + lu) ^ (row & 7);
            const int um  = (4 + lu) ^ (row & 7);
            ah[f] = *(const bf16x8*)(At + row * 64 + uh * 8);
            am[f] = *(const bf16x8*)(At + row * 64 + um * 8);
        }
        #pragma unroll
        for (int f = 0; f < 4; ++f) {
            const int col = wc + f * 16 + lrow;
            const int uh  = (0 + lu) ^ (col & 7);
            const int um  = (4 + lu) ^ (col & 7);
            bh[f] = *(const bf16x8*)(Bt + col * 64 + uh * 8);
            bm[f] = *(const bf16x8*)(Bt + col * 64 + um * 8);
        }
        #pragma unroll
        for (int fm = 0; fm < 4; ++fm)
            #pragma unroll
            for (int fn = 0; fn < 4; ++fn) {
                acc[fm][fn] = __builtin_amdgcn_mfma_f32_16x16x32_bf16(ah[fm], bh[fn], acc[fm][fn], 0, 0, 0);
                acc[fm][fn] = __builtin_amdgcn_mfma_f32_16x16x32_bf16(ah[fm], bm[fn], acc[fm][fn], 0, 0, 0);
                acc[fm][fn] = __builtin_amdgcn_mfma_f32_16x16x32_bf16(am[fm], bh[fn], acc[fm][fn], 0, 0, 0);
            }
        __syncthreads();
    }
    #undef STAGE1

    // ---- epilogue: bias, split to planes, deterministic zsq partials ----
    float* rowsum = (float*)lds;
    if (tid < 256) rowsum[tid] = 0.f;
    __syncthreads();

    float bias_v[4]; int colv[4]; bool cok[4];
    #pragma unroll
    for (int fn = 0; fn < 4; ++fn) {
        const int col = n0 + wc + fn * 16 + lrow;
        colv[fn] = col;
        cok[fn]  = (col < ED);
        bias_v[fn] = cok[fn] ? bproj[col] : 0.f;
    }
    #pragma unroll
    for (int fm = 0; fm < 4; ++fm) {
        #pragma unroll
        for (int r = 0; r < 4; ++r) {
            const int lrowid = wr + fm * 16 + lu * 4 + r;
            const int grow   = m0 + lrowid;
            float z2 = 0.f;
            #pragma unroll
            for (int fn = 0; fn < 4; ++fn) {
                if (cok[fn]) {
                    const float zv = acc[fm][fn][r] + bias_v[fn];
                    const unsigned short h  = f2bf(zv);
                    const unsigned short ml = f2bf(zv - bf2f(h));
                    Zh[(size_t)grow * ED + colv[fn]] = h;
                    Zm[(size_t)grow * ED + colv[fn]] = ml;
                    z2 += zv * zv;
                }
            }
            #pragma unroll
            for (int off = 8; off > 0; off >>= 1) z2 += __shfl_xor(z2, off, 16);
            if ((l & 15) == 0) rowsum[(w & 1) * 128 + lrowid] = z2;
        }
    }
    __syncthreads();
    if (tid < 128)
        zsqpart[(size_t)nt * BKROWS + m0 + tid] = rowsum[tid] + rowsum[128 + tid];
}

// ---- zsq[r] = sum over NT1 partials (f64, deterministic) ----
__global__ void k_zsqred(const float* __restrict__ part, float* __restrict__ zsq) {
    const int r = blockIdx.x * 256 + threadIdx.x;
    double s = 0.0;
    #pragma unroll
    for (int b = 0; b < NT1; ++b) s += (double)part[(size_t)b * BKROWS + r];
    zsq[r] = (float)s;
}

// ---- K2m: G = Z.B^T via 3-product split-bf16 MFMA, 256x256 tile, 8 waves ----
__global__ __launch_bounds__(512, 2)
void k_gemm2(const unsigned short* __restrict__ Zh, const unsigned short* __restrict__ Zm,
             const unsigned short* __restrict__ Bh, const unsigned short* __restrict__ Bm,
             float* __restrict__ G) {
    // per buffer: A = 256 rows x 128B (8 x 16B units: 0-3 h-plane, 4-7 m-plane),
    // B same. physical_unit = logical_unit ^ (row & 7). 2 buffers = 128 KiB.
    __shared__ unsigned short lds[2 * 32768];

    const int bid  = blockIdx.x;
    const int xcd  = bid & 7, local = bid >> 3;
    const int mt   = xcd * 16 + (local >> 2);
    const int nt   = local & 3;
    const int m0   = mt * 256, n0 = nt * 256;
    const int tid  = threadIdx.x;
    const int w    = tid >> 6, l = tid & 63;
    const int wr   = (w >> 2) * 128;   // 2 wave-rows
    const int wc   = (w & 3) * 64;     // 4 wave-cols

    // staging: 2048 A unit-slots + 2048 B unit-slots; thread does 4 of each
    const unsigned short* gsrc[8];
    int ldsoff[8];
    #pragma unroll
    for (int i = 0; i < 8; ++i) {
        const int slot = (i & 3) * 512 + tid;
        const int row  = slot >> 3;
        const int unit = slot & 7;
        const int sg   = unit ^ (row & 7);
        const int pl   = sg >> 2;
        const int koff = (sg & 3) * 8;
        if (i < 4)
            gsrc[i] = (pl ? Zm : Zh) + (size_t)(m0 + row) * ED + koff;
        else
            gsrc[i] = (pl ? Bm : Bh) + (size_t)(n0 + row) * BSTRIDE + koff;
        ldsoff[i] = (i >= 4 ? 16384 : 0) + slot * 8;
    }

    f32x4 acc[8][4];
    #pragma unroll
    for (int i = 0; i < 8; ++i)
        #pragma unroll
        for (int j = 0; j < 4; ++j) acc[i][j] = (f32x4){0.f, 0.f, 0.f, 0.f};

    #define STAGE(buf, t) { \
        const int bb = (buf) * 32768; \
        const int kk = (t) * 32;      \
        _Pragma("unroll") \
        for (int i = 0; i < 8; ++i) \
            __builtin_amdgcn_global_load_lds( \
                (const __attribute__((address_space(1))) unsigned int*)(const void*)(gsrc[i] + kk), \
                (__attribute__((address_space(3))) unsigned int*)(void*)&lds[bb + ldsoff[i]], \
                16, 0, 0); \
    }

    STAGE(0, 0);
    __syncthreads();

    const int lrow = l & 15;
    const int lu   = l >> 4;

    for (int t = 0; t < NCHUNK; ++t) {
        if (t + 1 < NCHUNK) STAGE((t + 1) & 1, t + 1);

        const unsigned short* At = &lds[(t & 1) * 32768];
        const unsigned short* Bt = At + 16384;

        #pragma unroll
        for (int qm = 0; qm < 2; ++qm) {
            bf16x8 ah[4], am[4];
            #pragma unroll
            for (int f = 0; f < 4; ++f) {
                const int row = wr + (qm * 4 + f) * 16 + lrow;
                const int uh  = (0 + lu) ^ (row & 7);
                const int um  = (4 + lu) ^ (row & 7);
                ah[f] = *(const bf16x8*)(At + row * 64 + uh * 8);
                am[f] = *(const bf16x8*)(At + row * 64 + um * 8);
            }
            #pragma unroll
            for (int qn = 0; qn < 2; ++qn) {
                bf16x8 bh[2], bm[2];
                #pragma unroll
                for (int f = 0; f < 2; ++f) {
                    const int col = wc + (qn * 2 + f) * 16 + lrow;
                    const int uh  = (0 + lu) ^ (col & 7);
                    const int um  = (4 + lu) ^ (col & 7);
                    bh[f] = *(const bf16x8*)(Bt + col * 64 + uh * 8);
                    bm[f] = *(const bf16x8*)(Bt + col * 64 + um * 8);
                }
                #pragma unroll
                for (int i = 0; i < 4; ++i)
                    #pragma unroll
                    for (int j = 0; j < 2; ++j) {
                        f32x4 c = acc[qm * 4 + i][qn * 2 + j];
                        c = __builtin_amdgcn_mfma_f32_16x16x32_bf16(ah[i], bh[j], c, 0, 0, 0);
                        c = __builtin_amdgcn_mfma_f32_16x16x32_bf16(ah[i], bm[j], c, 0, 0, 0);
                        c = __builtin_amdgcn_mfma_f32_16x16x32_bf16(am[i], bh[j], c, 0, 0, 0);
                        acc[qm * 4 + i][qn * 2 + j] = c;
                    }
            }
        }
        __syncthreads();
    }
    #undef STAGE

    // C layout: col = lane&15, row = (lane>>4)*4 + reg
    #pragma unroll
    for (int fm = 0; fm < 8; ++fm)
        #pragma unroll
        for (int fn = 0; fn < 4; ++fn) {
            const int col = n0 + wc + fn * 16 + lrow;
            #pragma unroll
            for (int r = 0; r < 4; ++r) {
                const int row = m0 + wr + fm * 16 + lu * 4 + r;
                G[(size_t)row * NC + col] = acc[fm][fn][r];
            }
        }
}

// ---- K-post: dist assembly + argmin + softmax + avg_prob partials ----
__global__ __launch_bounds__(512)
void k_post(const float* __restrict__ G, const float* __restrict__ bsq,
            const float* __restrict__ zsq, float* __restrict__ A,
            float* __restrict__ wgpart, int* __restrict__ idxws,
            float* __restrict__ out) {
    const int bid = blockIdx.x;
    const int wr0 = bid * 32;
    const int t   = threadIdx.x;
    const int cg  = t & 127;
    const int rq  = t >> 7;
    const int r0  = rq * 8;
    const int c0  = cg * 4;
    const int c1  = 512 + cg * 4;

    __shared__ float sm[9280];
    float* red_v    = sm;
    int*   red_i    = (int*)(sm + 4096);
    float* row_dmin = sm + 8192;
    float* row_s    = sm + 8224;
    float* pc       = sm + 8256;

    float acc[8][8];
    #pragma unroll
    for (int i = 0; i < 8; ++i) {
        const float4 g0 = *(const float4*)&G[(size_t)(wr0 + r0 + i) * NC + c0];
        const float4 g1 = *(const float4*)&G[(size_t)(wr0 + r0 + i) * NC + c1];
        acc[i][0] = g0.x; acc[i][1] = g0.y; acc[i][2] = g0.z; acc[i][3] = g0.w;
        acc[i][4] = g1.x; acc[i][5] = g1.y; acc[i][6] = g1.z; acc[i][7] = g1.w;
    }

    float bsqv[8], zsqv[8];
    #pragma unroll
    for (int j = 0; j < 4; ++j) { bsqv[j] = bsq[c0 + j]; bsqv[4 + j] = bsq[c1 + j]; }
    #pragma unroll
    for (int i = 0; i < 8; ++i) zsqv[i] = zsq[wr0 + r0 + i];

    #pragma unroll
    for (int i = 0; i < 8; ++i)
        #pragma unroll
        for (int j = 0; j < 8; ++j) {
            const float tv = zsqv[i] - 2.f * acc[i][j];
            acc[i][j] = tv + bsqv[j];
        }

    #pragma unroll
    for (int i = 0; i < 8; ++i) {
        float bv = acc[i][0]; int bi = c0;
        #pragma unroll
        for (int j = 1; j < 8; ++j) {
            const int c = (j < 4) ? (c0 + j) : (c1 + (j - 4));
            if (acc[i][j] < bv || (acc[i][j] == bv && c < bi)) { bv = acc[i][j]; bi = c; }
        }
        red_v[(r0 + i) * 128 + cg] = bv;
        red_i[(r0 + i) * 128 + cg] = bi;
    }
    __syncthreads();
    if (t < 32) {
        float bv = red_v[t * 128]; int bi = red_i[t * 128];
        for (int x = 1; x < 128; ++x) {
            const float v = red_v[t * 128 + x];
            const int  iv = red_i[t * 128 + x];
            if (v < bv || (v == bv && iv < bi)) { bv = v; bi = iv; }
        }
        row_dmin[t] = bv;
        idxws[wr0 + t] = bi;
        out[IDX_OFF + wr0 + t] = (float)bi;
    }
    __syncthreads();

    float su[8];
    #pragma unroll
    for (int i = 0; i < 8; ++i) {
        const float dm = row_dmin[r0 + i];
        float s = 0.f;
        #pragma unroll
        for (int j = 0; j < 8; ++j) {
            const float u = expf(dm - acc[i][j]);
            acc[i][j] = u;
            s += u;
        }
        su[i] = s;
    }
    #pragma unroll
    for (int i = 0; i < 8; ++i) red_v[(r0 + i) * 128 + cg] = su[i];
    __syncthreads();
    if (t < 32) {
        float s = 0.f;
        for (int x = 0; x < 128; ++x) s += red_v[t * 128 + x];
        row_s[t] = s;
    }
    __syncthreads();

    float rcp[8];
    #pragma unroll
    for (int i = 0; i < 8; ++i) rcp[i] = 1.f / row_s[r0 + i];

    pc[t] = 0.f; pc[t + 512] = 0.f;
    __syncthreads();
    #pragma unroll
    for (int j = 0; j < 8; ++j) {
        const int c = (j < 4) ? (c0 + j) : (c1 + (j - 4));
        float s = 0.f;
        #pragma unroll
        for (int i = 0; i < 8; ++i) s += acc[i][j] * rcp[i];
        atomicAdd(&pc[c], s);
    }
    __syncthreads();
    atomicAdd(&A[t],       pc[t]);
    atomicAdd(&A[t + 512], pc[t + 512]);

    if (t == 0) {
        float s = 0.f;
        for (int r = 0; r < 32; ++r) s += row_dmin[r];
        wgpart[bid] = s;
    }
}

// ---- finalize scalars ----
__global__ void k_final(const float* __restrict__ wgpart, const float* __restrict__ A,
                        float* __restrict__ out) {
    __shared__ double sd[1024];
    const int t = threadIdx.x;
    sd[t] = (double)wgpart[t];
    __syncthreads();
    for (int off = 512; off > 0; off >>= 1) {
        if (t < off) sd[t] += sd[t + off];
        __syncthreads();
    }
    if (t == 0) out[VQ_OFF] = (float)(0.25 * sd[0] / 88473600.0);
    __syncthreads();
    const double p = (double)A[t] * (1.0 / 32768.0);
    sd[t] = -p * log(p + 1e-8);
    __syncthreads();
    for (int off = 512; off > 0; off >>= 1) {
        if (t < off) sd[t] += sd[t + off];
        __syncthreads();
    }
    if (t == 0) out[ENT_OFF] = (float)sd[0];
}

// ---- q_st = basis[indices] ----
__global__ void k_gather(const float* __restrict__ basis, const int* __restrict__ idxws,
                         float* __restrict__ out) {
    const int r = blockIdx.x;
    const int idx = idxws[r];
    const float4* src = (const float4*)(basis + (size_t)idx * ED);
    float4* dst = (float4*)(out + (size_t)r * ED);
    for (int j = threadIdx.x; j < ED / 4; j += 256) dst[j] = src[j];
}

// =====================================================================
// ===================== FALLBACK (round-2, f32 VALU) ==================
// =====================================================================

__global__ void k_bsq(const float* __restrict__ basis, float* __restrict__ bsq) {
    int c = blockIdx.x;
    const float* row = basis + (size_t)c * ED;
    double s = 0.0;
    for (int j = threadIdx.x; j < ED; j += 256) { float v = row[j]; s += (double)v * (double)v; }
    __shared__ double sd[256];
    sd[threadIdx.x] = s;
    __syncthreads();
    for (int off = 128; off > 0; off >>= 1) {
        if (threadIdx.x < off) sd[threadIdx.x] += sd[threadIdx.x + off];
        __syncthreads();
    }
    if (threadIdx.x == 0) bsq[c] = (float)sd[0];
}

__global__ __launch_bounds__(256, 4)
void k_gemm1(const float* __restrict__ S, const float* __restrict__ W,
             const float* __restrict__ bproj, float* __restrict__ Z) {
    const int e0 = blockIdx.x * 64;
    const int m0 = blockIdx.y * 64;
    const int t  = threadIdx.x;
    const int tx = t & 15, ty = t >> 4;
    __shared__ float alds[32 * 68];
    __shared__ float blds[32 * 68];
    float acc[4][4] = {};
    for (int k0 = 0; k0 < DM; k0 += 32) {
        #pragma unroll
        for (int rep = 0; rep < 2; ++rep) {
            const int id  = t + rep * 256;
            const int row = id >> 3, kq = id & 7;
            const float4 va = *(const float4*)(S + (size_t)(m0 + row) * DM + k0 + 4 * kq);
            alds[(4*kq+0)*68 + row] = va.x;
            alds[(4*kq+1)*68 + row] = va.y;
            alds[(4*kq+2)*68 + row] = va.z;
            alds[(4*kq+3)*68 + row] = va.w;
            float4 vb = make_float4(0.f, 0.f, 0.f, 0.f);
            if (e0 + row < ED)
                vb = *(const float4*)(W + (size_t)(e0 + row) * DM + k0 + 4 * kq);
            blds[(4*kq+0)*68 + row] = vb.x;
            blds[(4*kq+1)*68 + row] = vb.y;
            blds[(4*kq+2)*68 + row] = vb.z;
            blds[(4*kq+3)*68 + row] = vb.w;
        }
        __syncthreads();
        #pragma unroll 8
        for (int k = 0; k < 32; ++k) {
            const float4 a = *(const float4*)&alds[k*68 + 4*ty];
            const float4 b = *(const float4*)&blds[k*68 + 4*tx];
            const float av[4] = {a.x, a.y, a.z, a.w};
            const float bv[4] = {b.x, b.y, b.z, b.w};
            #pragma unroll
            for (int i = 0; i < 4; ++i)
                #pragma unroll
                for (int j = 0; j < 4; ++j)
                    acc[i][j] = fmaf(av[i], bv[j], acc[i][j]);
        }
        __syncthreads();
    }
    const bool valid = (e0 + 4*tx + 4) <= ED;
    float4 bias = make_float4(0.f, 0.f, 0.f, 0.f);
    if (valid) bias = *(const float4*)(bproj + e0 + 4*tx);
    #pragma unroll
    for (int i = 0; i < 4; ++i) {
        if (valid) {
            float4 o;
            o.x = acc[i][0] + bias.x;
            o.y = acc[i][1] + bias.y;
            o.z = acc[i][2] + bias.z;
            o.w = acc[i][3] + bias.w;
            *(float4*)(Z + (size_t)(m0 + 4*ty + i) * ED + e0 + 4*tx) = o;
        }
    }
}

__global__ __launch_bounds__(64)
void k_zsq(const float* __restrict__ Z, float* __restrict__ zsq) {
    const int r = blockIdx.x;
    const float4* row4 = (const float4*)(Z + (size_t)r * ED);
    double s = 0.0;
    for (int q = threadIdx.x; q < ED / 4; q += 64) {
        const float4 v = row4[q];
        s += (double)v.x * v.x + (double)v.y * v.y + (double)v.z * v.z + (double)v.w * v.w;
    }
    #pragma unroll
    for (int off = 32; off > 0; off >>= 1) s += __shfl_down(s, off);
    if (threadIdx.x == 0) zsq[r] = (float)s;
}

__global__ __launch_bounds__(512, 2)
void k_dist(const float* __restrict__ Z, const float* __restrict__ basis,
            const float* __restrict__ bsq, const float* __restrict__ zsq,
            float* __restrict__ A, float* __restrict__ wgpart,
            int* __restrict__ idxws, float* __restrict__ out) {
    const int bid = blockIdx.x;
    const int wr0 = bid * 32;
    const int t   = threadIdx.x;
    const int cg  = t & 127;
    const int rq  = t >> 7;
    const int r0  = rq * 8;
    const int c0  = cg * 4;
    const int c1  = 512 + cg * 4;
    __shared__ float blds[16 * 1024];
    __shared__ float zlds[16 * 36];
    float acc[8][8];
    #pragma unroll
    for (int i = 0; i < 8; ++i)
        #pragma unroll
        for (int j = 0; j < 8; ++j) acc[i][j] = 0.f;
    for (int k0 = 0; k0 < ED; k0 += 16) {
        const bool full = (k0 + 16) <= ED;
        #pragma unroll
        for (int rep = 0; rep < 2; ++rep) {
            const int c = t + rep * 512;
            const float* bp = basis + (size_t)c * ED + k0;
            if (full) {
                const float4 v0 = *(const float4*)(bp + 0);
                const float4 v1 = *(const float4*)(bp + 4);
                const float4 v2 = *(const float4*)(bp + 8);
                const float4 v3 = *(const float4*)(bp + 12);
                blds[ 0*1024+c]=v0.x; blds[ 1*1024+c]=v0.y; blds[ 2*1024+c]=v0.z; blds[ 3*1024+c]=v0.w;
                blds[ 4*1024+c]=v1.x; blds[ 5*1024+c]=v1.y; blds[ 6*1024+c]=v1.z; blds[ 7*1024+c]=v1.w;
                blds[ 8*1024+c]=v2.x; blds[ 9*1024+c]=v2.y; blds[10*1024+c]=v2.z; blds[11*1024+c]=v2.w;
                blds[12*1024+c]=v3.x; blds[13*1024+c]=v3.y; blds[14*1024+c]=v3.z; blds[15*1024+c]=v3.w;
            } else {
                for (int kk = 0; kk < 16; ++kk)
                    blds[kk*1024 + c] = (k0 + kk < ED) ? bp[kk] : 0.f;
            }
        }
        if (t < 128) {
            const int row = t >> 2, kq = t & 3;
            const float* zp = Z + (size_t)(wr0 + row) * ED + k0 + 4 * kq;
            if (full) {
                const float4 v = *(const float4*)zp;
                zlds[(4*kq+0)*36 + row] = v.x;
                zlds[(4*kq+1)*36 + row] = v.y;
                zlds[(4*kq+2)*36 + row] = v.z;
                zlds[(4*kq+3)*36 + row] = v.w;
            } else {
                for (int j = 0; j < 4; ++j) {
                    const int k = k0 + 4*kq + j;
                    zlds[(4*kq+j)*36 + row] = (k < ED) ? zp[j] : 0.f;
                }
            }
        }
        __syncthreads();
        #pragma unroll
        for (int k = 0; k < 16; ++k) {
            const float4 z0 = *(const float4*)&zlds[k*36 + r0];
            const float4 z1 = *(const float4*)&zlds[k*36 + r0 + 4];
            const float4 b0 = *(const float4*)&blds[k*1024 + c0];
            const float4 b1 = *(const float4*)&blds[k*1024 + c1];
            const float zz[8] = {z0.x, z0.y, z0.z, z0.w, z1.x, z1.y, z1.z, z1.w};
            const float bb[8] = {b0.x, b0.y, b0.z, b0.w, b1.x, b1.y, b1.z, b1.w};
            #pragma unroll
            for (int i = 0; i < 8; ++i)
                #pragma unroll
                for (int j = 0; j < 8; ++j)
                    acc[i][j] = fmaf(zz[i], bb[j], acc[i][j]);
        }
        __syncthreads();
    }
    float* red_v    = blds;
    int*   red_i    = (int*)(blds + 4096);
    float* row_dmin = blds + 8192;
    float* row_s    = blds + 8224;
    float* pc       = blds + 8256;
    float bsqv[8], zsqv[8];
    #pragma unroll
    for (int j = 0; j < 4; ++j) { bsqv[j] = bsq[c0 + j]; bsqv[4 + j] = bsq[c1 + j]; }
    #pragma unroll
    for (int i = 0; i < 8; ++i) zsqv[i] = zsq[wr0 + r0 + i];
    #pragma unroll
    for (int i = 0; i < 8; ++i)
        #pragma unroll
        for (int j = 0; j < 8; ++j) {
            const float tv = zsqv[i] - 2.f * acc[i][j];
            acc[i][j] = tv + bsqv[j];
        }
    #pragma unroll
    for (int i = 0; i < 8; ++i) {
        float bv = acc[i][0]; int bi = c0;
        #pragma unroll
        for (int j = 1; j < 8; ++j) {
            const int c = (j < 4) ? (c0 + j) : (c1 + (j - 4));
            if (acc[i][j] < bv || (acc[i][j] == bv && c < bi)) { bv = acc[i][j]; bi = c; }
        }
        red_v[(r0 + i) * 128 + cg] = bv;
        red_i[(r0 + i) * 128 + cg] = bi;
    }
    __syncthreads();
    if (t < 32) {
        float bv = red_v[t * 128]; int bi = red_i[t * 128];
        for (int x = 1; x < 128; ++x) {
            const float v = red_v[t * 128 + x];
            const int  iv = red_i[t * 128 + x];
            if (v < bv || (v == bv && iv < bi)) { bv = v; bi = iv; }
        }
        row_dmin[t] = bv;
        idxws[wr0 + t] = bi;
        out[IDX_OFF + wr0 + t] = (float)bi;
    }
    __syncthreads();
    float su[8];
    #pragma unroll
    for (int i = 0; i < 8; ++i) {
        const float dm = row_dmin[r0 + i];
        float s = 0.f;
        #pragma unroll
        for (int j = 0; j < 8; ++j) {
            const float u = expf(dm - acc[i][j]);
            acc[i][j] = u;
            s += u;
        }
        su[i] = s;
    }
    #pragma unroll
    for (int i = 0; i < 8; ++i) red_v[(r0 + i) * 128 + cg] = su[i];
    __syncthreads();
    if (t < 32) {
        float s = 0.f;
        for (int x = 0; x < 128; ++x) s += red_v[t * 128 + x];
        row_s[t] = s;
    }
    __syncthreads();
    float rcp[8];
    #pragma unroll
    for (int i = 0; i < 8; ++i) rcp[i] = 1.f / row_s[r0 + i];
    pc[t] = 0.f; pc[t + 512] = 0.f;
    __syncthreads();
    #pragma unroll
    for (int j = 0; j < 8; ++j) {
        const int c = (j < 4) ? (c0 + j) : (c1 + (j - 4));
        float s = 0.f;
        #pragma unroll
        for (int i = 0; i < 8; ++i) s += acc[i][j] * rcp[i];
        atomicAdd(&pc[c], s);
    }
    __syncthreads();
    atomicAdd(&A[t],       pc[t]);
    atomicAdd(&A[t + 512], pc[t + 512]);
    if (t == 0) {
        float s = 0.f;
        for (int r = 0; r < 32; ++r) s += row_dmin[r];
        wgpart[bid] = s;
    }
}

// =====================================================================

extern "C" void kernel_launch(void* const* d_in, const int* in_sizes, int n_in,
                              void* d_out, int out_size, void* d_ws, size_t ws_size,
                              hipStream_t stream) {
    const float* S     = (const float*)d_in[0];  // [32768, 256]
    const float* W     = (const float*)d_in[1];  // [2700, 256]
    const float* bproj = (const float*)d_in[2];  // [2700]
    const float* basis = (const float*)d_in[3];  // [1024, 2700]
    float* out = (float*)d_out;
    float* ws  = (float*)d_ws;

    // common small regions
    float* zsq    = ws;                  // 32768
    float* A      = ws + 32768;          // 1024
    float* bsq    = ws + 33792;          // 1024
    float* wgpart = ws + 34816;          // 1024
    int*   idxws  = (int*)(ws + 35840);  // 32768

    const size_t NEED = (size_t)37129216 * sizeof(float);   // ~148.5 MB
    if (ws_size >= NEED) {
        // -------- MFMA path --------
        unsigned short* Bh = (unsigned short*)(ws + 68608);            // 1024*2720
        unsigned short* Bm = (unsigned short*)(ws + 68608 + 1392640);
        unsigned short* Wh = (unsigned short*)(ws + 68608 + 2785280);  // 2816*256
        unsigned short* Wm = (unsigned short*)(ws + 68608 + 3145728);
        float*          G  = ws + 3574784;                             // 32768*1024
        // transient allocations inside the G region (dead before k_gemm2 writes G)
        unsigned short* Sh = (unsigned short*)G;                       // 32768*256
        unsigned short* Sm = (unsigned short*)(G + 4194304);
        float*     zsqpart = G + 8388608;                              // 22*32768
        // Z planes live in the q_st output region (overwritten by k_gather at the end)
        unsigned short* Zh = (unsigned short*)out;
        unsigned short* Zm = Zh + (size_t)BKROWS * ED;

        hipMemsetAsync(A, 0, (size_t)NC * sizeof(float), stream);
        k_packS <<<BKROWS * DM / 1024, 256, 0, stream>>>(S, Sh, Sm);
        k_packW <<<WPAD * DM / 1024, 256, 0, stream>>>(W, Wh, Wm);
        k_packB <<<NC, 256, 0, stream>>>(basis, Bh, Bm, bsq);
        k_gemm1m<<<(BKROWS / 128) * NT1, 256, 0, stream>>>(Sh, Sm, Wh, Wm, bproj, Zh, Zm, zsqpart);
        k_zsqred<<<BKROWS / 256, 256, 0, stream>>>(zsqpart, zsq);
        k_gemm2 <<<512, 512, 0, stream>>>(Zh, Zm, Bh, Bm, G);
        k_post  <<<BKROWS / 32, 512, 0, stream>>>(G, bsq, zsq, A, wgpart, idxws, out);
        k_final <<<1, 1024, 0, stream>>>(wgpart, A, out);
        k_gather<<<BKROWS, 256, 0, stream>>>(basis, idxws, out);
    } else {
        // -------- fallback: round-2 f32 path --------
        float* Z = out;
        hipMemsetAsync(A, 0, (size_t)NC * sizeof(float), stream);
        k_bsq   <<<NC, 256, 0, stream>>>(basis, bsq);
        k_gemm1 <<<dim3(43, 512), 256, 0, stream>>>(S, W, bproj, Z);
        k_zsq   <<<BKROWS, 64, 0, stream>>>(Z, zsq);
        k_dist  <<<BKROWS / 32, 512, 0, stream>>>(Z, basis, bsq, zsq, A, wgpart, idxws, out);
        k_final <<<1, 1024, 0, stream>>>(wgpart, A, out);
        k_gather<<<BKROWS, 256, 0, stream>>>(basis, idxws, out);
    }
}

// Round 6
// 891.822 us; speedup vs baseline: 10.9787x; 1.0536x over previous
//
#include <hip/hip_runtime.h>
#include <math.h>

#define ED 2700     // basis_dim
#define NC 1024     // num_codes
#define DM 256      // d_model
#define BKROWS 32768

#define IDX_OFF 88473600
#define VQ_OFF  88506368
#define ENT_OFF 88506369

#define BSTRIDE 2720        // padded k-stride for basis planes (zero tail)
#define NCHUNK 85           // ceil(2700/32)
#define WPAD 2816           // padded e-rows for W planes
#define NT1 22              // N-tiles in gemm1

typedef float  f32x4  __attribute__((ext_vector_type(4)));
typedef short  bf16x8 __attribute__((ext_vector_type(8)));

__device__ inline unsigned short f2bf(float x) {
    unsigned int u = __float_as_uint(x);
    unsigned int r = (u + 0x7FFFu + ((u >> 16) & 1u)) >> 16;
    return (unsigned short)r;
}
__device__ inline float bf2f(unsigned short h) {
    return __uint_as_float(((unsigned int)h) << 16);
}

// =====================================================================
// ============================ MFMA PATH ==============================
// =====================================================================

// ---- packs S -> Sh/Sm planes ----
__global__ __launch_bounds__(256)
void k_packS(const float* __restrict__ S, unsigned short* __restrict__ Sh,
             unsigned short* __restrict__ Sm) {
    const size_t i4 = (size_t)blockIdx.x * 256 + threadIdx.x;
    const float4 v = *(const float4*)(S + i4 * 4);
    ushort4 hv, mv;
    unsigned short* hp = (unsigned short*)&hv;
    unsigned short* mp = (unsigned short*)&mv;
    const float xs[4] = {v.x, v.y, v.z, v.w};
    #pragma unroll
    for (int j = 0; j < 4; ++j) {
        const unsigned short h = f2bf(xs[j]);
        hp[j] = h;
        mp[j] = f2bf(xs[j] - bf2f(h));
    }
    *(ushort4*)(Sh + i4 * 4) = hv;
    *(ushort4*)(Sm + i4 * 4) = mv;
}

// ---- packs W -> Wh/Wm planes, padded to WPAD rows (zeros) ----
__global__ __launch_bounds__(256)
void k_packW(const float* __restrict__ W, unsigned short* __restrict__ Wh,
             unsigned short* __restrict__ Wm) {
    const size_t i4 = (size_t)blockIdx.x * 256 + threadIdx.x;
    const size_t row = (i4 * 4) / DM;
    float4 v = make_float4(0.f, 0.f, 0.f, 0.f);
    if (row < ED) v = *(const float4*)(W + i4 * 4);
    ushort4 hv, mv;
    unsigned short* hp = (unsigned short*)&hv;
    unsigned short* mp = (unsigned short*)&mv;
    const float xs[4] = {v.x, v.y, v.z, v.w};
    #pragma unroll
    for (int j = 0; j < 4; ++j) {
        const unsigned short h = f2bf(xs[j]);
        hp[j] = h;
        mp[j] = f2bf(xs[j] - bf2f(h));
    }
    *(ushort4*)(Wh + i4 * 4) = hv;
    *(ushort4*)(Wm + i4 * 4) = mv;
}

// ---- basis -> Bh/Bm bf16 planes (stride 2720, zero pad) + bsq (f64) ----
__global__ void k_packB(const float* __restrict__ basis, unsigned short* __restrict__ Bh,
                        unsigned short* __restrict__ Bm, float* __restrict__ bsq) {
    const int c = blockIdx.x;
    const int t = threadIdx.x;
    const float* row = basis + (size_t)c * ED;
    double s = 0.0;
    for (int j = t; j < ED; j += 256) {
        const float x = row[j];
        s += (double)x * (double)x;
        const unsigned short h = f2bf(x);
        Bh[(size_t)c * BSTRIDE + j] = h;
        Bm[(size_t)c * BSTRIDE + j] = f2bf(x - bf2f(h));
    }
    if (t < BSTRIDE - ED) {
        Bh[(size_t)c * BSTRIDE + ED + t] = 0;
        Bm[(size_t)c * BSTRIDE + ED + t] = 0;
    }
    __shared__ double sd[256];
    sd[t] = s;
    __syncthreads();
    for (int off = 128; off > 0; off >>= 1) {
        if (t < off) sd[t] += sd[t + off];
        __syncthreads();
    }
    if (t == 0) bsq[c] = (float)sd[0];
}

// ---- K1m: Z = S@W^T + b via split-bf16 MFMA; emits Zh/Zm planes + zsq partials ----
__global__ __launch_bounds__(256, 2)
void k_gemm1m(const unsigned short* __restrict__ Sh, const unsigned short* __restrict__ Sm,
              const unsigned short* __restrict__ Wh, const unsigned short* __restrict__ Wm,
              const float* __restrict__ bproj, unsigned short* __restrict__ Zh,
              unsigned short* __restrict__ Zm, float* __restrict__ zsqpart) {
    __shared__ unsigned short lds[2 * 16384];

    const int bid  = blockIdx.x;
    const int mt   = bid / NT1;
    const int nt   = bid % NT1;
    const int m0   = mt * 128, n0 = nt * 128;
    const int tid  = threadIdx.x;
    const int w    = tid >> 6, l = tid & 63;
    const int wr   = (w >> 1) * 64;
    const int wc   = (w & 1) * 64;

    const unsigned short* gsrc[8];
    int ldsoff[8];
    #pragma unroll
    for (int i = 0; i < 8; ++i) {
        const int q    = i & 3;
        const int row  = q * 32 + w * 8 + (l >> 3);
        const int sg   = (l & 7) ^ (row & 7);
        const int pl   = sg >> 2;
        const int koff = (sg & 3) * 8;
        if (i < 4)
            gsrc[i] = (pl ? Sm : Sh) + (size_t)(m0 + row) * DM + koff;
        else
            gsrc[i] = (pl ? Wm : Wh) + (size_t)(n0 + row) * DM + koff;
        ldsoff[i] = (i >= 4 ? 8192 : 0) + q * 2048 + w * 512 + l * 8;
    }

    f32x4 acc[4][4];
    #pragma unroll
    for (int i = 0; i < 4; ++i)
        #pragma unroll
        for (int j = 0; j < 4; ++j) acc[i][j] = (f32x4){0.f, 0.f, 0.f, 0.f};

    #define STAGE1(buf, t) { \
        const int bb = (buf) * 16384; \
        const int kk = (t) * 32;      \
        _Pragma("unroll") \
        for (int i = 0; i < 8; ++i) \
            __builtin_amdgcn_global_load_lds( \
                (const __attribute__((address_space(1))) unsigned int*)(const void*)(gsrc[i] + kk), \
                (__attribute__((address_space(3))) unsigned int*)(void*)&lds[bb + ldsoff[i]], \
                16, 0, 0); \
    }

    STAGE1(0, 0);
    __syncthreads();

    const int lrow = l & 15;
    const int lu   = l >> 4;

    for (int t = 0; t < 8; ++t) {
        if (t + 1 < 8) STAGE1((t + 1) & 1, t + 1);

        const unsigned short* At = &lds[(t & 1) * 16384];
        const unsigned short* Bt = At + 8192;

        bf16x8 ah[4], am[4], bh[4], bm[4];
        #pragma unroll
        for (int f = 0; f < 4; ++f) {
            const int row = wr + f * 16 + lrow;
            const int uh  = (0 + lu) ^ (row & 7);
            const int um  = (4 + lu) ^ (row & 7);
            ah[f] = *(const bf16x8*)(At + row * 64 + uh * 8);
            am[f] = *(const bf16x8*)(At + row * 64 + um * 8);
        }
        #pragma unroll
        for (int f = 0; f < 4; ++f) {
            const int col = wc + f * 16 + lrow;
            const int uh  = (0 + lu) ^ (col & 7);
            const int um  = (4 + lu) ^ (col & 7);
            bh[f] = *(const bf16x8*)(Bt + col * 64 + uh * 8);
            bm[f] = *(const bf16x8*)(Bt + col * 64 + um * 8);
        }
        #pragma unroll
        for (int fm = 0; fm < 4; ++fm)
            #pragma unroll
            for (int fn = 0; fn < 4; ++fn) {
                acc[fm][fn] = __builtin_amdgcn_mfma_f32_16x16x32_bf16(ah[fm], bh[fn], acc[fm][fn], 0, 0, 0);
                acc[fm][fn] = __builtin_amdgcn_mfma_f32_16x16x32_bf16(ah[fm], bm[fn], acc[fm][fn], 0, 0, 0);
                acc[fm][fn] = __builtin_amdgcn_mfma_f32_16x16x32_bf16(am[fm], bh[fn], acc[fm][fn], 0, 0, 0);
            }
        __syncthreads();
    }
    #undef STAGE1

    // ---- epilogue: bias, split to planes, deterministic zsq partials ----
    float* rowsum = (float*)lds;
    if (tid < 256) rowsum[tid] = 0.f;
    __syncthreads();

    float bias_v[4]; int colv[4]; bool cok[4];
    #pragma unroll
    for (int fn = 0; fn < 4; ++fn) {
        const int col = n0 + wc + fn * 16 + lrow;
        colv[fn] = col;
        cok[fn]  = (col < ED);
        bias_v[fn] = cok[fn] ? bproj[col] : 0.f;
    }
    #pragma unroll
    for (int fm = 0; fm < 4; ++fm) {
        #pragma unroll
        for (int r = 0; r < 4; ++r) {
            const int lrowid = wr + fm * 16 + lu * 4 + r;
            const int grow   = m0 + lrowid;
            float z2 = 0.f;
            #pragma unroll
            for (int fn = 0; fn < 4; ++fn) {
                if (cok[fn]) {
                    const float zv = acc[fm][fn][r] + bias_v[fn];
                    const unsigned short h  = f2bf(zv);
                    const unsigned short ml = f2bf(zv - bf2f(h));
                    Zh[(size_t)grow * ED + colv[fn]] = h;
                    Zm[(size_t)grow * ED + colv[fn]] = ml;
                    z2 += zv * zv;
                }
            }
            #pragma unroll
            for (int off = 8; off > 0; off >>= 1) z2 += __shfl_xor(z2, off, 16);
            if ((l & 15) == 0) rowsum[(w & 1) * 128 + lrowid] = z2;
        }
    }
    __syncthreads();
    if (tid < 128)
        zsqpart[(size_t)nt * BKROWS + m0 + tid] = rowsum[tid] + rowsum[128 + tid];
}

// ---- zsq[r] = sum over NT1 partials (f64, deterministic) ----
__global__ void k_zsqred(const float* __restrict__ part, float* __restrict__ zsq) {
    const int r = blockIdx.x * 256 + threadIdx.x;
    double s = 0.0;
    #pragma unroll
    for (int b = 0; b < NT1; ++b) s += (double)part[(size_t)b * BKROWS + r];
    zsq[r] = (float)s;
}

// ---- K2m: G = Z.B^T, 256x256 tile, 8 waves, 4-phase counted-vmcnt schedule ----
// Half-tiles (per chunk, per operand): A-early = rows 0-63,128-191; A-late = rows
// 64-127,192-255; B-qn0 = rows 0-31,64-95,128-159,192-223; B-qn1 = complement.
// Phase p of chunk c computes C-quadrant (qm,qn) and stages one half:
//   P1(0,0): B-qn1(c+1)->ob   P2(0,1): A-late(c+1)->ob
//   P3(1,0): A-early(c+2)->cb P4(1,1): B-qn0(c+2)->cb  (overwrites dead halves)
// vmcnt(8) at end of P1/P2/P4 retires exactly the half the next phase needs.
__global__ __launch_bounds__(512, 2)
void k_gemm2(const unsigned short* __restrict__ Zh, const unsigned short* __restrict__ Zm,
             const unsigned short* __restrict__ Bh, const unsigned short* __restrict__ Bm,
             float* __restrict__ G) {
    __shared__ unsigned short lds[2 * 32768];

    const int bid  = blockIdx.x;
    const int xcd  = bid & 7, local = bid >> 3;
    const int mt   = xcd * 16 + (local >> 2);
    const int nt   = local & 3;
    const int m0   = mt * 256, n0 = nt * 256;
    const int tid  = threadIdx.x;
    const int w    = tid >> 6, l = tid & 63;
    const int wr   = (w >> 2) * 128;
    const int wc   = (w & 3) * 64;
    const int lrow = l & 15;
    const int lu   = l >> 4;

    // per-thread half-tile staging descriptors: ht 0=A-early 1=A-late 2=B-qn0 3=B-qn1
    const unsigned short* hsrc[4][2];
    int hlds[4][2];
    #pragma unroll
    for (int ht = 0; ht < 4; ++ht) {
        #pragma unroll
        for (int j = 0; j < 2; ++j) {
            const int slot = j * 512 + tid;
            const int rwh  = slot >> 3;
            const int unit = slot & 7;
            int row; bool isB;
            if (ht == 0)      { row = (rwh & 63) + (rwh >> 6) * 128;       isB = false; }
            else if (ht == 1) { row = 64 + (rwh & 63) + (rwh >> 6) * 128;  isB = false; }
            else if (ht == 2) { row = (rwh & 31) + (rwh >> 5) * 64;        isB = true;  }
            else              { row = 32 + (rwh & 31) + (rwh >> 5) * 64;   isB = true;  }
            const int sg   = unit ^ (row & 7);
            const int pl   = sg >> 2;
            const int koff = (sg & 3) * 8;
            if (!isB) hsrc[ht][j] = (pl ? Zm : Zh) + (size_t)(m0 + row) * ED + koff;
            else      hsrc[ht][j] = (pl ? Bm : Bh) + (size_t)(n0 + row) * BSTRIDE + koff;
            hlds[ht][j] = (isB ? 16384 : 0) + row * 64 + unit * 8;
        }
    }

    f32x4 acc[8][4];
    #pragma unroll
    for (int i = 0; i < 8; ++i)
        #pragma unroll
        for (int j = 0; j < 4; ++j) acc[i][j] = (f32x4){0.f, 0.f, 0.f, 0.f};

    #define STAGE_HALF(ht, ck, db) { \
        _Pragma("unroll") \
        for (int j = 0; j < 2; ++j) \
            __builtin_amdgcn_global_load_lds( \
                (const __attribute__((address_space(1))) unsigned int*)(const void*)(hsrc[ht][j] + (ck) * 32), \
                (__attribute__((address_space(3))) unsigned int*)(void*)&lds[(db) * 32768 + hlds[ht][j]], \
                16, 0, 0); \
    }

    #define LOAD_A(db, qm) { \
        const unsigned short* At = &lds[(db) * 32768]; \
        _Pragma("unroll") \
        for (int f = 0; f < 4; ++f) { \
            const int row = wr + ((qm) * 4 + f) * 16 + lrow; \
            ah[f] = *(const bf16x8*)(At + row * 64 + (((0 + lu) ^ (row & 7))) * 8); \
            am[f] = *(const bf16x8*)(At + row * 64 + (((4 + lu) ^ (row & 7))) * 8); \
        } \
    }
    #define LOAD_B(db, qn) { \
        const unsigned short* Bt = &lds[(db) * 32768 + 16384]; \
        _Pragma("unroll") \
        for (int f = 0; f < 2; ++f) { \
            const int col = wc + ((qn) * 2 + f) * 16 + lrow; \
            bh[f] = *(const bf16x8*)(Bt + col * 64 + (((0 + lu) ^ (col & 7))) * 8); \
            bm[f] = *(const bf16x8*)(Bt + col * 64 + (((4 + lu) ^ (col & 7))) * 8); \
        } \
    }
    #define MFMA_Q(qm, qn) { \
        __builtin_amdgcn_s_setprio(1); \
        _Pragma("unroll") \
        for (int i = 0; i < 4; ++i) \
            _Pragma("unroll") \
            for (int j = 0; j < 2; ++j) { \
                f32x4 cc = acc[(qm) * 4 + i][(qn) * 2 + j]; \
                cc = __builtin_amdgcn_mfma_f32_16x16x32_bf16(ah[i], bh[j], cc, 0, 0, 0); \
                cc = __builtin_amdgcn_mfma_f32_16x16x32_bf16(ah[i], bm[j], cc, 0, 0, 0); \
                cc = __builtin_amdgcn_mfma_f32_16x16x32_bf16(am[i], bh[j], cc, 0, 0, 0); \
                acc[(qm) * 4 + i][(qn) * 2 + j] = cc; \
            } \
        __builtin_amdgcn_s_setprio(0); \
    }
    #define VM8  asm volatile("s_waitcnt vmcnt(8)" ::: "memory");
    #define BAR  __builtin_amdgcn_s_barrier();

    // ---- prologue: chunk0 all halves (dbuf0) + chunk1 AE/B0 (dbuf1) ----
    STAGE_HALF(0, 0, 0) STAGE_HALF(2, 0, 0) STAGE_HALF(3, 0, 0) STAGE_HALF(1, 0, 0)
    STAGE_HALF(0, 1, 1) STAGE_HALF(2, 1, 1)
    VM8
    BAR

    // ---- main loop: chunks 0..NCHUNK-3 ----
    for (int c = 0; c < NCHUNK - 2; ++c) {
        const int cb = c & 1, ob = cb ^ 1;
        bf16x8 ah[4], am[4], bh[2], bm[2];
        // P1: quadrant (0,0)
        LOAD_A(cb, 0) LOAD_B(cb, 0)
        STAGE_HALF(3, c + 1, ob)
        BAR
        MFMA_Q(0, 0)
        VM8
        BAR
        // P2: quadrant (0,1)  (A regs reused)
        LOAD_B(cb, 1)
        STAGE_HALF(1, c + 1, ob)
        BAR
        MFMA_Q(0, 1)
        VM8
        BAR
        // P3: quadrant (1,0)
        LOAD_A(cb, 1) LOAD_B(cb, 0)
        STAGE_HALF(0, c + 2, cb)
        BAR
        MFMA_Q(1, 0)
        BAR
        // P4: quadrant (1,1)
        LOAD_B(cb, 1)
        STAGE_HALF(2, c + 2, cb)
        BAR
        MFMA_Q(1, 1)
        VM8
        BAR
    }

    // ---- epilogue: stage remaining halves of last chunk, drain, compute last 2 ----
    STAGE_HALF(3, NCHUNK - 1, (NCHUNK - 1) & 1) STAGE_HALF(1, NCHUNK - 1, (NCHUNK - 1) & 1)
    asm volatile("s_waitcnt vmcnt(0)" ::: "memory");
    BAR
    #pragma unroll
    for (int e = 0; e < 2; ++e) {
        const int cb = (NCHUNK - 2 + e) & 1;
        bf16x8 ah[4], am[4], bh[2], bm[2];
        LOAD_A(cb, 0) LOAD_B(cb, 0)
        MFMA_Q(0, 0)
        LOAD_B(cb, 1)
        MFMA_Q(0, 1)
        LOAD_A(cb, 1) LOAD_B(cb, 0)
        MFMA_Q(1, 0)
        LOAD_B(cb, 1)
        MFMA_Q(1, 1)
    }
    #undef STAGE_HALF
    #undef LOAD_A
    #undef LOAD_B
    #undef MFMA_Q
    #undef VM8
    #undef BAR

    // C layout: col = lane&15, row = (lane>>4)*4 + reg
    #pragma unroll
    for (int fm = 0; fm < 8; ++fm)
        #pragma unroll
        for (int fn = 0; fn < 4; ++fn) {
            const int col = n0 + wc + fn * 16 + lrow;
            #pragma unroll
            for (int r = 0; r < 4; ++r) {
                const int row = m0 + wr + fm * 16 + lu * 4 + r;
                G[(size_t)row * NC + col] = acc[fm][fn][r];
            }
        }
}

// ---- K-post: dist assembly + argmin + softmax + avg_prob partials ----
__global__ __launch_bounds__(512)
void k_post(const float* __restrict__ G, const float* __restrict__ bsq,
            const float* __restrict__ zsq, float* __restrict__ A,
            float* __restrict__ wgpart, int* __restrict__ idxws,
            float* __restrict__ out) {
    const int bid = blockIdx.x;
    const int wr0 = bid * 32;
    const int t   = threadIdx.x;
    const int cg  = t & 127;
    const int rq  = t >> 7;
    const int r0  = rq * 8;
    const int c0  = cg * 4;
    const int c1  = 512 + cg * 4;

    __shared__ float sm[9280];
    float* red_v    = sm;
    int*   red_i    = (int*)(sm + 4096);
    float* row_dmin = sm + 8192;
    float* row_s    = sm + 8224;
    float* pc       = sm + 8256;

    float acc[8][8];
    #pragma unroll
    for (int i = 0; i < 8; ++i) {
        const float4 g0 = *(const float4*)&G[(size_t)(wr0 + r0 + i) * NC + c0];
        const float4 g1 = *(const float4*)&G[(size_t)(wr0 + r0 + i) * NC + c1];
        acc[i][0] = g0.x; acc[i][1] = g0.y; acc[i][2] = g0.z; acc[i][3] = g0.w;
        acc[i][4] = g1.x; acc[i][5] = g1.y; acc[i][6] = g1.z; acc[i][7] = g1.w;
    }

    float bsqv[8], zsqv[8];
    #pragma unroll
    for (int j = 0; j < 4; ++j) { bsqv[j] = bsq[c0 + j]; bsqv[4 + j] = bsq[c1 + j]; }
    #pragma unroll
    for (int i = 0; i < 8; ++i) zsqv[i] = zsq[wr0 + r0 + i];

    #pragma unroll
    for (int i = 0; i < 8; ++i)
        #pragma unroll
        for (int j = 0; j < 8; ++j) {
            const float tv = zsqv[i] - 2.f * acc[i][j];
            acc[i][j] = tv + bsqv[j];
        }

    #pragma unroll
    for (int i = 0; i < 8; ++i) {
        float bv = acc[i][0]; int bi = c0;
        #pragma unroll
        for (int j = 1; j < 8; ++j) {
            const int c = (j < 4) ? (c0 + j) : (c1 + (j - 4));
            if (acc[i][j] < bv || (acc[i][j] == bv && c < bi)) { bv = acc[i][j]; bi = c; }
        }
        red_v[(r0 + i) * 128 + cg] = bv;
        red_i[(r0 + i) * 128 + cg] = bi;
    }
    __syncthreads();
    if (t < 32) {
        float bv = red_v[t * 128]; int bi = red_i[t * 128];
        for (int x = 1; x < 128; ++x) {
            const float v = red_v[t * 128 + x];
            const int  iv = red_i[t * 128 + x];
            if (v < bv || (v == bv && iv < bi)) { bv = v; bi = iv; }
        }
        row_dmin[t] = bv;
        idxws[wr0 + t] = bi;
        out[IDX_OFF + wr0 + t] = (float)bi;
    }
    __syncthreads();

    float su[8];
    #pragma unroll
    for (int i = 0; i < 8; ++i) {
        const float dm = row_dmin[r0 + i];
        float s = 0.f;
        #pragma unroll
        for (int j = 0; j < 8; ++j) {
            const float u = expf(dm - acc[i][j]);
            acc[i][j] = u;
            s += u;
        }
        su[i] = s;
    }
    #pragma unroll
    for (int i = 0; i < 8; ++i) red_v[(r0 + i) * 128 + cg] = su[i];
    __syncthreads();
    if (t < 32) {
        float s = 0.f;
        for (int x = 0; x < 128; ++x) s += red_v[t * 128 + x];
        row_s[t] = s;
    }
    __syncthreads();

    float rcp[8];
    #pragma unroll
    for (int i = 0; i < 8; ++i) rcp[i] = 1.f / row_s[r0 + i];

    pc[t] = 0.f; pc[t + 512] = 0.f;
    __syncthreads();
    #pragma unroll
    for (int j = 0; j < 8; ++j) {
        const int c = (j < 4) ? (c0 + j) : (c1 + (j - 4));
        float s = 0.f;
        #pragma unroll
        for (int i = 0; i < 8; ++i) s += acc[i][j] * rcp[i];
        atomicAdd(&pc[c], s);
    }
    __syncthreads();
    atomicAdd(&A[t],       pc[t]);
    atomicAdd(&A[t + 512], pc[t + 512]);

    if (t == 0) {
        float s = 0.f;
        for (int r = 0; r < 32; ++r) s += row_dmin[r];
        wgpart[bid] = s;
    }
}

// ---- finalize scalars ----
__global__ void k_final(const float* __restrict__ wgpart, const float* __restrict__ A,
                        float* __restrict__ out) {
    __shared__ double sd[1024];
    const int t = threadIdx.x;
    sd[t] = (double)wgpart[t];
    __syncthreads();
    for (int off = 512; off > 0; off >>= 1) {
        if (t < off) sd[t] += sd[t + off];
        __syncthreads();
    }
    if (t == 0) out[VQ_OFF] = (float)(0.25 * sd[0] / 88473600.0);
    __syncthreads();
    const double p = (double)A[t] * (1.0 / 32768.0);
    sd[t] = -p * log(p + 1e-8);
    __syncthreads();
    for (int off = 512; off > 0; off >>= 1) {
        if (t < off) sd[t] += sd[t + off];
        __syncthreads();
    }
    if (t == 0) out[ENT_OFF] = (float)sd[0];
}

// ---- q_st = basis[indices] ----
__global__ void k_gather(const float* __restrict__ basis, const int* __restrict__ idxws,
                         float* __restrict__ out) {
    const int r = blockIdx.x;
    const int idx = idxws[r];
    const float4* src = (const float4*)(basis + (size_t)idx * ED);
    float4* dst = (float4*)(out + (size_t)r * ED);
    for (int j = threadIdx.x; j < ED / 4; j += 256) dst[j] = src[j];
}

// =====================================================================
// ===================== FALLBACK (round-2, f32 VALU) ==================
// =====================================================================

__global__ void k_bsq(const float* __restrict__ basis, float* __restrict__ bsq) {
    int c = blockIdx.x;
    const float* row = basis + (size_t)c * ED;
    double s = 0.0;
    for (int j = threadIdx.x; j < ED; j += 256) { float v = row[j]; s += (double)v * (double)v; }
    __shared__ double sd[256];
    sd[threadIdx.x] = s;
    __syncthreads();
    for (int off = 128; off > 0; off >>= 1) {
        if (threadIdx.x < off) sd[threadIdx.x] += sd[threadIdx.x + off];
        __syncthreads();
    }
    if (threadIdx.x == 0) bsq[c] = (float)sd[0];
}

__global__ __launch_bounds__(256, 4)
void k_gemm1(const float* __restrict__ S, const float* __restrict__ W,
             const float* __restrict__ bproj, float* __restrict__ Z) {
    const int e0 = blockIdx.x * 64;
    const int m0 = blockIdx.y * 64;
    const int t  = threadIdx.x;
    const int tx = t & 15, ty = t >> 4;
    __shared__ float alds[32 * 68];
    __shared__ float blds[32 * 68];
    float acc[4][4] = {};
    for (int k0 = 0; k0 < DM; k0 += 32) {
        #pragma unroll
        for (int rep = 0; rep < 2; ++rep) {
            const int id  = t + rep * 256;
            const int row = id >> 3, kq = id & 7;
            const float4 va = *(const float4*)(S + (size_t)(m0 + row) * DM + k0 + 4 * kq);
            alds[(4*kq+0)*68 + row] = va.x;
            alds[(4*kq+1)*68 + row] = va.y;
            alds[(4*kq+2)*68 + row] = va.z;
            alds[(4*kq+3)*68 + row] = va.w;
            float4 vb = make_float4(0.f, 0.f, 0.f, 0.f);
            if (e0 + row < ED)
                vb = *(const float4*)(W + (size_t)(e0 + row) * DM + k0 + 4 * kq);
            blds[(4*kq+0)*68 + row] = vb.x;
            blds[(4*kq+1)*68 + row] = vb.y;
            blds[(4*kq+2)*68 + row] = vb.z;
            blds[(4*kq+3)*68 + row] = vb.w;
        }
        __syncthreads();
        #pragma unroll 8
        for (int k = 0; k < 32; ++k) {
            const float4 a = *(const float4*)&alds[k*68 + 4*ty];
            const float4 b = *(const float4*)&blds[k*68 + 4*tx];
            const float av[4] = {a.x, a.y, a.z, a.w};
            const float bv[4] = {b.x, b.y, b.z, b.w};
            #pragma unroll
            for (int i = 0; i < 4; ++i)
                #pragma unroll
                for (int j = 0; j < 4; ++j)
                    acc[i][j] = fmaf(av[i], bv[j], acc[i][j]);
        }
        __syncthreads();
    }
    const bool valid = (e0 + 4*tx + 4) <= ED;
    float4 bias = make_float4(0.f, 0.f, 0.f, 0.f);
    if (valid) bias = *(const float4*)(bproj + e0 + 4*tx);
    #pragma unroll
    for (int i = 0; i < 4; ++i) {
        if (valid) {
            float4 o;
            o.x = acc[i][0] + bias.x;
            o.y = acc[i][1] + bias.y;
            o.z = acc[i][2] + bias.z;
            o.w = acc[i][3] + bias.w;
            *(float4*)(Z + (size_t)(m0 + 4*ty + i) * ED + e0 + 4*tx) = o;
        }
    }
}

__global__ __launch_bounds__(64)
void k_zsq(const float* __restrict__ Z, float* __restrict__ zsq) {
    const int r = blockIdx.x;
    const float4* row4 = (const float4*)(Z + (size_t)r * ED);
    double s = 0.0;
    for (int q = threadIdx.x; q < ED / 4; q += 64) {
        const float4 v = row4[q];
        s += (double)v.x * v.x + (double)v.y * v.y + (double)v.z * v.z + (double)v.w * v.w;
    }
    #pragma unroll
    for (int off = 32; off > 0; off >>= 1) s += __shfl_down(s, off);
    if (threadIdx.x == 0) zsq[r] = (float)s;
}

__global__ __launch_bounds__(512, 2)
void k_dist(const float* __restrict__ Z, const float* __restrict__ basis,
            const float* __restrict__ bsq, const float* __restrict__ zsq,
            float* __restrict__ A, float* __restrict__ wgpart,
            int* __restrict__ idxws, float* __restrict__ out) {
    const int bid = blockIdx.x;
    const int wr0 = bid * 32;
    const int t   = threadIdx.x;
    const int cg  = t & 127;
    const int rq  = t >> 7;
    const int r0  = rq * 8;
    const int c0  = cg * 4;
    const int c1  = 512 + cg * 4;
    __shared__ float blds[16 * 1024];
    __shared__ float zlds[16 * 36];
    float acc[8][8];
    #pragma unroll
    for (int i = 0; i < 8; ++i)
        #pragma unroll
        for (int j = 0; j < 8; ++j) acc[i][j] = 0.f;
    for (int k0 = 0; k0 < ED; k0 += 16) {
        const bool full = (k0 + 16) <= ED;
        #pragma unroll
        for (int rep = 0; rep < 2; ++rep) {
            const int c = t + rep * 512;
            const float* bp = basis + (size_t)c * ED + k0;
            if (full) {
                const float4 v0 = *(const float4*)(bp + 0);
                const float4 v1 = *(const float4*)(bp + 4);
                const float4 v2 = *(const float4*)(bp + 8);
                const float4 v3 = *(const float4*)(bp + 12);
                blds[ 0*1024+c]=v0.x; blds[ 1*1024+c]=v0.y; blds[ 2*1024+c]=v0.z; blds[ 3*1024+c]=v0.w;
                blds[ 4*1024+c]=v1.x; blds[ 5*1024+c]=v1.y; blds[ 6*1024+c]=v1.z; blds[ 7*1024+c]=v1.w;
                blds[ 8*1024+c]=v2.x; blds[ 9*1024+c]=v2.y; blds[10*1024+c]=v2.z; blds[11*1024+c]=v2.w;
                blds[12*1024+c]=v3.x; blds[13*1024+c]=v3.y; blds[14*1024+c]=v3.z; blds[15*1024+c]=v3.w;
            } else {
                for (int kk = 0; kk < 16; ++kk)
                    blds[kk*1024 + c] = (k0 + kk < ED) ? bp[kk] : 0.f;
            }
        }
        if (t < 128) {
            const int row = t >> 2, kq = t & 3;
            const float* zp = Z + (size_t)(wr0 + row) * ED + k0 + 4 * kq;
            if (full) {
                const float4 v = *(const float4*)zp;
                zlds[(4*kq+0)*36 + row] = v.x;
                zlds[(4*kq+1)*36 + row] = v.y;
                zlds[(4*kq+2)*36 + row] = v.z;
                zlds[(4*kq+3)*36 + row] = v.w;
            } else {
                for (int j = 0; j < 4; ++j) {
                    const int k = k0 + 4*kq + j;
                    zlds[(4*kq+j)*36 + row] = (k < ED) ? zp[j] : 0.f;
                }
            }
        }
        __syncthreads();
        #pragma unroll
        for (int k = 0; k < 16; ++k) {
            const float4 z0 = *(const float4*)&zlds[k*36 + r0];
            const float4 z1 = *(const float4*)&zlds[k*36 + r0 + 4];
            const float4 b0 = *(const float4*)&blds[k*1024 + c0];
            const float4 b1 = *(const float4*)&blds[k*1024 + c1];
            const float zz[8] = {z0.x, z0.y, z0.z, z0.w, z1.x, z1.y, z1.z, z1.w};
            const float bb[8] = {b0.x, b0.y, b0.z, b0.w, b1.x, b1.y, b1.z, b1.w};
            #pragma unroll
            for (int i = 0; i < 8; ++i)
                #pragma unroll
                for (int j = 0; j < 8; ++j)
                    acc[i][j] = fmaf(zz[i], bb[j], acc[i][j]);
        }
        __syncthreads();
    }
    float* red_v    = blds;
    int*   red_i    = (int*)(blds + 4096);
    float* row_dmin = blds + 8192;
    float* row_s    = blds + 8224;
    float* pc       = blds + 8256;
    float bsqv[8], zsqv[8];
    #pragma unroll
    for (int j = 0; j < 4; ++j) { bsqv[j] = bsq[c0 + j]; bsqv[4 + j] = bsq[c1 + j]; }
    #pragma unroll
    for (int i = 0; i < 8; ++i) zsqv[i] = zsq[wr0 + r0 + i];
    #pragma unroll
    for (int i = 0; i < 8; ++i)
        #pragma unroll
        for (int j = 0; j < 8; ++j) {
            const float tv = zsqv[i] - 2.f * acc[i][j];
            acc[i][j] = tv + bsqv[j];
        }
    #pragma unroll
    for (int i = 0; i < 8; ++i) {
        float bv = acc[i][0]; int bi = c0;
        #pragma unroll
        for (int j = 1; j < 8; ++j) {
            const int c = (j < 4) ? (c0 + j) : (c1 + (j - 4));
            if (acc[i][j] < bv || (acc[i][j] == bv && c < bi)) { bv = acc[i][j]; bi = c; }
        }
        red_v[(r0 + i) * 128 + cg] = bv;
        red_i[(r0 + i) * 128 + cg] = bi;
    }
    __syncthreads();
    if (t < 32) {
        float bv = red_v[t * 128]; int bi = red_i[t * 128];
        for (int x = 1; x < 128; ++x) {
            const float v = red_v[t * 128 + x];
            const int  iv = red_i[t * 128 + x];
            if (v < bv || (v == bv && iv < bi)) { bv = v; bi = iv; }
        }
        row_dmin[t] = bv;
        idxws[wr0 + t] = bi;
        out[IDX_OFF + wr0 + t] = (float)bi;
    }
    __syncthreads();
    float su[8];
    #pragma unroll
    for (int i = 0; i < 8; ++i) {
        const float dm = row_dmin[r0 + i];
        float s = 0.f;
        #pragma unroll
        for (int j = 0; j < 8; ++j) {
            const float u = expf(dm - acc[i][j]);
            acc[i][j] = u;
            s += u;
        }
        su[i] = s;
    }
    #pragma unroll
    for (int i = 0; i < 8; ++i) red_v[(r0 + i) * 128 + cg] = su[i];
    __syncthreads();
    if (t < 32) {
        float s = 0.f;
        for (int x = 0; x < 128; ++x) s += red_v[t * 128 + x];
        row_s[t] = s;
    }
    __syncthreads();
    float rcp[8];
    #pragma unroll
    for (int i = 0; i < 8; ++i) rcp[i] = 1.f / row_s[r0 + i];
    pc[t] = 0.f; pc[t + 512] = 0.f;
    __syncthreads();
    #pragma unroll
    for (int j = 0; j < 8; ++j) {
        const int c = (j < 4) ? (c0 + j) : (c1 + (j - 4));
        float s = 0.f;
        #pragma unroll
        for (int i = 0; i < 8; ++i) s += acc[i][j] * rcp[i];
        atomicAdd(&pc[c], s);
    }
    __syncthreads();
    atomicAdd(&A[t],       pc[t]);
    atomicAdd(&A[t + 512], pc[t + 512]);
    if (t == 0) {
        float s = 0.f;
        for (int r = 0; r < 32; ++r) s += row_dmin[r];
        wgpart[bid] = s;
    }
}

// =====================================================================

extern "C" void kernel_launch(void* const* d_in, const int* in_sizes, int n_in,
                              void* d_out, int out_size, void* d_ws, size_t ws_size,
                              hipStream_t stream) {
    const float* S     = (const float*)d_in[0];  // [32768, 256]
    const float* W     = (const float*)d_in[1];  // [2700, 256]
    const float* bproj = (const float*)d_in[2];  // [2700]
    const float* basis = (const float*)d_in[3];  // [1024, 2700]
    float* out = (float*)d_out;
    float* ws  = (float*)d_ws;

    // common small regions
    float* zsq    = ws;                  // 32768
    float* A      = ws + 32768;          // 1024
    float* bsq    = ws + 33792;          // 1024
    float* wgpart = ws + 34816;          // 1024
    int*   idxws  = (int*)(ws + 35840);  // 32768

    const size_t NEED = (size_t)37129216 * sizeof(float);   // ~148.5 MB
    if (ws_size >= NEED) {
        // -------- MFMA path --------
        unsigned short* Bh = (unsigned short*)(ws + 68608);            // 1024*2720
        unsigned short* Bm = (unsigned short*)(ws + 68608 + 1392640);
        unsigned short* Wh = (unsigned short*)(ws + 68608 + 2785280);  // 2816*256
        unsigned short* Wm = (unsigned short*)(ws + 68608 + 3145728);
        float*          G  = ws + 3574784;                             // 32768*1024
        // transient allocations inside the G region (dead before k_gemm2 writes G)
        unsigned short* Sh = (unsigned short*)G;                       // 32768*256
        unsigned short* Sm = (unsigned short*)(G + 4194304);
        float*     zsqpart = G + 8388608;                              // 22*32768
        // Z planes live in the q_st output region (overwritten by k_gather at the end)
        unsigned short* Zh = (unsigned short*)out;
        unsigned short* Zm = Zh + (size_t)BKROWS * ED;

        hipMemsetAsync(A, 0, (size_t)NC * sizeof(float), stream);
        k_packS <<<BKROWS * DM / 1024, 256, 0, stream>>>(S, Sh, Sm);
        k_packW <<<WPAD * DM / 1024, 256, 0, stream>>>(W, Wh, Wm);
        k_packB <<<NC, 256, 0, stream>>>(basis, Bh, Bm, bsq);
        k_gemm1m<<<(BKROWS / 128) * NT1, 256, 0, stream>>>(Sh, Sm, Wh, Wm, bproj, Zh, Zm, zsqpart);
        k_zsqred<<<BKROWS / 256, 256, 0, stream>>>(zsqpart, zsq);
        k_gemm2 <<<512, 512, 0, stream>>>(Zh, Zm, Bh, Bm, G);
        k_post  <<<BKROWS / 32, 512, 0, stream>>>(G, bsq, zsq, A, wgpart, idxws, out);
        k_final <<<1, 1024, 0, stream>>>(wgpart, A, out);
        k_gather<<<BKROWS, 256, 0, stream>>>(basis, idxws, out);
    } else {
        // -------- fallback: round-2 f32 path --------
        float* Z = out;
        hipMemsetAsync(A, 0, (size_t)NC * sizeof(float), stream);
        k_bsq   <<<NC, 256, 0, stream>>>(basis, bsq);
        k_gemm1 <<<dim3(43, 512), 256, 0, stream>>>(S, W, bproj, Z);
        k_zsq   <<<BKROWS, 64, 0, stream>>>(Z, zsq);
        k_dist  <<<BKROWS / 32, 512, 0, stream>>>(Z, basis, bsq, zsq, A, wgpart, idxws, out);
        k_final <<<1, 1024, 0, stream>>>(wgpart, A, out);
        k_gather<<<BKROWS, 256, 0, stream>>>(basis, idxws, out);
    }
}

// Round 7
// 578.369 us; speedup vs baseline: 16.9287x; 1.5420x over previous
//
#include <hip/hip_runtime.h>
#include <math.h>

#define ED 2700     // basis_dim
#define NC 1024     // num_codes
#define DM 256      // d_model
#define BKROWS 32768

#define IDX_OFF 88473600
#define VQ_OFF  88506368
#define ENT_OFF 88506369

#define KPAD 2720     // padded K for P/M small GEMMs (5 x 544)
#define K2CH 8        // gemm2 chunks (K=256 / 32)
#define NTZ 4         // zsq n-tile partials

typedef float  f32x4  __attribute__((ext_vector_type(4)));
typedef short  bf16x8 __attribute__((ext_vector_type(8)));

__device__ inline unsigned short f2bf(float x) {
    unsigned int u = __float_as_uint(x);
    unsigned int r = (u + 0x7FFFu + ((u >> 16) & 1u)) >> 16;
    return (unsigned short)r;
}
__device__ inline float bf2f(unsigned short h) {
    return __uint_as_float(((unsigned int)h) << 16);
}

// =====================================================================
// ============================ MFMA PATH ==============================
// =====================================================================

// ---- S -> Sh/Sm bf16 planes ----
__global__ __launch_bounds__(256)
void k_packS(const float* __restrict__ S, unsigned short* __restrict__ Sh,
             unsigned short* __restrict__ Sm) {
    const size_t i4 = (size_t)blockIdx.x * 256 + threadIdx.x;
    const float4 v = *(const float4*)(S + i4 * 4);
    ushort4 hv, mv;
    unsigned short* hp = (unsigned short*)&hv;
    unsigned short* mp = (unsigned short*)&mv;
    const float xs[4] = {v.x, v.y, v.z, v.w};
    #pragma unroll
    for (int j = 0; j < 4; ++j) {
        const unsigned short h = f2bf(xs[j]);
        hp[j] = h;
        mp[j] = f2bf(xs[j] - bf2f(h));
    }
    *(ushort4*)(Sh + i4 * 4) = hv;
    *(ushort4*)(Sm + i4 * 4) = mv;
}

// ---- bsq'[c] = sum basis^2 - 2*basis.bproj (f64) ----
__global__ void k_bsq2(const float* __restrict__ basis, const float* __restrict__ bproj,
                       float* __restrict__ bsq) {
    const int c = blockIdx.x;
    const int t = threadIdx.x;
    const float* row = basis + (size_t)c * ED;
    double s2 = 0.0, sp = 0.0;
    for (int j = t; j < ED; j += 256) {
        const float x = row[j];
        s2 += (double)x * (double)x;
        sp += (double)x * (double)bproj[j];
    }
    __shared__ double sd[512];
    sd[t] = s2; sd[256 + t] = sp;
    __syncthreads();
    for (int off = 128; off > 0; off >>= 1) {
        if (t < off) { sd[t] += sd[t + off]; sd[256 + t] += sd[256 + t + off]; }
        __syncthreads();
    }
    if (t == 0) bsq[c] = (float)(sd[0] - 2.0 * sd[256]);
}

// ---- basisP = basis zero-padded to [1024][2720] ----
__global__ __launch_bounds__(256)
void k_padB(const float* __restrict__ basis, float* __restrict__ bP) {
    const int c = blockIdx.x;
    const float4* src = (const float4*)(basis + (size_t)c * ED);     // 675 float4
    float4* dst = (float4*)(bP + (size_t)c * KPAD);                  // 680 float4
    for (int q = threadIdx.x; q < KPAD / 4; q += 256)
        dst[q] = (q < ED / 4) ? src[q] : make_float4(0.f, 0.f, 0.f, 0.f);
}

// ---- WT = W^T zero-padded to [256][2720] ----
__global__ __launch_bounds__(256)
void k_padWT(const float* __restrict__ W, float* __restrict__ WT) {
    const int e0 = blockIdx.x * 64;   // 43 tiles over 2700 (covers up to 2751)
    const int d0 = blockIdx.y * 64;   // 4 tiles over 256
    __shared__ float tbuf[64][65];
    const int t  = threadIdx.x;
    const int r  = t >> 2;            // 0..63
    const int q4 = t & 3;
    #pragma unroll
    for (int j = 0; j < 4; ++j) {
        const int col = q4 * 16 + j * 4;
        const int e = e0 + r;
        float4 v = make_float4(0.f, 0.f, 0.f, 0.f);
        if (e < ED) v = *(const float4*)(W + (size_t)e * DM + d0 + col);
        tbuf[r][col + 0] = v.x; tbuf[r][col + 1] = v.y;
        tbuf[r][col + 2] = v.z; tbuf[r][col + 3] = v.w;
    }
    __syncthreads();
    #pragma unroll
    for (int j = 0; j < 4; ++j) {
        const int col = q4 * 16 + j * 4;   // e-offset within tile
        if (e0 + col < KPAD) {
            float4 o;
            o.x = tbuf[col + 0][r]; o.y = tbuf[col + 1][r];
            o.z = tbuf[col + 2][r]; o.w = tbuf[col + 3][r];
            *(float4*)(WT + (size_t)(d0 + r) * KPAD + e0 + col) = o;
        }
    }
}

// ---- uv: u[d] = sum_e W[e,d]*bproj[e]; uv[256] = ||bproj||^2 ----
__global__ __launch_bounds__(256)
void k_uv(const float* __restrict__ W, const float* __restrict__ bproj,
          float* __restrict__ uv) {
    const int d = threadIdx.x;
    double su = 0.0;
    #pragma unroll 4
    for (int e = 0; e < ED; ++e) su += (double)W[(size_t)e * DM + d] * (double)bproj[e];
    uv[d] = (float)su;
    double sv = 0.0;
    for (int e = d; e < ED; e += 256) { const double b = bproj[e]; sv += b * b; }
    __shared__ double sd[256];
    sd[d] = sv;
    __syncthreads();
    for (int off = 128; off > 0; off >>= 1) {
        if (d < off) sd[d] += sd[d + off];
        __syncthreads();
    }
    if (d == 0) uv[256] = (float)sd[0];
}

// ---- generic 64x64-tile f32 GEMM partial: Cp[ks] = A[m-tile]·B[n-tile]^T over K-slab ----
// A [*, KPAD], B [*, KPAD]; K-slab = 544 at blockIdx.z*544. nld = output row stride.
__global__ __launch_bounds__(256)
void k_gsplit(const float* __restrict__ A, const float* __restrict__ B,
              float* __restrict__ Cp, int nld) {
    const int n0  = blockIdx.x * 64;
    const int m0  = blockIdx.y * 64;
    const int k00 = blockIdx.z * 544;
    float* Cout = Cp + (size_t)blockIdx.z * (size_t)gridDim.y * 64 * nld;
    const int t  = threadIdx.x;
    const int tx = t & 15, ty = t >> 4;

    __shared__ float alds[32 * 68];
    __shared__ float blds[32 * 68];

    float acc[4][4] = {};

    for (int k0 = k00; k0 < k00 + 544; k0 += 32) {
        #pragma unroll
        for (int rep = 0; rep < 2; ++rep) {
            const int id  = t + rep * 256;
            const int row = id >> 3, kq = id & 7;
            const float4 va = *(const float4*)(A + (size_t)(m0 + row) * KPAD + k0 + 4 * kq);
            alds[(4*kq+0)*68 + row] = va.x;
            alds[(4*kq+1)*68 + row] = va.y;
            alds[(4*kq+2)*68 + row] = va.z;
            alds[(4*kq+3)*68 + row] = va.w;
            const float4 vb = *(const float4*)(B + (size_t)(n0 + row) * KPAD + k0 + 4 * kq);
            blds[(4*kq+0)*68 + row] = vb.x;
            blds[(4*kq+1)*68 + row] = vb.y;
            blds[(4*kq+2)*68 + row] = vb.z;
            blds[(4*kq+3)*68 + row] = vb.w;
        }
        __syncthreads();
        #pragma unroll 8
        for (int k = 0; k < 32; ++k) {
            const float4 a = *(const float4*)&alds[k*68 + 4*ty];
            const float4 b = *(const float4*)&blds[k*68 + 4*tx];
            const float av[4] = {a.x, a.y, a.z, a.w};
            const float bv[4] = {b.x, b.y, b.z, b.w};
            #pragma unroll
            for (int i = 0; i < 4; ++i)
                #pragma unroll
                for (int j = 0; j < 4; ++j)
                    acc[i][j] = fmaf(av[i], bv[j], acc[i][j]);
        }
        __syncthreads();
    }
    #pragma unroll
    for (int i = 0; i < 4; ++i) {
        float4 o; o.x = acc[i][0]; o.y = acc[i][1]; o.z = acc[i][2]; o.w = acc[i][3];
        *(float4*)(Cout + (size_t)(m0 + 4*ty + i) * nld + n0 + 4*tx) = o;
    }
}

// ---- reduce 5 P-partials -> Ph/Pm planes ----
__global__ __launch_bounds__(256)
void k_redP(const float* __restrict__ Pp, unsigned short* __restrict__ Ph,
            unsigned short* __restrict__ Pm) {
    const size_t idx = (size_t)blockIdx.x * 256 + threadIdx.x;   // 262144
    float s = 0.f;
    #pragma unroll
    for (int k = 0; k < 5; ++k) s += Pp[(size_t)k * 262144 + idx];
    const unsigned short h = f2bf(s);
    Ph[idx] = h;
    Pm[idx] = f2bf(s - bf2f(h));
}

// ---- reduce 5 M-partials -> M f32 ----
__global__ __launch_bounds__(256)
void k_redM(const float* __restrict__ Mp, float* __restrict__ M) {
    const size_t idx = (size_t)blockIdx.x * 256 + threadIdx.x;   // 65536
    float s = 0.f;
    #pragma unroll
    for (int k = 0; k < 5; ++k) s += Mp[(size_t)k * 65536 + idx];
    M[idx] = s;
}

// ---- zsq partials: zsq_r = S_r M S_r^T + 2 S_r.u + v  (64x64 tiles of Y=S.M) ----
__global__ __launch_bounds__(256)
void k_zsqS(const float* __restrict__ S, const float* __restrict__ M,
            const float* __restrict__ uv, float* __restrict__ zsqpart) {
    const int e0 = blockIdx.x * 64;   // 4 n-tiles over 256
    const int m0 = blockIdx.y * 64;   // 512 m-tiles
    const int t  = threadIdx.x;
    const int tx = t & 15, ty = t >> 4;

    __shared__ float alds[32 * 68];
    __shared__ float blds[32 * 68];

    float acc[4][4] = {};

    for (int k0 = 0; k0 < DM; k0 += 32) {
        #pragma unroll
        for (int rep = 0; rep < 2; ++rep) {
            const int id  = t + rep * 256;
            const int row = id >> 3, kq = id & 7;
            const float4 va = *(const float4*)(S + (size_t)(m0 + row) * DM + k0 + 4 * kq);
            alds[(4*kq+0)*68 + row] = va.x;
            alds[(4*kq+1)*68 + row] = va.y;
            alds[(4*kq+2)*68 + row] = va.z;
            alds[(4*kq+3)*68 + row] = va.w;
            const float4 vb = *(const float4*)(M + (size_t)(e0 + row) * DM + k0 + 4 * kq);
            blds[(4*kq+0)*68 + row] = vb.x;
            blds[(4*kq+1)*68 + row] = vb.y;
            blds[(4*kq+2)*68 + row] = vb.z;
            blds[(4*kq+3)*68 + row] = vb.w;
        }
        __syncthreads();
        #pragma unroll 8
        for (int k = 0; k < 32; ++k) {
            const float4 a = *(const float4*)&alds[k*68 + 4*ty];
            const float4 b = *(const float4*)&blds[k*68 + 4*tx];
            const float av[4] = {a.x, a.y, a.z, a.w};
            const float bv[4] = {b.x, b.y, b.z, b.w};
            #pragma unroll
            for (int i = 0; i < 4; ++i)
                #pragma unroll
                for (int j = 0; j < 4; ++j)
                    acc[i][j] = fmaf(av[i], bv[j], acc[i][j]);
        }
        __syncthreads();
    }

    // psum[i] = sum_j (Y[r, c_j] + 2 u[c_j]) * S[r, c_j] + v/4
    const int col0 = e0 + 4 * tx;
    const float4 uu = *(const float4*)(uv + col0);
    const float vq4 = uv[256] * 0.25f;
    float psum[4];
    #pragma unroll
    for (int i = 0; i < 4; ++i) {
        const int row = m0 + 4 * ty + i;
        const float4 sv = *(const float4*)(S + (size_t)row * DM + col0);
        psum[i] = (acc[i][0] + 2.f * uu.x) * sv.x
                + (acc[i][1] + 2.f * uu.y) * sv.y
                + (acc[i][2] + 2.f * uu.z) * sv.z
                + (acc[i][3] + 2.f * uu.w) * sv.w + vq4;
    }
    float* red = alds;
    #pragma unroll
    for (int i = 0; i < 4; ++i) red[(4*ty + i) * 16 + tx] = psum[i];
    __syncthreads();
    if (t < 64) {
        float s = 0.f;
        #pragma unroll
        for (int x = 0; x < 16; ++x) s += red[t * 16 + x];
        zsqpart[(size_t)blockIdx.x * BKROWS + m0 + t] = s;
    }
}

// ---- zsq[r] = sum over NTZ partials (f64, deterministic) ----
__global__ void k_zsqred(const float* __restrict__ part, float* __restrict__ zsq) {
    const int r = blockIdx.x * 256 + threadIdx.x;
    double s = 0.0;
    #pragma unroll
    for (int b = 0; b < NTZ; ++b) s += (double)part[(size_t)b * BKROWS + r];
    zsq[r] = (float)s;
}

// ---- K2m: G = S.P^T, 256x256 tile, 8 waves, 4-phase counted-vmcnt, K=256 ----
__global__ __launch_bounds__(512, 2)
void k_gemm2(const unsigned short* __restrict__ Sh, const unsigned short* __restrict__ Sm,
             const unsigned short* __restrict__ Ph, const unsigned short* __restrict__ Pm,
             float* __restrict__ G) {
    __shared__ unsigned short lds[2 * 32768];

    const int bid  = blockIdx.x;
    const int xcd  = bid & 7, local = bid >> 3;
    const int mt   = xcd * 16 + (local >> 2);
    const int nt   = local & 3;
    const int m0   = mt * 256, n0 = nt * 256;
    const int tid  = threadIdx.x;
    const int w    = tid >> 6, l = tid & 63;
    const int wr   = (w >> 2) * 128;
    const int wc   = (w & 3) * 64;
    const int lrow = l & 15;
    const int lu   = l >> 4;

    // half-tile staging descriptors: ht 0=A-early 1=A-late 2=B-qn0 3=B-qn1
    const unsigned short* hsrc[4][2];
    int hlds[4][2];
    #pragma unroll
    for (int ht = 0; ht < 4; ++ht) {
        #pragma unroll
        for (int j = 0; j < 2; ++j) {
            const int slot = j * 512 + tid;
            const int rwh  = slot >> 3;
            const int unit = slot & 7;
            int row; bool isB;
            if (ht == 0)      { row = (rwh & 63) + (rwh >> 6) * 128;       isB = false; }
            else if (ht == 1) { row = 64 + (rwh & 63) + (rwh >> 6) * 128;  isB = false; }
            else if (ht == 2) { row = (rwh & 31) + (rwh >> 5) * 64;        isB = true;  }
            else              { row = 32 + (rwh & 31) + (rwh >> 5) * 64;   isB = true;  }
            const int sg   = unit ^ (row & 7);
            const int pl   = sg >> 2;
            const int koff = (sg & 3) * 8;
            if (!isB) hsrc[ht][j] = (pl ? Sm : Sh) + (size_t)(m0 + row) * DM + koff;
            else      hsrc[ht][j] = (pl ? Pm : Ph) + (size_t)(n0 + row) * DM + koff;
            hlds[ht][j] = (isB ? 16384 : 0) + row * 64 + unit * 8;
        }
    }

    f32x4 acc[8][4];
    #pragma unroll
    for (int i = 0; i < 8; ++i)
        #pragma unroll
        for (int j = 0; j < 4; ++j) acc[i][j] = (f32x4){0.f, 0.f, 0.f, 0.f};

    #define STAGE_HALF(ht, ck, db) { \
        _Pragma("unroll") \
        for (int j = 0; j < 2; ++j) \
            __builtin_amdgcn_global_load_lds( \
                (const __attribute__((address_space(1))) unsigned int*)(const void*)(hsrc[ht][j] + (ck) * 32), \
                (__attribute__((address_space(3))) unsigned int*)(void*)&lds[(db) * 32768 + hlds[ht][j]], \
                16, 0, 0); \
    }

    #define LOAD_A(db, qm) { \
        const unsigned short* At = &lds[(db) * 32768]; \
        _Pragma("unroll") \
        for (int f = 0; f < 4; ++f) { \
            const int row = wr + ((qm) * 4 + f) * 16 + lrow; \
            ah[f] = *(const bf16x8*)(At + row * 64 + (((0 + lu) ^ (row & 7))) * 8); \
            am[f] = *(const bf16x8*)(At + row * 64 + (((4 + lu) ^ (row & 7))) * 8); \
        } \
    }
    #define LOAD_B(db, qn) { \
        const unsigned short* Bt = &lds[(db) * 32768 + 16384]; \
        _Pragma("unroll") \
        for (int f = 0; f < 2; ++f) { \
            const int col = wc + ((qn) * 2 + f) * 16 + lrow; \
            bh[f] = *(const bf16x8*)(Bt + col * 64 + (((0 + lu) ^ (col & 7))) * 8); \
            bm[f] = *(const bf16x8*)(Bt + col * 64 + (((4 + lu) ^ (col & 7))) * 8); \
        } \
    }
    #define MFMA_Q(qm, qn) { \
        __builtin_amdgcn_s_setprio(1); \
        _Pragma("unroll") \
        for (int i = 0; i < 4; ++i) \
            _Pragma("unroll") \
            for (int j = 0; j < 2; ++j) { \
                f32x4 cc = acc[(qm) * 4 + i][(qn) * 2 + j]; \
                cc = __builtin_amdgcn_mfma_f32_16x16x32_bf16(ah[i], bh[j], cc, 0, 0, 0); \
                cc = __builtin_amdgcn_mfma_f32_16x16x32_bf16(ah[i], bm[j], cc, 0, 0, 0); \
                cc = __builtin_amdgcn_mfma_f32_16x16x32_bf16(am[i], bh[j], cc, 0, 0, 0); \
                acc[(qm) * 4 + i][(qn) * 2 + j] = cc; \
            } \
        __builtin_amdgcn_s_setprio(0); \
    }
    #define VM8  asm volatile("s_waitcnt vmcnt(8)" ::: "memory");
    #define BAR  __builtin_amdgcn_s_barrier();

    // prologue: chunk0 all halves (dbuf0) + chunk1 AE/B0 (dbuf1)
    STAGE_HALF(0, 0, 0) STAGE_HALF(2, 0, 0) STAGE_HALF(3, 0, 0) STAGE_HALF(1, 0, 0)
    STAGE_HALF(0, 1, 1) STAGE_HALF(2, 1, 1)
    VM8
    BAR

    for (int c = 0; c < K2CH - 2; ++c) {
        const int cb = c & 1, ob = cb ^ 1;
        bf16x8 ah[4], am[4], bh[2], bm[2];
        LOAD_A(cb, 0) LOAD_B(cb, 0)
        STAGE_HALF(3, c + 1, ob)
        BAR
        MFMA_Q(0, 0)
        VM8
        BAR
        LOAD_B(cb, 1)
        STAGE_HALF(1, c + 1, ob)
        BAR
        MFMA_Q(0, 1)
        VM8
        BAR
        LOAD_A(cb, 1) LOAD_B(cb, 0)
        STAGE_HALF(0, c + 2, cb)
        BAR
        MFMA_Q(1, 0)
        BAR
        LOAD_B(cb, 1)
        STAGE_HALF(2, c + 2, cb)
        BAR
        MFMA_Q(1, 1)
        VM8
        BAR
    }

    STAGE_HALF(3, K2CH - 1, (K2CH - 1) & 1) STAGE_HALF(1, K2CH - 1, (K2CH - 1) & 1)
    asm volatile("s_waitcnt vmcnt(0)" ::: "memory");
    BAR
    #pragma unroll
    for (int e = 0; e < 2; ++e) {
        const int cb = (K2CH - 2 + e) & 1;
        bf16x8 ah[4], am[4], bh[2], bm[2];
        LOAD_A(cb, 0) LOAD_B(cb, 0)
        MFMA_Q(0, 0)
        LOAD_B(cb, 1)
        MFMA_Q(0, 1)
        LOAD_A(cb, 1) LOAD_B(cb, 0)
        MFMA_Q(1, 0)
        LOAD_B(cb, 1)
        MFMA_Q(1, 1)
    }
    #undef STAGE_HALF
    #undef LOAD_A
    #undef LOAD_B
    #undef MFMA_Q
    #undef VM8
    #undef BAR

    // C layout: col = lane&15, row = (lane>>4)*4 + reg
    #pragma unroll
    for (int fm = 0; fm < 8; ++fm)
        #pragma unroll
        for (int fn = 0; fn < 4; ++fn) {
            const int col = n0 + wc + fn * 16 + lrow;
            #pragma unroll
            for (int r = 0; r < 4; ++r) {
                const int row = m0 + wr + fm * 16 + lu * 4 + r;
                G[(size_t)row * NC + col] = acc[fm][fn][r];
            }
        }
}

// ---- K-post: dist assembly + argmin + softmax + avg_prob partials ----
__global__ __launch_bounds__(512)
void k_post(const float* __restrict__ G, const float* __restrict__ bsq,
            const float* __restrict__ zsq, float* __restrict__ A,
            float* __restrict__ wgpart, int* __restrict__ idxws,
            float* __restrict__ out) {
    const int bid = blockIdx.x;
    const int wr0 = bid * 32;
    const int t   = threadIdx.x;
    const int cg  = t & 127;
    const int rq  = t >> 7;
    const int r0  = rq * 8;
    const int c0  = cg * 4;
    const int c1  = 512 + cg * 4;

    __shared__ float sm[9280];
    float* red_v    = sm;
    int*   red_i    = (int*)(sm + 4096);
    float* row_dmin = sm + 8192;
    float* row_s    = sm + 8224;
    float* pc       = sm + 8256;

    float acc[8][8];
    #pragma unroll
    for (int i = 0; i < 8; ++i) {
        const float4 g0 = *(const float4*)&G[(size_t)(wr0 + r0 + i) * NC + c0];
        const float4 g1 = *(const float4*)&G[(size_t)(wr0 + r0 + i) * NC + c1];
        acc[i][0] = g0.x; acc[i][1] = g0.y; acc[i][2] = g0.z; acc[i][3] = g0.w;
        acc[i][4] = g1.x; acc[i][5] = g1.y; acc[i][6] = g1.z; acc[i][7] = g1.w;
    }

    float bsqv[8], zsqv[8];
    #pragma unroll
    for (int j = 0; j < 4; ++j) { bsqv[j] = bsq[c0 + j]; bsqv[4 + j] = bsq[c1 + j]; }
    #pragma unroll
    for (int i = 0; i < 8; ++i) zsqv[i] = zsq[wr0 + r0 + i];

    #pragma unroll
    for (int i = 0; i < 8; ++i)
        #pragma unroll
        for (int j = 0; j < 8; ++j) {
            const float tv = zsqv[i] - 2.f * acc[i][j];
            acc[i][j] = tv + bsqv[j];
        }

    #pragma unroll
    for (int i = 0; i < 8; ++i) {
        float bv = acc[i][0]; int bi = c0;
        #pragma unroll
        for (int j = 1; j < 8; ++j) {
            const int c = (j < 4) ? (c0 + j) : (c1 + (j - 4));
            if (acc[i][j] < bv || (acc[i][j] == bv && c < bi)) { bv = acc[i][j]; bi = c; }
        }
        red_v[(r0 + i) * 128 + cg] = bv;
        red_i[(r0 + i) * 128 + cg] = bi;
    }
    __syncthreads();
    if (t < 32) {
        float bv = red_v[t * 128]; int bi = red_i[t * 128];
        for (int x = 1; x < 128; ++x) {
            const float v = red_v[t * 128 + x];
            const int  iv = red_i[t * 128 + x];
            if (v < bv || (v == bv && iv < bi)) { bv = v; bi = iv; }
        }
        row_dmin[t] = bv;
        idxws[wr0 + t] = bi;
        out[IDX_OFF + wr0 + t] = (float)bi;
    }
    __syncthreads();

    float su[8];
    #pragma unroll
    for (int i = 0; i < 8; ++i) {
        const float dm = row_dmin[r0 + i];
        float s = 0.f;
        #pragma unroll
        for (int j = 0; j < 8; ++j) {
            const float u = expf(dm - acc[i][j]);
            acc[i][j] = u;
            s += u;
        }
        su[i] = s;
    }
    #pragma unroll
    for (int i = 0; i < 8; ++i) red_v[(r0 + i) * 128 + cg] = su[i];
    __syncthreads();
    if (t < 32) {
        float s = 0.f;
        for (int x = 0; x < 128; ++x) s += red_v[t * 128 + x];
        row_s[t] = s;
    }
    __syncthreads();

    float rcp[8];
    #pragma unroll
    for (int i = 0; i < 8; ++i) rcp[i] = 1.f / row_s[r0 + i];

    pc[t] = 0.f; pc[t + 512] = 0.f;
    __syncthreads();
    #pragma unroll
    for (int j = 0; j < 8; ++j) {
        const int c = (j < 4) ? (c0 + j) : (c1 + (j - 4));
        float s = 0.f;
        #pragma unroll
        for (int i = 0; i < 8; ++i) s += acc[i][j] * rcp[i];
        atomicAdd(&pc[c], s);
    }
    __syncthreads();
    atomicAdd(&A[t],       pc[t]);
    atomicAdd(&A[t + 512], pc[t + 512]);

    if (t == 0) {
        float s = 0.f;
        for (int r = 0; r < 32; ++r) s += row_dmin[r];
        wgpart[bid] = s;
    }
}

// ---- finalize scalars ----
__global__ void k_final(const float* __restrict__ wgpart, const float* __restrict__ A,
                        float* __restrict__ out) {
    __shared__ double sd[1024];
    const int t = threadIdx.x;
    sd[t] = (double)wgpart[t];
    __syncthreads();
    for (int off = 512; off > 0; off >>= 1) {
        if (t < off) sd[t] += sd[t + off];
        __syncthreads();
    }
    if (t == 0) out[VQ_OFF] = (float)(0.25 * sd[0] / 88473600.0);
    __syncthreads();
    const double p = (double)A[t] * (1.0 / 32768.0);
    sd[t] = -p * log(p + 1e-8);
    __syncthreads();
    for (int off = 512; off > 0; off >>= 1) {
        if (t < off) sd[t] += sd[t + off];
        __syncthreads();
    }
    if (t == 0) out[ENT_OFF] = (float)sd[0];
}

// ---- q_st = basis[indices] ----
__global__ void k_gather(const float* __restrict__ basis, const int* __restrict__ idxws,
                         float* __restrict__ out) {
    const int r = blockIdx.x;
    const int idx = idxws[r];
    const float4* src = (const float4*)(basis + (size_t)idx * ED);
    float4* dst = (float4*)(out + (size_t)r * ED);
    for (int j = threadIdx.x; j < ED / 4; j += 256) dst[j] = src[j];
}

// =====================================================================
// ===================== FALLBACK (round-2, f32 VALU) ==================
// =====================================================================

__global__ void k_bsq(const float* __restrict__ basis, float* __restrict__ bsq) {
    int c = blockIdx.x;
    const float* row = basis + (size_t)c * ED;
    double s = 0.0;
    for (int j = threadIdx.x; j < ED; j += 256) { float v = row[j]; s += (double)v * (double)v; }
    __shared__ double sd[256];
    sd[threadIdx.x] = s;
    __syncthreads();
    for (int off = 128; off > 0; off >>= 1) {
        if (threadIdx.x < off) sd[threadIdx.x] += sd[threadIdx.x + off];
        __syncthreads();
    }
    if (threadIdx.x == 0) bsq[c] = (float)sd[0];
}

__global__ __launch_bounds__(256, 4)
void k_gemm1(const float* __restrict__ S, const float* __restrict__ W,
             const float* __restrict__ bproj, float* __restrict__ Z) {
    const int e0 = blockIdx.x * 64;
    const int m0 = blockIdx.y * 64;
    const int t  = threadIdx.x;
    const int tx = t & 15, ty = t >> 4;
    __shared__ float alds[32 * 68];
    __shared__ float blds[32 * 68];
    float acc[4][4] = {};
    for (int k0 = 0; k0 < DM; k0 += 32) {
        #pragma unroll
        for (int rep = 0; rep < 2; ++rep) {
            const int id  = t + rep * 256;
            const int row = id >> 3, kq = id & 7;
            const float4 va = *(const float4*)(S + (size_t)(m0 + row) * DM + k0 + 4 * kq);
            alds[(4*kq+0)*68 + row] = va.x;
            alds[(4*kq+1)*68 + row] = va.y;
            alds[(4*kq+2)*68 + row] = va.z;
            alds[(4*kq+3)*68 + row] = va.w;
            float4 vb = make_float4(0.f, 0.f, 0.f, 0.f);
            if (e0 + row < ED)
                vb = *(const float4*)(W + (size_t)(e0 + row) * DM + k0 + 4 * kq);
            blds[(4*kq+0)*68 + row] = vb.x;
            blds[(4*kq+1)*68 + row] = vb.y;
            blds[(4*kq+2)*68 + row] = vb.z;
            blds[(4*kq+3)*68 + row] = vb.w;
        }
        __syncthreads();
        #pragma unroll 8
        for (int k = 0; k < 32; ++k) {
            const float4 a = *(const float4*)&alds[k*68 + 4*ty];
            const float4 b = *(const float4*)&blds[k*68 + 4*tx];
            const float av[4] = {a.x, a.y, a.z, a.w};
            const float bv[4] = {b.x, b.y, b.z, b.w};
            #pragma unroll
            for (int i = 0; i < 4; ++i)
                #pragma unroll
                for (int j = 0; j < 4; ++j)
                    acc[i][j] = fmaf(av[i], bv[j], acc[i][j]);
        }
        __syncthreads();
    }
    const bool valid = (e0 + 4*tx + 4) <= ED;
    float4 bias = make_float4(0.f, 0.f, 0.f, 0.f);
    if (valid) bias = *(const float4*)(bproj + e0 + 4*tx);
    #pragma unroll
    for (int i = 0; i < 4; ++i) {
        if (valid) {
            float4 o;
            o.x = acc[i][0] + bias.x;
            o.y = acc[i][1] + bias.y;
            o.z = acc[i][2] + bias.z;
            o.w = acc[i][3] + bias.w;
            *(float4*)(Z + (size_t)(m0 + 4*ty + i) * ED + e0 + 4*tx) = o;
        }
    }
}

__global__ __launch_bounds__(64)
void k_zsq(const float* __restrict__ Z, float* __restrict__ zsq) {
    const int r = blockIdx.x;
    const float4* row4 = (const float4*)(Z + (size_t)r * ED);
    double s = 0.0;
    for (int q = threadIdx.x; q < ED / 4; q += 64) {
        const float4 v = row4[q];
        s += (double)v.x * v.x + (double)v.y * v.y + (double)v.z * v.z + (double)v.w * v.w;
    }
    #pragma unroll
    for (int off = 32; off > 0; off >>= 1) s += __shfl_down(s, off);
    if (threadIdx.x == 0) zsq[r] = (float)s;
}

__global__ __launch_bounds__(512, 2)
void k_dist(const float* __restrict__ Z, const float* __restrict__ basis,
            const float* __restrict__ bsq, const float* __restrict__ zsq,
            float* __restrict__ A, float* __restrict__ wgpart,
            int* __restrict__ idxws, float* __restrict__ out) {
    const int bid = blockIdx.x;
    const int wr0 = bid * 32;
    const int t   = threadIdx.x;
    const int cg  = t & 127;
    const int rq  = t >> 7;
    const int r0  = rq * 8;
    const int c0  = cg * 4;
    const int c1  = 512 + cg * 4;
    __shared__ float blds[16 * 1024];
    __shared__ float zlds[16 * 36];
    float acc[8][8];
    #pragma unroll
    for (int i = 0; i < 8; ++i)
        #pragma unroll
        for (int j = 0; j < 8; ++j) acc[i][j] = 0.f;
    for (int k0 = 0; k0 < ED; k0 += 16) {
        const bool full = (k0 + 16) <= ED;
        #pragma unroll
        for (int rep = 0; rep < 2; ++rep) {
            const int c = t + rep * 512;
            const float* bp = basis + (size_t)c * ED + k0;
            if (full) {
                const float4 v0 = *(const float4*)(bp + 0);
                const float4 v1 = *(const float4*)(bp + 4);
                const float4 v2 = *(const float4*)(bp + 8);
                const float4 v3 = *(const float4*)(bp + 12);
                blds[ 0*1024+c]=v0.x; blds[ 1*1024+c]=v0.y; blds[ 2*1024+c]=v0.z; blds[ 3*1024+c]=v0.w;
                blds[ 4*1024+c]=v1.x; blds[ 5*1024+c]=v1.y; blds[ 6*1024+c]=v1.z; blds[ 7*1024+c]=v1.w;
                blds[ 8*1024+c]=v2.x; blds[ 9*1024+c]=v2.y; blds[10*1024+c]=v2.z; blds[11*1024+c]=v2.w;
                blds[12*1024+c]=v3.x; blds[13*1024+c]=v3.y; blds[14*1024+c]=v3.z; blds[15*1024+c]=v3.w;
            } else {
                for (int kk = 0; kk < 16; ++kk)
                    blds[kk*1024 + c] = (k0 + kk < ED) ? bp[kk] : 0.f;
            }
        }
        if (t < 128) {
            const int row = t >> 2, kq = t & 3;
            const float* zp = Z + (size_t)(wr0 + row) * ED + k0 + 4 * kq;
            if (full) {
                const float4 v = *(const float4*)zp;
                zlds[(4*kq+0)*36 + row] = v.x;
                zlds[(4*kq+1)*36 + row] = v.y;
                zlds[(4*kq+2)*36 + row] = v.z;
                zlds[(4*kq+3)*36 + row] = v.w;
            } else {
                for (int j = 0; j < 4; ++j) {
                    const int k = k0 + 4*kq + j;
                    zlds[(4*kq+j)*36 + row] = (k < ED) ? zp[j] : 0.f;
                }
            }
        }
        __syncthreads();
        #pragma unroll
        for (int k = 0; k < 16; ++k) {
            const float4 z0 = *(const float4*)&zlds[k*36 + r0];
            const float4 z1 = *(const float4*)&zlds[k*36 + r0 + 4];
            const float4 b0 = *(const float4*)&blds[k*1024 + c0];
            const float4 b1 = *(const float4*)&blds[k*1024 + c1];
            const float zz[8] = {z0.x, z0.y, z0.z, z0.w, z1.x, z1.y, z1.z, z1.w};
            const float bb[8] = {b0.x, b0.y, b0.z, b0.w, b1.x, b1.y, b1.z, b1.w};
            #pragma unroll
            for (int i = 0; i < 8; ++i)
                #pragma unroll
                for (int j = 0; j < 8; ++j)
                    acc[i][j] = fmaf(zz[i], bb[j], acc[i][j]);
        }
        __syncthreads();
    }
    float* red_v    = blds;
    int*   red_i    = (int*)(blds + 4096);
    float* row_dmin = blds + 8192;
    float* row_s    = blds + 8224;
    float* pc       = blds + 8256;
    float bsqv[8], zsqv[8];
    #pragma unroll
    for (int j = 0; j < 4; ++j) { bsqv[j] = bsq[c0 + j]; bsqv[4 + j] = bsq[c1 + j]; }
    #pragma unroll
    for (int i = 0; i < 8; ++i) zsqv[i] = zsq[wr0 + r0 + i];
    #pragma unroll
    for (int i = 0; i < 8; ++i)
        #pragma unroll
        for (int j = 0; j < 8; ++j) {
            const float tv = zsqv[i] - 2.f * acc[i][j];
            acc[i][j] = tv + bsqv[j];
        }
    #pragma unroll
    for (int i = 0; i < 8; ++i) {
        float bv = acc[i][0]; int bi = c0;
        #pragma unroll
        for (int j = 1; j < 8; ++j) {
            const int c = (j < 4) ? (c0 + j) : (c1 + (j - 4));
            if (acc[i][j] < bv || (acc[i][j] == bv && c < bi)) { bv = acc[i][j]; bi = c; }
        }
        red_v[(r0 + i) * 128 + cg] = bv;
        red_i[(r0 + i) * 128 + cg] = bi;
    }
    __syncthreads();
    if (t < 32) {
        float bv = red_v[t * 128]; int bi = red_i[t * 128];
        for (int x = 1; x < 128; ++x) {
            const float v = red_v[t * 128 + x];
            const int  iv = red_i[t * 128 + x];
            if (v < bv || (v == bv && iv < bi)) { bv = v; bi = iv; }
        }
        row_dmin[t] = bv;
        idxws[wr0 + t] = bi;
        out[IDX_OFF + wr0 + t] = (float)bi;
    }
    __syncthreads();
    float su[8];
    #pragma unroll
    for (int i = 0; i < 8; ++i) {
        const float dm = row_dmin[r0 + i];
        float s = 0.f;
        #pragma unroll
        for (int j = 0; j < 8; ++j) {
            const float u = expf(dm - acc[i][j]);
            acc[i][j] = u;
            s += u;
        }
        su[i] = s;
    }
    #pragma unroll
    for (int i = 0; i < 8; ++i) red_v[(r0 + i) * 128 + cg] = su[i];
    __syncthreads();
    if (t < 32) {
        float s = 0.f;
        for (int x = 0; x < 128; ++x) s += red_v[t * 128 + x];
        row_s[t] = s;
    }
    __syncthreads();
    float rcp[8];
    #pragma unroll
    for (int i = 0; i < 8; ++i) rcp[i] = 1.f / row_s[r0 + i];
    pc[t] = 0.f; pc[t + 512] = 0.f;
    __syncthreads();
    #pragma unroll
    for (int j = 0; j < 8; ++j) {
        const int c = (j < 4) ? (c0 + j) : (c1 + (j - 4));
        float s = 0.f;
        #pragma unroll
        for (int i = 0; i < 8; ++i) s += acc[i][j] * rcp[i];
        atomicAdd(&pc[c], s);
    }
    __syncthreads();
    atomicAdd(&A[t],       pc[t]);
    atomicAdd(&A[t + 512], pc[t + 512]);
    if (t == 0) {
        float s = 0.f;
        for (int r = 0; r < 32; ++r) s += row_dmin[r];
        wgpart[bid] = s;
    }
}

// =====================================================================

extern "C" void kernel_launch(void* const* d_in, const int* in_sizes, int n_in,
                              void* d_out, int out_size, void* d_ws, size_t ws_size,
                              hipStream_t stream) {
    const float* S     = (const float*)d_in[0];  // [32768, 256]
    const float* W     = (const float*)d_in[1];  // [2700, 256]
    const float* bproj = (const float*)d_in[2];  // [2700]
    const float* basis = (const float*)d_in[3];  // [1024, 2700]
    float* out = (float*)d_out;
    float* ws  = (float*)d_ws;

    // common small regions
    float* zsq    = ws;                  // 32768
    float* A      = ws + 32768;          // 1024
    float* bsq    = ws + 33792;          // 1024
    float* wgpart = ws + 34816;          // 1024
    int*   idxws  = (int*)(ws + 35840);  // 32768

    // ws floats: 68608 small + Ph/Pm 262144 + G 33554432 = 33,885,184 (~135.5 MB)
    const size_t NEED = (size_t)33885184 * sizeof(float);
    if (ws_size >= NEED) {
        // -------- MFMA path (reassociated: G = S.(basis.W)^T) --------
        unsigned short* Ph = (unsigned short*)(ws + 68608);            // 1024*256 ush
        unsigned short* Pm = (unsigned short*)(ws + 68608 + 131072);
        float*          G  = ws + 330752;                              // 32768*1024
        // transients aliased into G (all dead before k_gemm2 writes G)
        float* basisP  = G;                  // 1024*2720 = 2785280
        float* WT      = G + 2785280;        // 256*2720  = 696320
        float* uv      = G + 3481600;        // 257 (u[256], v)
        float* Pp      = G + 3481984;        // 5*262144 = 1310720
        float* Mp      = G + 4792704;        // 5*65536  = 327680
        float* Mm      = G + 5120384;        // 65536
        float* zsqpart = G + 5185920;        // 4*32768  = 131072 -> ends 5316992
        // S planes live in q_st output region (dead before k_gather writes q_st)
        unsigned short* Sh = (unsigned short*)out;                     // 32768*256 ush
        unsigned short* Sm = Sh + (size_t)BKROWS * DM;

        hipMemsetAsync(A, 0, (size_t)NC * sizeof(float), stream);
        k_packS <<<BKROWS * DM / 1024, 256, 0, stream>>>(S, Sh, Sm);
        k_bsq2  <<<NC, 256, 0, stream>>>(basis, bproj, bsq);
        k_padB  <<<NC, 256, 0, stream>>>(basis, basisP);
        k_padWT <<<dim3(43, 4), 256, 0, stream>>>(W, WT);
        k_uv    <<<1, 256, 0, stream>>>(W, bproj, uv);
        k_gsplit<<<dim3(4, 16, 5), 256, 0, stream>>>(basisP, WT, Pp, 256);  // P partials
        k_gsplit<<<dim3(4, 4, 5),  256, 0, stream>>>(WT, WT, Mp, 256);      // M partials
        k_redP  <<<1024, 256, 0, stream>>>(Pp, Ph, Pm);
        k_redM  <<<256, 256, 0, stream>>>(Mp, Mm);
        k_zsqS  <<<dim3(NTZ, 512), 256, 0, stream>>>(S, Mm, uv, zsqpart);
        k_zsqred<<<BKROWS / 256, 256, 0, stream>>>(zsqpart, zsq);
        k_gemm2 <<<512, 512, 0, stream>>>(Sh, Sm, Ph, Pm, G);
        k_post  <<<BKROWS / 32, 512, 0, stream>>>(G, bsq, zsq, A, wgpart, idxws, out);
        k_final <<<1, 1024, 0, stream>>>(wgpart, A, out);
        k_gather<<<BKROWS, 256, 0, stream>>>(basis, idxws, out);
    } else {
        // -------- fallback: round-2 f32 path --------
        float* Z = out;
        hipMemsetAsync(A, 0, (size_t)NC * sizeof(float), stream);
        k_bsq   <<<NC, 256, 0, stream>>>(basis, bsq);
        k_gemm1 <<<dim3(43, 512), 256, 0, stream>>>(S, W, bproj, Z);
        k_zsq   <<<BKROWS, 64, 0, stream>>>(Z, zsq);
        k_dist  <<<BKROWS / 32, 512, 0, stream>>>(Z, basis, bsq, zsq, A, wgpart, idxws, out);
        k_final <<<1, 1024, 0, stream>>>(wgpart, A, out);
        k_gather<<<BKROWS, 256, 0, stream>>>(basis, idxws, out);
    }
}

// Round 9
// 404.555 us; speedup vs baseline: 24.2020x; 1.4296x over previous
//
#include <hip/hip_runtime.h>
#include <math.h>

#define ED 2700     // basis_dim
#define NC 1024     // num_codes
#define DM 256      // d_model
#define BKROWS 32768

#define IDX_OFF 88473600
#define VQ_OFF  88506368
#define ENT_OFF 88506369

#define KPAD 2720     // padded K for P/M small GEMMs (5 x 544)
#define K2CH 8        // gemm2 chunks (K=256 / 32)
#define NTZ 4         // zsq n-tile partials

typedef float  f32x4  __attribute__((ext_vector_type(4)));
typedef short  bf16x8 __attribute__((ext_vector_type(8)));

__device__ inline unsigned short f2bf(float x) {
    unsigned int u = __float_as_uint(x);
    unsigned int r = (u + 0x7FFFu + ((u >> 16) & 1u)) >> 16;
    return (unsigned short)r;
}
__device__ inline float bf2f(unsigned short h) {
    return __uint_as_float(((unsigned int)h) << 16);
}

// =====================================================================
// ============================ MFMA PATH ==============================
// =====================================================================

// ---- S -> Sh/Sm bf16 planes ----
__global__ __launch_bounds__(256)
void k_packS(const float* __restrict__ S, unsigned short* __restrict__ Sh,
             unsigned short* __restrict__ Sm) {
    const size_t i4 = (size_t)blockIdx.x * 256 + threadIdx.x;
    const float4 v = *(const float4*)(S + i4 * 4);
    ushort4 hv, mv;
    unsigned short* hp = (unsigned short*)&hv;
    unsigned short* mp = (unsigned short*)&mv;
    const float xs[4] = {v.x, v.y, v.z, v.w};
    #pragma unroll
    for (int j = 0; j < 4; ++j) {
        const unsigned short h = f2bf(xs[j]);
        hp[j] = h;
        mp[j] = f2bf(xs[j] - bf2f(h));
    }
    *(ushort4*)(Sh + i4 * 4) = hv;
    *(ushort4*)(Sm + i4 * 4) = mv;
}

// ---- bsq'[c] = sum basis^2 - 2*basis.bproj (f64) ----
__global__ void k_bsq2(const float* __restrict__ basis, const float* __restrict__ bproj,
                       float* __restrict__ bsq) {
    const int c = blockIdx.x;
    const int t = threadIdx.x;
    const float* row = basis + (size_t)c * ED;
    double s2 = 0.0, sp = 0.0;
    for (int j = t; j < ED; j += 256) {
        const float x = row[j];
        s2 += (double)x * (double)x;
        sp += (double)x * (double)bproj[j];
    }
    __shared__ double sd[512];
    sd[t] = s2; sd[256 + t] = sp;
    __syncthreads();
    for (int off = 128; off > 0; off >>= 1) {
        if (t < off) { sd[t] += sd[t + off]; sd[256 + t] += sd[256 + t + off]; }
        __syncthreads();
    }
    if (t == 0) bsq[c] = (float)(sd[0] - 2.0 * sd[256]);
}

// ---- basisP = basis zero-padded to [1024][2720] ----
__global__ __launch_bounds__(256)
void k_padB(const float* __restrict__ basis, float* __restrict__ bP) {
    const int c = blockIdx.x;
    const float4* src = (const float4*)(basis + (size_t)c * ED);
    float4* dst = (float4*)(bP + (size_t)c * KPAD);
    for (int q = threadIdx.x; q < KPAD / 4; q += 256)
        dst[q] = (q < ED / 4) ? src[q] : make_float4(0.f, 0.f, 0.f, 0.f);
}

// ---- WT = W^T zero-padded to [256][2720] ----
__global__ __launch_bounds__(256)
void k_padWT(const float* __restrict__ W, float* __restrict__ WT) {
    const int e0 = blockIdx.x * 64;
    const int d0 = blockIdx.y * 64;
    __shared__ float tbuf[64][65];
    const int t  = threadIdx.x;
    const int r  = t >> 2;
    const int q4 = t & 3;
    #pragma unroll
    for (int j = 0; j < 4; ++j) {
        const int col = q4 * 16 + j * 4;
        const int e = e0 + r;
        float4 v = make_float4(0.f, 0.f, 0.f, 0.f);
        if (e < ED) v = *(const float4*)(W + (size_t)e * DM + d0 + col);
        tbuf[r][col + 0] = v.x; tbuf[r][col + 1] = v.y;
        tbuf[r][col + 2] = v.z; tbuf[r][col + 3] = v.w;
    }
    __syncthreads();
    #pragma unroll
    for (int j = 0; j < 4; ++j) {
        const int col = q4 * 16 + j * 4;
        if (e0 + col < KPAD) {
            float4 o;
            o.x = tbuf[col + 0][r]; o.y = tbuf[col + 1][r];
            o.z = tbuf[col + 2][r]; o.w = tbuf[col + 3][r];
            *(float4*)(WT + (size_t)(d0 + r) * KPAD + e0 + col) = o;
        }
    }
}

// ---- k_uv2: u[d] = WT[d].bproj (blocks 0..255); v = ||bproj||^2 (block 256) ----
__global__ __launch_bounds__(256)
void k_uv2(const float* __restrict__ WT, const float* __restrict__ bproj,
           float* __restrict__ uv) {
    const int b = blockIdx.x;
    const int t = threadIdx.x;
    double s = 0.0;
    if (b < 256) {
        const float* row = WT + (size_t)b * KPAD;
        for (int j = t; j < ED; j += 256) s += (double)row[j] * (double)bproj[j];
    } else {
        for (int j = t; j < ED; j += 256) { const double x = bproj[j]; s += x * x; }
    }
    __shared__ double sd[256];
    sd[t] = s;
    __syncthreads();
    for (int off = 128; off > 0; off >>= 1) {
        if (t < off) sd[t] += sd[t + off];
        __syncthreads();
    }
    if (t == 0) uv[b] = (float)sd[0];
}

// ---- generic 64x64-tile f32 GEMM partial over K-slab of 544 ----
__global__ __launch_bounds__(256)
void k_gsplit(const float* __restrict__ A, const float* __restrict__ B,
              float* __restrict__ Cp, int nld) {
    const int n0  = blockIdx.x * 64;
    const int m0  = blockIdx.y * 64;
    const int k00 = blockIdx.z * 544;
    float* Cout = Cp + (size_t)blockIdx.z * (size_t)gridDim.y * 64 * nld;
    const int t  = threadIdx.x;
    const int tx = t & 15, ty = t >> 4;

    __shared__ float alds[32 * 68];
    __shared__ float blds[32 * 68];

    float acc[4][4] = {};

    for (int k0 = k00; k0 < k00 + 544; k0 += 32) {
        #pragma unroll
        for (int rep = 0; rep < 2; ++rep) {
            const int id  = t + rep * 256;
            const int row = id >> 3, kq = id & 7;
            const float4 va = *(const float4*)(A + (size_t)(m0 + row) * KPAD + k0 + 4 * kq);
            alds[(4*kq+0)*68 + row] = va.x;
            alds[(4*kq+1)*68 + row] = va.y;
            alds[(4*kq+2)*68 + row] = va.z;
            alds[(4*kq+3)*68 + row] = va.w;
            const float4 vb = *(const float4*)(B + (size_t)(n0 + row) * KPAD + k0 + 4 * kq);
            blds[(4*kq+0)*68 + row] = vb.x;
            blds[(4*kq+1)*68 + row] = vb.y;
            blds[(4*kq+2)*68 + row] = vb.z;
            blds[(4*kq+3)*68 + row] = vb.w;
        }
        __syncthreads();
        #pragma unroll 8
        for (int k = 0; k < 32; ++k) {
            const float4 a = *(const float4*)&alds[k*68 + 4*ty];
            const float4 b = *(const float4*)&blds[k*68 + 4*tx];
            const float av[4] = {a.x, a.y, a.z, a.w};
            const float bv[4] = {b.x, b.y, b.z, b.w};
            #pragma unroll
            for (int i = 0; i < 4; ++i)
                #pragma unroll
                for (int j = 0; j < 4; ++j)
                    acc[i][j] = fmaf(av[i], bv[j], acc[i][j]);
        }
        __syncthreads();
    }
    #pragma unroll
    for (int i = 0; i < 4; ++i) {
        float4 o; o.x = acc[i][0]; o.y = acc[i][1]; o.z = acc[i][2]; o.w = acc[i][3];
        *(float4*)(Cout + (size_t)(m0 + 4*ty + i) * nld + n0 + 4*tx) = o;
    }
}

// ---- reduce 5 P-partials -> Ph/Pm planes ----
__global__ __launch_bounds__(256)
void k_redP(const float* __restrict__ Pp, unsigned short* __restrict__ Ph,
            unsigned short* __restrict__ Pm) {
    const size_t idx = (size_t)blockIdx.x * 256 + threadIdx.x;
    float s = 0.f;
    #pragma unroll
    for (int k = 0; k < 5; ++k) s += Pp[(size_t)k * 262144 + idx];
    const unsigned short h = f2bf(s);
    Ph[idx] = h;
    Pm[idx] = f2bf(s - bf2f(h));
}

// ---- reduce 5 M-partials -> M f32 ----
__global__ __launch_bounds__(256)
void k_redM(const float* __restrict__ Mp, float* __restrict__ M) {
    const size_t idx = (size_t)blockIdx.x * 256 + threadIdx.x;
    float s = 0.f;
    #pragma unroll
    for (int k = 0; k < 5; ++k) s += Mp[(size_t)k * 65536 + idx];
    M[idx] = s;
}

// ---- zsq partials: zsq_r = S_r M S_r^T + 2 S_r.u + v ----
__global__ __launch_bounds__(256)
void k_zsqS(const float* __restrict__ S, const float* __restrict__ M,
            const float* __restrict__ uv, float* __restrict__ zsqpart) {
    const int e0 = blockIdx.x * 64;
    const int m0 = blockIdx.y * 64;
    const int t  = threadIdx.x;
    const int tx = t & 15, ty = t >> 4;

    __shared__ float alds[32 * 68];
    __shared__ float blds[32 * 68];

    float acc[4][4] = {};

    for (int k0 = 0; k0 < DM; k0 += 32) {
        #pragma unroll
        for (int rep = 0; rep < 2; ++rep) {
            const int id  = t + rep * 256;
            const int row = id >> 3, kq = id & 7;
            const float4 va = *(const float4*)(S + (size_t)(m0 + row) * DM + k0 + 4 * kq);
            alds[(4*kq+0)*68 + row] = va.x;
            alds[(4*kq+1)*68 + row] = va.y;
            alds[(4*kq+2)*68 + row] = va.z;
            alds[(4*kq+3)*68 + row] = va.w;
            const float4 vb = *(const float4*)(M + (size_t)(e0 + row) * DM + k0 + 4 * kq);
            blds[(4*kq+0)*68 + row] = vb.x;
            blds[(4*kq+1)*68 + row] = vb.y;
            blds[(4*kq+2)*68 + row] = vb.z;
            blds[(4*kq+3)*68 + row] = vb.w;
        }
        __syncthreads();
        #pragma unroll 8
        for (int k = 0; k < 32; ++k) {
            const float4 a = *(const float4*)&alds[k*68 + 4*ty];
            const float4 b = *(const float4*)&blds[k*68 + 4*tx];
            const float av[4] = {a.x, a.y, a.z, a.w};
            const float bv[4] = {b.x, b.y, b.z, b.w};
            #pragma unroll
            for (int i = 0; i < 4; ++i)
                #pragma unroll
                for (int j = 0; j < 4; ++j)
                    acc[i][j] = fmaf(av[i], bv[j], acc[i][j]);
        }
        __syncthreads();
    }

    const int col0 = e0 + 4 * tx;
    const float4 uu = *(const float4*)(uv + col0);
    const float vq4 = uv[256] * 0.25f;
    float psum[4];
    #pragma unroll
    for (int i = 0; i < 4; ++i) {
        const int row = m0 + 4 * ty + i;
        const float4 sv = *(const float4*)(S + (size_t)row * DM + col0);
        psum[i] = (acc[i][0] + 2.f * uu.x) * sv.x
                + (acc[i][1] + 2.f * uu.y) * sv.y
                + (acc[i][2] + 2.f * uu.z) * sv.z
                + (acc[i][3] + 2.f * uu.w) * sv.w + vq4;
    }
    float* red = alds;
    #pragma unroll
    for (int i = 0; i < 4; ++i) red[(4*ty + i) * 16 + tx] = psum[i];
    __syncthreads();
    if (t < 64) {
        float s = 0.f;
        #pragma unroll
        for (int x = 0; x < 16; ++x) s += red[t * 16 + x];
        zsqpart[(size_t)blockIdx.x * BKROWS + m0 + t] = s;
    }
}

// ---- zsq[r] = sum over NTZ partials (f64, deterministic) ----
__global__ void k_zsqred(const float* __restrict__ part, float* __restrict__ zsq) {
    const int r = blockIdx.x * 256 + threadIdx.x;
    double s = 0.0;
    #pragma unroll
    for (int b = 0; b < NTZ; ++b) s += (double)part[(size_t)b * BKROWS + r];
    zsq[r] = (float)s;
}

// ---- K2m: G = S.P^T, 256x256 tile, 8 waves, 4-phase counted-vmcnt, K=256 ----
__global__ __launch_bounds__(512, 2)
void k_gemm2(const unsigned short* __restrict__ Zh, const unsigned short* __restrict__ Zm,
             const unsigned short* __restrict__ Bh, const unsigned short* __restrict__ Bm,
             float* __restrict__ G) {
    __shared__ unsigned short lds[2 * 32768];

    const int bid  = blockIdx.x;
    const int xcd  = bid & 7, local = bid >> 3;
    const int mt   = xcd * 16 + (local >> 2);
    const int nt   = local & 3;
    const int m0   = mt * 256, n0 = nt * 256;
    const int tid  = threadIdx.x;
    const int w    = tid >> 6, l = tid & 63;
    const int wr   = (w >> 2) * 128;
    const int wc   = (w & 3) * 64;
    const int lrow = l & 15;
    const int lu   = l >> 4;

    // half-tile staging descriptors: ht 0=A-early 1=A-late 2=B-qn0 3=B-qn1
    const unsigned short* hsrc[4][2];
    int hlds[4][2];
    #pragma unroll
    for (int ht = 0; ht < 4; ++ht) {
        #pragma unroll
        for (int j = 0; j < 2; ++j) {
            const int slot = j * 512 + tid;
            const int rwh  = slot >> 3;
            const int unit = slot & 7;
            int row; bool isB;
            if (ht == 0)      { row = (rwh & 63) + (rwh >> 6) * 128;       isB = false; }
            else if (ht == 1) { row = 64 + (rwh & 63) + (rwh >> 6) * 128;  isB = false; }
            else if (ht == 2) { row = (rwh & 31) + (rwh >> 5) * 64;        isB = true;  }
            else              { row = 32 + (rwh & 31) + (rwh >> 5) * 64;   isB = true;  }
            const int sg   = unit ^ (row & 7);
            const int pl   = sg >> 2;
            const int koff = (sg & 3) * 8;
            if (!isB) hsrc[ht][j] = (pl ? Zm : Zh) + (size_t)(m0 + row) * DM + koff;
            else      hsrc[ht][j] = (pl ? Bm : Bh) + (size_t)(n0 + row) * DM + koff;
            hlds[ht][j] = (isB ? 16384 : 0) + row * 64 + unit * 8;
        }
    }

    f32x4 acc[8][4];
    #pragma unroll
    for (int i = 0; i < 8; ++i)
        #pragma unroll
        for (int j = 0; j < 4; ++j) acc[i][j] = (f32x4){0.f, 0.f, 0.f, 0.f};

    #define STAGE_HALF(ht, ck, db) { \
        _Pragma("unroll") \
        for (int j = 0; j < 2; ++j) \
            __builtin_amdgcn_global_load_lds( \
                (const __attribute__((address_space(1))) unsigned int*)(const void*)(hsrc[ht][j] + (ck) * 32), \
                (__attribute__((address_space(3))) unsigned int*)(void*)&lds[(db) * 32768 + hlds[ht][j]], \
                16, 0, 0); \
    }

    #define LOAD_A(db, qm) { \
        const unsigned short* At = &lds[(db) * 32768]; \
        _Pragma("unroll") \
        for (int f = 0; f < 4; ++f) { \
            const int row = wr + ((qm) * 4 + f) * 16 + lrow; \
            ah[f] = *(const bf16x8*)(At + row * 64 + (((0 + lu) ^ (row & 7))) * 8); \
            am[f] = *(const bf16x8*)(At + row * 64 + (((4 + lu) ^ (row & 7))) * 8); \
        } \
    }
    #define LOAD_B(db, qn) { \
        const unsigned short* Bt = &lds[(db) * 32768 + 16384]; \
        _Pragma("unroll") \
        for (int f = 0; f < 2; ++f) { \
            const int col = wc + ((qn) * 2 + f) * 16 + lrow; \
            bh[f] = *(const bf16x8*)(Bt + col * 64 + (((0 + lu) ^ (col & 7))) * 8); \
            bm[f] = *(const bf16x8*)(Bt + col * 64 + (((4 + lu) ^ (col & 7))) * 8); \
        } \
    }
    #define MFMA_Q(qm, qn) { \
        __builtin_amdgcn_s_setprio(1); \
        _Pragma("unroll") \
        for (int i = 0; i < 4; ++i) \
            _Pragma("unroll") \
            for (int j = 0; j < 2; ++j) { \
                f32x4 cc = acc[(qm) * 4 + i][(qn) * 2 + j]; \
                cc = __builtin_amdgcn_mfma_f32_16x16x32_bf16(ah[i], bh[j], cc, 0, 0, 0); \
                cc = __builtin_amdgcn_mfma_f32_16x16x32_bf16(ah[i], bm[j], cc, 0, 0, 0); \
                cc = __builtin_amdgcn_mfma_f32_16x16x32_bf16(am[i], bh[j], cc, 0, 0, 0); \
                acc[(qm) * 4 + i][(qn) * 2 + j] = cc; \
            } \
        __builtin_amdgcn_s_setprio(0); \
    }
    #define VM8  asm volatile("s_waitcnt vmcnt(8)" ::: "memory");
    #define BAR  __builtin_amdgcn_s_barrier();

    // prologue: chunk0 all halves (dbuf0) + chunk1 AE/B0 (dbuf1)
    STAGE_HALF(0, 0, 0) STAGE_HALF(2, 0, 0) STAGE_HALF(3, 0, 0) STAGE_HALF(1, 0, 0)
    STAGE_HALF(0, 1, 1) STAGE_HALF(2, 1, 1)
    VM8
    BAR

    for (int c = 0; c < K2CH - 2; ++c) {
        const int cb = c & 1, ob = cb ^ 1;
        bf16x8 ah[4], am[4], bh[2], bm[2];
        LOAD_A(cb, 0) LOAD_B(cb, 0)
        STAGE_HALF(3, c + 1, ob)
        BAR
        MFMA_Q(0, 0)
        VM8
        BAR
        LOAD_B(cb, 1)
        STAGE_HALF(1, c + 1, ob)
        BAR
        MFMA_Q(0, 1)
        VM8
        BAR
        LOAD_A(cb, 1) LOAD_B(cb, 0)
        STAGE_HALF(0, c + 2, cb)
        BAR
        MFMA_Q(1, 0)
        BAR
        LOAD_B(cb, 1)
        STAGE_HALF(2, c + 2, cb)
        BAR
        MFMA_Q(1, 1)
        VM8
        BAR
    }

    STAGE_HALF(3, K2CH - 1, (K2CH - 1) & 1) STAGE_HALF(1, K2CH - 1, (K2CH - 1) & 1)
    asm volatile("s_waitcnt vmcnt(0)" ::: "memory");
    BAR
    #pragma unroll
    for (int e = 0; e < 2; ++e) {
        const int cb = (K2CH - 2 + e) & 1;
        bf16x8 ah[4], am[4], bh[2], bm[2];
        LOAD_A(cb, 0) LOAD_B(cb, 0)
        MFMA_Q(0, 0)
        LOAD_B(cb, 1)
        MFMA_Q(0, 1)
        LOAD_A(cb, 1) LOAD_B(cb, 0)
        MFMA_Q(1, 0)
        LOAD_B(cb, 1)
        MFMA_Q(1, 1)
    }
    #undef STAGE_HALF
    #undef LOAD_A
    #undef LOAD_B
    #undef MFMA_Q
    #undef VM8
    #undef BAR

    // C layout: col = lane&15, row = (lane>>4)*4 + reg
    #pragma unroll
    for (int fm = 0; fm < 8; ++fm)
        #pragma unroll
        for (int fn = 0; fn < 4; ++fn) {
            const int col = n0 + wc + fn * 16 + lrow;
            #pragma unroll
            for (int r = 0; r < 4; ++r) {
                const int row = m0 + wr + fm * 16 + lu * 4 + r;
                G[(size_t)row * NC + col] = acc[fm][fn][r];
            }
        }
}

// ---- K-post: dist assembly + argmin + softmax + avg_prob partials ----
__global__ __launch_bounds__(512)
void k_post(const float* __restrict__ G, const float* __restrict__ bsq,
            const float* __restrict__ zsq, float* __restrict__ A,
            float* __restrict__ wgpart, int* __restrict__ idxws,
            float* __restrict__ out) {
    const int bid = blockIdx.x;
    const int wr0 = bid * 32;
    const int t   = threadIdx.x;
    const int cg  = t & 127;
    const int rq  = t >> 7;
    const int r0  = rq * 8;
    const int c0  = cg * 4;
    const int c1  = 512 + cg * 4;

    __shared__ float sm[9280];
    float* red_v    = sm;
    int*   red_i    = (int*)(sm + 4096);
    float* row_dmin = sm + 8192;
    float* row_s    = sm + 8224;
    float* pc       = sm + 8256;

    float acc[8][8];
    #pragma unroll
    for (int i = 0; i < 8; ++i) {
        const float4 g0 = *(const float4*)&G[(size_t)(wr0 + r0 + i) * NC + c0];
        const float4 g1 = *(const float4*)&G[(size_t)(wr0 + r0 + i) * NC + c1];
        acc[i][0] = g0.x; acc[i][1] = g0.y; acc[i][2] = g0.z; acc[i][3] = g0.w;
        acc[i][4] = g1.x; acc[i][5] = g1.y; acc[i][6] = g1.z; acc[i][7] = g1.w;
    }

    float bsqv[8], zsqv[8];
    #pragma unroll
    for (int j = 0; j < 4; ++j) { bsqv[j] = bsq[c0 + j]; bsqv[4 + j] = bsq[c1 + j]; }
    #pragma unroll
    for (int i = 0; i < 8; ++i) zsqv[i] = zsq[wr0 + r0 + i];

    #pragma unroll
    for (int i = 0; i < 8; ++i)
        #pragma unroll
        for (int j = 0; j < 8; ++j) {
            const float tv = zsqv[i] - 2.f * acc[i][j];
            acc[i][j] = tv + bsqv[j];
        }

    #pragma unroll
    for (int i = 0; i < 8; ++i) {
        float bv = acc[i][0]; int bi = c0;
        #pragma unroll
        for (int j = 1; j < 8; ++j) {
            const int c = (j < 4) ? (c0 + j) : (c1 + (j - 4));
            if (acc[i][j] < bv || (acc[i][j] == bv && c < bi)) { bv = acc[i][j]; bi = c; }
        }
        red_v[(r0 + i) * 128 + cg] = bv;
        red_i[(r0 + i) * 128 + cg] = bi;
    }
    __syncthreads();
    if (t < 32) {
        float bv = red_v[t * 128]; int bi = red_i[t * 128];
        for (int x = 1; x < 128; ++x) {
            const float v = red_v[t * 128 + x];
            const int  iv = red_i[t * 128 + x];
            if (v < bv || (v == bv && iv < bi)) { bv = v; bi = iv; }
        }
        row_dmin[t] = bv;
        idxws[wr0 + t] = bi;
        out[IDX_OFF + wr0 + t] = (float)bi;
    }
    __syncthreads();

    float su[8];
    #pragma unroll
    for (int i = 0; i < 8; ++i) {
        const float dm = row_dmin[r0 + i];
        float s = 0.f;
        #pragma unroll
        for (int j = 0; j < 8; ++j) {
            const float u = expf(dm - acc[i][j]);
            acc[i][j] = u;
            s += u;
        }
        su[i] = s;
    }
    #pragma unroll
    for (int i = 0; i < 8; ++i) red_v[(r0 + i) * 128 + cg] = su[i];
    __syncthreads();
    if (t < 32) {
        float s = 0.f;
        for (int x = 0; x < 128; ++x) s += red_v[t * 128 + x];
        row_s[t] = s;
    }
    __syncthreads();

    float rcp[8];
    #pragma unroll
    for (int i = 0; i < 8; ++i) rcp[i] = 1.f / row_s[r0 + i];

    pc[t] = 0.f; pc[t + 512] = 0.f;
    __syncthreads();
    #pragma unroll
    for (int j = 0; j < 8; ++j) {
        const int c = (j < 4) ? (c0 + j) : (c1 + (j - 4));
        float s = 0.f;
        #pragma unroll
        for (int i = 0; i < 8; ++i) s += acc[i][j] * rcp[i];
        atomicAdd(&pc[c], s);
    }
    __syncthreads();
    atomicAdd(&A[t],       pc[t]);
    atomicAdd(&A[t + 512], pc[t + 512]);

    if (t == 0) {
        float s = 0.f;
        for (int r = 0; r < 32; ++r) s += row_dmin[r];
        wgpart[bid] = s;
    }
}

// ---- finalize scalars ----
__global__ void k_final(const float* __restrict__ wgpart, const float* __restrict__ A,
                        float* __restrict__ out) {
    __shared__ double sd[1024];
    const int t = threadIdx.x;
    sd[t] = (double)wgpart[t];
    __syncthreads();
    for (int off = 512; off > 0; off >>= 1) {
        if (t < off) sd[t] += sd[t + off];
        __syncthreads();
    }
    if (t == 0) out[VQ_OFF] = (float)(0.25 * sd[0] / 88473600.0);
    __syncthreads();
    const double p = (double)A[t] * (1.0 / 32768.0);
    sd[t] = -p * log(p + 1e-8);
    __syncthreads();
    for (int off = 512; off > 0; off >>= 1) {
        if (t < off) sd[t] += sd[t + off];
        __syncthreads();
    }
    if (t == 0) out[ENT_OFF] = (float)sd[0];
}

// ---- q_st = basis[indices] ----
__global__ void k_gather(const float* __restrict__ basis, const int* __restrict__ idxws,
                         float* __restrict__ out) {
    const int r = blockIdx.x;
    const int idx = idxws[r];
    const float4* src = (const float4*)(basis + (size_t)idx * ED);
    float4* dst = (float4*)(out + (size_t)r * ED);
    for (int j = threadIdx.x; j < ED / 4; j += 256) dst[j] = src[j];
}

// =====================================================================
// ===================== FALLBACK (round-2, f32 VALU) ==================
// =====================================================================

__global__ void k_bsq(const float* __restrict__ basis, float* __restrict__ bsq) {
    int c = blockIdx.x;
    const float* row = basis + (size_t)c * ED;
    double s = 0.0;
    for (int j = threadIdx.x; j < ED; j += 256) { float v = row[j]; s += (double)v * (double)v; }
    __shared__ double sd[256];
    sd[threadIdx.x] = s;
    __syncthreads();
    for (int off = 128; off > 0; off >>= 1) {
        if (threadIdx.x < off) sd[threadIdx.x] += sd[threadIdx.x + off];
        __syncthreads();
    }
    if (threadIdx.x == 0) bsq[c] = (float)sd[0];
}

__global__ __launch_bounds__(256, 4)
void k_gemm1(const float* __restrict__ S, const float* __restrict__ W,
             const float* __restrict__ bproj, float* __restrict__ Z) {
    const int e0 = blockIdx.x * 64;
    const int m0 = blockIdx.y * 64;
    const int t  = threadIdx.x;
    const int tx = t & 15, ty = t >> 4;
    __shared__ float alds[32 * 68];
    __shared__ float blds[32 * 68];
    float acc[4][4] = {};
    for (int k0 = 0; k0 < DM; k0 += 32) {
        #pragma unroll
        for (int rep = 0; rep < 2; ++rep) {
            const int id  = t + rep * 256;
            const int row = id >> 3, kq = id & 7;
            const float4 va = *(const float4*)(S + (size_t)(m0 + row) * DM + k0 + 4 * kq);
            alds[(4*kq+0)*68 + row] = va.x;
            alds[(4*kq+1)*68 + row] = va.y;
            alds[(4*kq+2)*68 + row] = va.z;
            alds[(4*kq+3)*68 + row] = va.w;
            float4 vb = make_float4(0.f, 0.f, 0.f, 0.f);
            if (e0 + row < ED)
                vb = *(const float4*)(W + (size_t)(e0 + row) * DM + k0 + 4 * kq);
            blds[(4*kq+0)*68 + row] = vb.x;
            blds[(4*kq+1)*68 + row] = vb.y;
            blds[(4*kq+2)*68 + row] = vb.z;
            blds[(4*kq+3)*68 + row] = vb.w;
        }
        __syncthreads();
        #pragma unroll 8
        for (int k = 0; k < 32; ++k) {
            const float4 a = *(const float4*)&alds[k*68 + 4*ty];
            const float4 b = *(const float4*)&blds[k*68 + 4*tx];
            const float av[4] = {a.x, a.y, a.z, a.w};
            const float bv[4] = {b.x, b.y, b.z, b.w};
            #pragma unroll
            for (int i = 0; i < 4; ++i)
                #pragma unroll
                for (int j = 0; j < 4; ++j)
                    acc[i][j] = fmaf(av[i], bv[j], acc[i][j]);
        }
        __syncthreads();
    }
    const bool valid = (e0 + 4*tx + 4) <= ED;
    float4 bias = make_float4(0.f, 0.f, 0.f, 0.f);
    if (valid) bias = *(const float4*)(bproj + e0 + 4*tx);
    #pragma unroll
    for (int i = 0; i < 4; ++i) {
        if (valid) {
            float4 o;
            o.x = acc[i][0] + bias.x;
            o.y = acc[i][1] + bias.y;
            o.z = acc[i][2] + bias.z;
            o.w = acc[i][3] + bias.w;
            *(float4*)(Z + (size_t)(m0 + 4*ty + i) * ED + e0 + 4*tx) = o;
        }
    }
}

__global__ __launch_bounds__(64)
void k_zsq(const float* __restrict__ Z, float* __restrict__ zsq) {
    const int r = blockIdx.x;
    const float4* row4 = (const float4*)(Z + (size_t)r * ED);
    double s = 0.0;
    for (int q = threadIdx.x; q < ED / 4; q += 64) {
        const float4 v = row4[q];
        s += (double)v.x * v.x + (double)v.y * v.y + (double)v.z * v.z + (double)v.w * v.w;
    }
    #pragma unroll
    for (int off = 32; off > 0; off >>= 1) s += __shfl_down(s, off);
    if (threadIdx.x == 0) zsq[r] = (float)s;
}

__global__ __launch_bounds__(512, 2)
void k_dist(const float* __restrict__ Z, const float* __restrict__ basis,
            const float* __restrict__ bsq, const float* __restrict__ zsq,
            float* __restrict__ A, float* __restrict__ wgpart,
            int* __restrict__ idxws, float* __restrict__ out) {
    const int bid = blockIdx.x;
    const int wr0 = bid * 32;
    const int t   = threadIdx.x;
    const int cg  = t & 127;
    const int rq  = t >> 7;
    const int r0  = rq * 8;
    const int c0  = cg * 4;
    const int c1  = 512 + cg * 4;
    __shared__ float blds[16 * 1024];
    __shared__ float zlds[16 * 36];
    float acc[8][8];
    #pragma unroll
    for (int i = 0; i < 8; ++i)
        #pragma unroll
        for (int j = 0; j < 8; ++j) acc[i][j] = 0.f;
    for (int k0 = 0; k0 < ED; k0 += 16) {
        const bool full = (k0 + 16) <= ED;
        #pragma unroll
        for (int rep = 0; rep < 2; ++rep) {
            const int c = t + rep * 512;
            const float* bp = basis + (size_t)c * ED + k0;
            if (full) {
                const float4 v0 = *(const float4*)(bp + 0);
                const float4 v1 = *(const float4*)(bp + 4);
                const float4 v2 = *(const float4*)(bp + 8);
                const float4 v3 = *(const float4*)(bp + 12);
                blds[ 0*1024+c]=v0.x; blds[ 1*1024+c]=v0.y; blds[ 2*1024+c]=v0.z; blds[ 3*1024+c]=v0.w;
                blds[ 4*1024+c]=v1.x; blds[ 5*1024+c]=v1.y; blds[ 6*1024+c]=v1.z; blds[ 7*1024+c]=v1.w;
                blds[ 8*1024+c]=v2.x; blds[ 9*1024+c]=v2.y; blds[10*1024+c]=v2.z; blds[11*1024+c]=v2.w;
                blds[12*1024+c]=v3.x; blds[13*1024+c]=v3.y; blds[14*1024+c]=v3.z; blds[15*1024+c]=v3.w;
            } else {
                for (int kk = 0; kk < 16; ++kk)
                    blds[kk*1024 + c] = (k0 + kk < ED) ? bp[kk] : 0.f;
            }
        }
        if (t < 128) {
            const int row = t >> 2, kq = t & 3;
            const float* zp = Z + (size_t)(wr0 + row) * ED + k0 + 4 * kq;
            if (full) {
                const float4 v = *(const float4*)zp;
                zlds[(4*kq+0)*36 + row] = v.x;
                zlds[(4*kq+1)*36 + row] = v.y;
                zlds[(4*kq+2)*36 + row] = v.z;
                zlds[(4*kq+3)*36 + row] = v.w;
            } else {
                for (int j = 0; j < 4; ++j) {
                    const int k = k0 + 4*kq + j;
                    zlds[(4*kq+j)*36 + row] = (k < ED) ? zp[j] : 0.f;
                }
            }
        }
        __syncthreads();
        #pragma unroll
        for (int k = 0; k < 16; ++k) {
            const float4 z0 = *(const float4*)&zlds[k*36 + r0];
            const float4 z1 = *(const float4*)&zlds[k*36 + r0 + 4];
            const float4 b0 = *(const float4*)&blds[k*1024 + c0];
            const float4 b1 = *(const float4*)&blds[k*1024 + c1];
            const float zz[8] = {z0.x, z0.y, z0.z, z0.w, z1.x, z1.y, z1.z, z1.w};
            const float bb[8] = {b0.x, b0.y, b0.z, b0.w, b1.x, b1.y, b1.z, b1.w};
            #pragma unroll
            for (int i = 0; i < 8; ++i)
                #pragma unroll
                for (int j = 0; j < 8; ++j)
                    acc[i][j] = fmaf(zz[i], bb[j], acc[i][j]);
        }
        __syncthreads();
    }
    float* red_v    = blds;
    int*   red_i    = (int*)(blds + 4096);
    float* row_dmin = blds + 8192;
    float* row_s    = blds + 8224;
    float* pc       = blds + 8256;
    float bsqv[8], zsqv[8];
    #pragma unroll
    for (int j = 0; j < 4; ++j) { bsqv[j] = bsq[c0 + j]; bsqv[4 + j] = bsq[c1 + j]; }
    #pragma unroll
    for (int i = 0; i < 8; ++i) zsqv[i] = zsq[wr0 + r0 + i];
    #pragma unroll
    for (int i = 0; i < 8; ++i)
        #pragma unroll
        for (int j = 0; j < 8; ++j) {
            const float tv = zsqv[i] - 2.f * acc[i][j];
            acc[i][j] = tv + bsqv[j];
        }
    #pragma unroll
    for (int i = 0; i < 8; ++i) {
        float bv = acc[i][0]; int bi = c0;
        #pragma unroll
        for (int j = 1; j < 8; ++j) {
            const int c = (j < 4) ? (c0 + j) : (c1 + (j - 4));
            if (acc[i][j] < bv || (acc[i][j] == bv && c < bi)) { bv = acc[i][j]; bi = c; }
        }
        red_v[(r0 + i) * 128 + cg] = bv;
        red_i[(r0 + i) * 128 + cg] = bi;
    }
    __syncthreads();
    if (t < 32) {
        float bv = red_v[t * 128]; int bi = red_i[t * 128];
        for (int x = 1; x < 128; ++x) {
            const float v = red_v[t * 128 + x];
            const int  iv = red_i[t * 128 + x];
            if (v < bv || (v == bv && iv < bi)) { bv = v; bi = iv; }
        }
        row_dmin[t] = bv;
        idxws[wr0 + t] = bi;
        out[IDX_OFF + wr0 + t] = (float)bi;
    }
    __syncthreads();
    float su[8];
    #pragma unroll
    for (int i = 0; i < 8; ++i) {
        const float dm = row_dmin[r0 + i];
        float s = 0.f;
        #pragma unroll
        for (int j = 0; j < 8; ++j) {
            const float u = expf(dm - acc[i][j]);
            acc[i][j] = u;
            s += u;
        }
        su[i] = s;
    }
    #pragma unroll
    for (int i = 0; i < 8; ++i) red_v[(r0 + i) * 128 + cg] = su[i];
    __syncthreads();
    if (t < 32) {
        float s = 0.f;
        for (int x = 0; x < 128; ++x) s += red_v[t * 128 + x];
        row_s[t] = s;
    }
    __syncthreads();
    float rcp[8];
    #pragma unroll
    for (int i = 0; i < 8; ++i) rcp[i] = 1.f / row_s[r0 + i];
    pc[t] = 0.f; pc[t + 512] = 0.f;
    __syncthreads();
    #pragma unroll
    for (int j = 0; j < 8; ++j) {
        const int c = (j < 4) ? (c0 + j) : (c1 + (j - 4));
        float s = 0.f;
        #pragma unroll
        for (int i = 0; i < 8; ++i) s += acc[i][j] * rcp[i];
        atomicAdd(&pc[c], s);
    }
    __syncthreads();
    atomicAdd(&A[t],       pc[t]);
    atomicAdd(&A[t + 512], pc[t + 512]);
    if (t == 0) {
        float s = 0.f;
        for (int r = 0; r < 32; ++r) s += row_dmin[r];
        wgpart[bid] = s;
    }
}

// =====================================================================

extern "C" void kernel_launch(void* const* d_in, const int* in_sizes, int n_in,
                              void* d_out, int out_size, void* d_ws, size_t ws_size,
                              hipStream_t stream) {
    const float* S     = (const float*)d_in[0];  // [32768, 256]
    const float* W     = (const float*)d_in[1];  // [2700, 256]
    const float* bproj = (const float*)d_in[2];  // [2700]
    const float* basis = (const float*)d_in[3];  // [1024, 2700]
    float* out = (float*)d_out;
    float* ws  = (float*)d_ws;

    // common small regions
    float* zsq    = ws;                  // 32768
    float* A      = ws + 32768;          // 1024
    float* bsq    = ws + 33792;          // 1024
    float* wgpart = ws + 34816;          // 1024
    int*   idxws  = (int*)(ws + 35840);  // 32768

    // ws floats: 68608 small + Ph/Pm 262144 + G 33554432 = 33,885,184 (~135.5 MB)
    const size_t NEED = (size_t)33885184 * sizeof(float);
    if (ws_size >= NEED) {
        // -------- MFMA path (reassociated: G = S.(basis.W)^T) --------
        unsigned short* Ph = (unsigned short*)(ws + 68608);            // 1024*256 ush
        unsigned short* Pm = (unsigned short*)(ws + 68608 + 131072);
        float*          G  = ws + 330752;                              // 32768*1024
        // transients aliased into G (all dead before k_gemm2 writes G)
        float* basisP  = G;                  // 1024*2720 = 2785280
        float* WT      = G + 2785280;        // 256*2720  = 696320
        float* uv      = G + 3481600;        // 257 (u[256], v)
        float* Pp      = G + 3481984;        // 5*262144 = 1310720
        float* Mp      = G + 4792704;        // 5*65536  = 327680
        float* Mm      = G + 5120384;        // 65536
        float* zsqpart = G + 5185920;        // 4*32768  = 131072 -> ends 5316992
        // S planes live in q_st output region (dead before k_gather writes q_st)
        unsigned short* Sh = (unsigned short*)out;                     // 32768*256 ush
        unsigned short* Sm = Sh + (size_t)BKROWS * DM;

        hipMemsetAsync(A, 0, (size_t)NC * sizeof(float), stream);
        k_packS <<<BKROWS * DM / 1024, 256, 0, stream>>>(S, Sh, Sm);
        k_bsq2  <<<NC, 256, 0, stream>>>(basis, bproj, bsq);
        k_padB  <<<NC, 256, 0, stream>>>(basis, basisP);
        k_padWT <<<dim3(43, 4), 256, 0, stream>>>(W, WT);
        k_uv2   <<<257, 256, 0, stream>>>(WT, bproj, uv);
        k_gsplit<<<dim3(4, 16, 5), 256, 0, stream>>>(basisP, WT, Pp, 256);  // P partials
        k_gsplit<<<dim3(4, 4, 5),  256, 0, stream>>>(WT, WT, Mp, 256);      // M partials
        k_redP  <<<1024, 256, 0, stream>>>(Pp, Ph, Pm);
        k_redM  <<<256, 256, 0, stream>>>(Mp, Mm);
        k_zsqS  <<<dim3(NTZ, 512), 256, 0, stream>>>(S, Mm, uv, zsqpart);
        k_zsqred<<<BKROWS / 256, 256, 0, stream>>>(zsqpart, zsq);
        k_gemm2 <<<512, 512, 0, stream>>>(Sh, Sm, Ph, Pm, G);
        k_post  <<<BKROWS / 32, 512, 0, stream>>>(G, bsq, zsq, A, wgpart, idxws, out);
        k_final <<<1, 1024, 0, stream>>>(wgpart, A, out);
        k_gather<<<BKROWS, 256, 0, stream>>>(basis, idxws, out);
    } else {
        // -------- fallback: round-2 f32 path --------
        float* Z = out;
        hipMemsetAsync(A, 0, (size_t)NC * sizeof(float), stream);
        k_bsq   <<<NC, 256, 0, stream>>>(basis, bsq);
        k_gemm1 <<<dim3(43, 512), 256, 0, stream>>>(S, W, bproj, Z);
        k_zsq   <<<BKROWS, 64, 0, stream>>>(Z, zsq);
        k_dist  <<<BKROWS / 32, 512, 0, stream>>>(Z, basis, bsq, zsq, A, wgpart, idxws, out);
        k_final <<<1, 1024, 0, stream>>>(wgpart, A, out);
        k_gather<<<BKROWS, 256, 0, stream>>>(basis, idxws, out);
    }
}